// Round 8
// baseline (611.227 us; speedup 1.0000x reference)
//
#include <hip/hip_runtime.h>
#include <hip/hip_bf16.h>

// ---------------------------------------------------------------------------
// GNN Residual Feature Extractor
//   x = embed(type features)                       [N,32]
//   x1 = gcn(x, W1)+b1                             [N,64]
//   h  = relu(gcn(relu(x1),W2)+b2)                 [N,128]
//   h  = relu(gcn(h,W3)+b3) + x1                   [N,64]
//   out = segment_mean(h, batch)                   [100,64]
//
// gcn agg commutes with weight multiply; aggregate on narrow side.
// Gather TABLES are bf16 (packed u32 pairs), PRE-SCALED by dinv and
// pre-activated by their producers; accumulation stays f32.
// Residual x1 is stored bf16 (x1b).
//
// CSR build: atomic-free two-pass radix partition (bin = dst>>10), pairs
// packed into one u32 (src<<10 | dst&1023).
//
// k_mmt: LDS-tiled x (coalesced), wave cg owns a column band, W/bias read
// as WAVE-UNIFORM SCALAR loads. R7 lesson: c0 derived from threadIdx.x is
// "divergent" to LLVM -> W fell to broadcast vector loads (SGPR 112->32,
// 92->137us). readfirstlane(tid>>6) restores s_load.
// ---------------------------------------------------------------------------

#define THREADS 256
#define BINSHIFT 10
#define EPBA 4096        // edges per partition block
#define SCANCH 8         // k_scanrows: values per thread (supports <=2048 blocks)

// ---------------- bf16 helpers ----------------
__device__ __forceinline__ unsigned bfpack2(float lo, float hi) {
    unsigned ul = __float_as_uint(lo);
    unsigned uh = __float_as_uint(hi);
    ul = (ul + 0x7fffu + ((ul >> 16) & 1u)) >> 16;          // rne, low half
    uh = (uh + 0x7fffu + ((uh >> 16) & 1u)) & 0xffff0000u;  // rne, high half
    return ul | uh;
}

__device__ __forceinline__ void bfacc(uint2 v, float& a0, float& a1,
                                      float& a2, float& a3) {
    a0 += __uint_as_float(v.x << 16);
    a1 += __uint_as_float(v.x & 0xffff0000u);
    a2 += __uint_as_float(v.y << 16);
    a3 += __uint_as_float(v.y & 0xffff0000u);
}

// ---------------- pass 1: per-(block,bin) exact counts ----------------
__global__ __launch_bounds__(THREADS)
void k_partcnt(const int* __restrict__ dst, int* __restrict__ counts,
               int nblk_part, int nb, int e) {
    extern __shared__ int h[];
    int t = threadIdx.x;
    for (int i = t; i < nb; i += THREADS) h[i] = 0;
    __syncthreads();
    int lo = blockIdx.x * EPBA;
    int hi = min(lo + EPBA, e);
    for (int i = lo + t; i < hi; i += THREADS)
        atomicAdd(&h[dst[i] >> BINSHIFT], 1);
    __syncthreads();
    for (int i = t; i < nb; i += THREADS)
        counts[(size_t)i * nblk_part + blockIdx.x] = h[i];
}

// ---------------- scan each bin's row of per-block counts ----------------
__global__ __launch_bounds__(THREADS)
void k_scanrows(int* __restrict__ counts, int* __restrict__ bintot, int nblk_part) {
    __shared__ int wsum[THREADS];
    int* row = counts + (size_t)blockIdx.x * nblk_part;
    int t = threadIdx.x;
    int base = t * SCANCH;
    int v[SCANCH];
    int s = 0;
#pragma unroll
    for (int k = 0; k < SCANCH; ++k) {
        v[k] = (base + k < nblk_part) ? row[base + k] : 0;
        s += v[k];
    }
    wsum[t] = s;
    __syncthreads();
    for (int off = 1; off < THREADS; off <<= 1) {
        int a = (t >= off) ? wsum[t - off] : 0;
        __syncthreads();
        wsum[t] += a;
        __syncthreads();
    }
    int run = wsum[t] - s;  // exclusive
#pragma unroll
    for (int k = 0; k < SCANCH; ++k) {
        int c = v[k];
        if (base + k < nblk_part) row[base + k] = run;
        run += c;
    }
    if (t == THREADS - 1) bintot[blockIdx.x] = run;
}

// ---------------- scan bin totals (single block, nb<=128) ----------------
__global__ __launch_bounds__(128)
void k_binscan(const int* __restrict__ bintot, int* __restrict__ binptr,
               int nb, int e) {
    __shared__ int lds[128];
    int t = threadIdx.x;
    int v = (t < nb) ? bintot[t] : 0;
    lds[t] = v;
    __syncthreads();
    for (int off = 1; off < 128; off <<= 1) {
        int a = (t >= off) ? lds[t - off] : 0;
        __syncthreads();
        lds[t] += a;
        __syncthreads();
    }
    if (t < nb) binptr[t] = lds[t] - v;  // exclusive
    if (t == 0) binptr[nb] = e;
}

// ---------------- pass 2: deterministic partition write (packed u32) --------
__global__ __launch_bounds__(THREADS)
void k_partwrite(const int* __restrict__ src, const int* __restrict__ dst,
                 const int* __restrict__ binptr, const int* __restrict__ counts,
                 int nblk_part, unsigned* __restrict__ pairs, int nb, int e) {
    extern __shared__ int smem[];
    int* base = smem;       // nb
    int* cnt  = smem + nb;  // nb
    int t = threadIdx.x;
    for (int i = t; i < nb; i += THREADS) {
        base[i] = binptr[i] + counts[(size_t)i * nblk_part + blockIdx.x];
        cnt[i] = 0;
    }
    __syncthreads();
    int lo = blockIdx.x * EPBA;
    int hi = min(lo + EPBA, e);
    for (int i = lo + t; i < hi; i += THREADS) {
        int s = src[i], d = dst[i];
        int b = d >> BINSHIFT;
        int pos = atomicAdd(&cnt[b], 1);   // LDS only
        pairs[base[b] + pos] = ((unsigned)s << BINSHIFT) | (unsigned)(d & ((1 << BINSHIFT) - 1));
    }
}

// ---------------- per-bin CSR finalize ----------------
__global__ __launch_bounds__(THREADS)
void k_bincsr(const unsigned* __restrict__ pairs, const int* __restrict__ binptr,
              int* __restrict__ rowptr, float* __restrict__ dinv,
              int* __restrict__ srcs, int n, int nb, int e) {
    __shared__ int lcnt[1024];
    __shared__ int lofs[1024];
    __shared__ int wsum[THREADS];
    int b = blockIdx.x, t = threadIdx.x;
    int e0 = binptr[b], e1 = binptr[b + 1];
    int n0 = b << BINSHIFT;
    for (int i = t; i < 1024; i += THREADS) lcnt[i] = 0;
    __syncthreads();
    for (int j = e0 + t; j < e1; j += THREADS)
        atomicAdd(&lcnt[pairs[j] & 1023u], 1);
    __syncthreads();
    int c0 = lcnt[4 * t + 0], c1 = lcnt[4 * t + 1];
    int c2 = lcnt[4 * t + 2], c3 = lcnt[4 * t + 3];
    int s = c0 + c1 + c2 + c3;
    wsum[t] = s;
    __syncthreads();
    for (int off = 1; off < THREADS; off <<= 1) {
        int a = (t >= off) ? wsum[t - off] : 0;
        __syncthreads();
        wsum[t] += a;
        __syncthreads();
    }
    int excl = wsum[t] - s;
    lofs[4 * t + 0] = excl;
    lofs[4 * t + 1] = excl + c0;
    lofs[4 * t + 2] = excl + c0 + c1;
    lofs[4 * t + 3] = excl + c0 + c1 + c2;
    __syncthreads();
    for (int i = t; i < 1024; i += THREADS) {
        int node = n0 + i;
        if (node < n) {
            rowptr[node] = e0 + lofs[i];
            dinv[node] = rsqrtf((float)lcnt[i] + 1.0f);
        }
    }
    if (b == nb - 1 && t == 0) rowptr[n] = e;
    __syncthreads();
    for (int j = e0 + t; j < e1; j += THREADS) {
        unsigned pp = pairs[j];
        int pos = e0 + atomicAdd(&lofs[pp & 1023u], 1);
        srcs[pos] = (int)(pp >> BINSHIFT);
    }
}

// ---------------- embedding: xb[idx[r]] = bf16(dinv * (f[r] @ W + b)) --------
template <int K>
__global__ __launch_bounds__(THREADS)
void k_embed(const float* __restrict__ f, const float* __restrict__ W,
             const float* __restrict__ b, const int* __restrict__ idx,
             const float* __restrict__ dinv, int rows, unsigned* __restrict__ xb) {
    int g = blockIdx.x * THREADS + threadIdx.x;
    int r = g >> 4, cp = g & 15;
    if (r >= rows) return;
    int node = idx[r];
    float dv = dinv[node];
    float a0 = b[2 * cp], a1 = b[2 * cp + 1];
#pragma unroll
    for (int k = 0; k < K; ++k) {
        float fv = f[r * K + k];
        a0 += fv * W[k * 32 + 2 * cp];
        a1 += fv * W[k * 32 + 2 * cp + 1];
    }
    xb[(size_t)node * 16 + cp] = bfpack2(dv * a0, dv * a1);
}

// ---------------- gather (bf16 table, row=128B): one wave per node ----------
// 4 quarter-groups of 16 lanes; each quarter owns one edge's full row.
// out[i] = dv_i * (tbl[i] + sum_s tbl[s])  [+bias][relu][+resid(bf16)], f32 out.
template <bool HASBIAS, bool OUTRELU, bool HASRES>
__global__ __launch_bounds__(THREADS)
void k_gather64(const unsigned* __restrict__ tblb, const int* __restrict__ rowptr,
                const int* __restrict__ srcs, const float* __restrict__ dinv,
                const float* __restrict__ bias, const unsigned* __restrict__ resid,
                float* __restrict__ out, int n) {
    int gt = blockIdx.x * THREADS + threadIdx.x;
    int node = gt >> 6;
    int lane = threadIdx.x & 63;
    if (node >= n) return;
    int qw = lane >> 4, li = lane & 15;
    const uint2* t2 = reinterpret_cast<const uint2*>(tblb);
    float a0 = 0.f, a1 = 0.f, a2 = 0.f, a3 = 0.f;
    int beg = rowptr[node], end = rowptr[node + 1];
    int j = beg;
    for (; j + 16 <= end; j += 16) {          // 16 edges, 4 rows in flight
        int i0 = srcs[j + qw];
        int i1 = srcs[j + 4 + qw];
        int i2 = srcs[j + 8 + qw];
        int i3 = srcs[j + 12 + qw];
        uint2 v0 = t2[(size_t)i0 * 16 + li];
        uint2 v1 = t2[(size_t)i1 * 16 + li];
        uint2 v2 = t2[(size_t)i2 * 16 + li];
        uint2 v3 = t2[(size_t)i3 * 16 + li];
        bfacc(v0, a0, a1, a2, a3);
        bfacc(v1, a0, a1, a2, a3);
        bfacc(v2, a0, a1, a2, a3);
        bfacc(v3, a0, a1, a2, a3);
    }
    for (; j + 8 <= end; j += 8) {
        int i0 = srcs[j + qw];
        int i1 = srcs[j + 4 + qw];
        uint2 v0 = t2[(size_t)i0 * 16 + li];
        uint2 v1 = t2[(size_t)i1 * 16 + li];
        bfacc(v0, a0, a1, a2, a3);
        bfacc(v1, a0, a1, a2, a3);
    }
    int rem = end - j;
    if (qw < rem) {
        uint2 v = t2[(size_t)srcs[j + qw] * 16 + li];
        bfacc(v, a0, a1, a2, a3);
    }
    if (qw + 4 < rem) {
        uint2 v = t2[(size_t)srcs[j + 4 + qw] * 16 + li];
        bfacc(v, a0, a1, a2, a3);
    }
    a0 += __shfl_down(a0, 32, 64); a1 += __shfl_down(a1, 32, 64);
    a2 += __shfl_down(a2, 32, 64); a3 += __shfl_down(a3, 32, 64);
    a0 += __shfl_down(a0, 16, 64); a1 += __shfl_down(a1, 16, 64);
    a2 += __shfl_down(a2, 16, 64); a3 += __shfl_down(a3, 16, 64);
    if (lane < 16) {
        uint2 sv = t2[(size_t)node * 16 + li];
        bfacc(sv, a0, a1, a2, a3);
        float dv = dinv[node];
        float r0 = dv * a0, r1 = dv * a1, r2 = dv * a2, r3 = dv * a3;
        if (HASBIAS) {
            float4 bv = *reinterpret_cast<const float4*>(bias + 4 * li);
            r0 += bv.x; r1 += bv.y; r2 += bv.z; r3 += bv.w;
        }
        if (OUTRELU) {
            r0 = fmaxf(r0, 0.f); r1 = fmaxf(r1, 0.f);
            r2 = fmaxf(r2, 0.f); r3 = fmaxf(r3, 0.f);
        }
        if (HASRES) {
            uint2 rv = reinterpret_cast<const uint2*>(resid)[(size_t)node * 16 + li];
            bfacc(rv, r0, r1, r2, r3);
        }
        float4 o = {r0, r1, r2, r3};
        reinterpret_cast<float4*>(out)[(size_t)node * 16 + li] = o;
    }
}

// ---------------- gather (bf16 table, row=64B): 8 groups of 8 lanes ---------
__global__ __launch_bounds__(THREADS)
void k_gather32(const unsigned* __restrict__ tblb, const int* __restrict__ rowptr,
                const int* __restrict__ srcs, const float* __restrict__ dinv,
                float* __restrict__ out, int n) {
    int gt = blockIdx.x * THREADS + threadIdx.x;
    int node = gt >> 6;
    int lane = threadIdx.x & 63;
    if (node >= n) return;
    int og = lane >> 3, li = lane & 7;
    const uint2* t2 = reinterpret_cast<const uint2*>(tblb);
    float a0 = 0.f, a1 = 0.f, a2 = 0.f, a3 = 0.f;
    int beg = rowptr[node], end = rowptr[node + 1];
    int j = beg;
    for (; j + 16 <= end; j += 16) {          // 16 edges, 2 rows in flight/lane
        int i0 = srcs[j + og];
        int i1 = srcs[j + 8 + og];
        uint2 v0 = t2[(size_t)i0 * 8 + li];
        uint2 v1 = t2[(size_t)i1 * 8 + li];
        bfacc(v0, a0, a1, a2, a3);
        bfacc(v1, a0, a1, a2, a3);
    }
    for (; j + 8 <= end; j += 8) {
        int i0 = srcs[j + og];
        uint2 v0 = t2[(size_t)i0 * 8 + li];
        bfacc(v0, a0, a1, a2, a3);
    }
    int rem = end - j;
    if (og < rem) {
        uint2 v = t2[(size_t)srcs[j + og] * 8 + li];
        bfacc(v, a0, a1, a2, a3);
    }
    a0 += __shfl_down(a0, 32, 64); a1 += __shfl_down(a1, 32, 64);
    a2 += __shfl_down(a2, 32, 64); a3 += __shfl_down(a3, 32, 64);
    a0 += __shfl_down(a0, 16, 64); a1 += __shfl_down(a1, 16, 64);
    a2 += __shfl_down(a2, 16, 64); a3 += __shfl_down(a3, 16, 64);
    a0 += __shfl_down(a0, 8, 64);  a1 += __shfl_down(a1, 8, 64);
    a2 += __shfl_down(a2, 8, 64);  a3 += __shfl_down(a3, 8, 64);
    if (lane < 8) {
        uint2 sv = t2[(size_t)node * 8 + li];
        bfacc(sv, a0, a1, a2, a3);
        float dv = dinv[node];
        float4 o = {dv * a0, dv * a1, dv * a2, dv * a3};
        reinterpret_cast<float4*>(out)[(size_t)node * 8 + li] = o;
    }
}

// ---------------- tiled dense matmul: out[N,FOUT] = in[N,FIN] @ W + b --------
// Block = 64 rows. x tile staged in LDS (coalesced); lane = row; wave cg
// (readfirstlane -> SGPR!) owns cols [cg*CW,(cg+1)*CW), processed 8 at a
// time; W/bias via wave-uniform scalar loads with immediate offsets.
// EXTRA: 0 = f32 out; 1 = outb=bf16(acc), outb2=bf16(dinv*relu(acc));
//        2 = outb=bf16(dinv*acc).
template <int FIN, int FOUT, bool HASBIAS, bool OUTRELU, int EXTRA>
__global__ __launch_bounds__(THREADS)
void k_mmt(const float* __restrict__ xin, const float* __restrict__ W,
           const float* __restrict__ bias, const float* __restrict__ dinv,
           float* __restrict__ out, unsigned* __restrict__ outb,
           unsigned* __restrict__ outb2, int nrows) {
    constexpr int FINQ = FIN / 4;
    constexpr int CW = FOUT / 4;      // cols per wave (4 waves)
    __shared__ float4 xs[64][FINQ + 1];
    int tid = threadIdx.x;
    int r0 = blockIdx.x * 64;
    const float4* xin4 = reinterpret_cast<const float4*>(xin);
    for (int i = tid; i < 64 * FINQ; i += THREADS) {
        int rr = i / FINQ, q = i - rr * FINQ;
        int grow = r0 + rr;
        float4 v = {0.f, 0.f, 0.f, 0.f};
        if (grow < nrows) v = xin4[(size_t)grow * FINQ + q];
        xs[rr][q] = v;
    }
    __syncthreads();
    int lane = tid & 63;
    int cg = __builtin_amdgcn_readfirstlane(tid >> 6);  // SGPR wave id -> s_load W
    int row = r0 + lane;
    int c0 = cg * CW;
    bool valid = row < nrows;
    float dv = (EXTRA != 0) ? (valid ? dinv[row] : 0.f) : 0.f;

#pragma unroll
    for (int cc = 0; cc < CW; cc += 8) {
        const float* Wc = W + c0 + cc;
        float a[8];
#pragma unroll
        for (int i = 0; i < 8; ++i) a[i] = HASBIAS ? bias[c0 + cc + i] : 0.f;
#pragma unroll
        for (int q = 0; q < FINQ; ++q) {
            float4 xv = xs[lane][q];
            const float* w0 = Wc + (size_t)(4 * q + 0) * FOUT;
            const float* w1 = Wc + (size_t)(4 * q + 1) * FOUT;
            const float* w2 = Wc + (size_t)(4 * q + 2) * FOUT;
            const float* w3 = Wc + (size_t)(4 * q + 3) * FOUT;
#pragma unroll
            for (int i = 0; i < 8; ++i) {
                a[i] = fmaf(xv.x, w0[i], a[i]);
                a[i] = fmaf(xv.y, w1[i], a[i]);
                a[i] = fmaf(xv.z, w2[i], a[i]);
                a[i] = fmaf(xv.w, w3[i], a[i]);
            }
        }
        if (valid) {
            if (OUTRELU) {
#pragma unroll
                for (int i = 0; i < 8; ++i) a[i] = fmaxf(a[i], 0.f);
            }
            int cb = c0 + cc;
            if (EXTRA == 0) {
                float4 o0 = {a[0], a[1], a[2], a[3]};
                float4 o1 = {a[4], a[5], a[6], a[7]};
                float4* op = reinterpret_cast<float4*>(out + (size_t)row * FOUT + cb);
                op[0] = o0; op[1] = o1;
            }
            if (EXTRA == 1) {
                uint4 b4 = {bfpack2(a[0], a[1]), bfpack2(a[2], a[3]),
                            bfpack2(a[4], a[5]), bfpack2(a[6], a[7])};
                uint4 s4 = {bfpack2(dv * fmaxf(a[0], 0.f), dv * fmaxf(a[1], 0.f)),
                            bfpack2(dv * fmaxf(a[2], 0.f), dv * fmaxf(a[3], 0.f)),
                            bfpack2(dv * fmaxf(a[4], 0.f), dv * fmaxf(a[5], 0.f)),
                            bfpack2(dv * fmaxf(a[6], 0.f), dv * fmaxf(a[7], 0.f))};
                *reinterpret_cast<uint4*>(outb + (size_t)row * (FOUT / 2) + cb / 2) = b4;
                *reinterpret_cast<uint4*>(outb2 + (size_t)row * (FOUT / 2) + cb / 2) = s4;
            }
            if (EXTRA == 2) {
                uint4 b4 = {bfpack2(dv * a[0], dv * a[1]), bfpack2(dv * a[2], dv * a[3]),
                            bfpack2(dv * a[4], dv * a[5]), bfpack2(dv * a[6], dv * a[7])};
                *reinterpret_cast<uint4*>(outb + (size_t)row * (FOUT / 2) + cb / 2) = b4;
            }
        }
    }
}

// ---------------- segment mean pool ----------------
__global__ __launch_bounds__(THREADS)
void k_pool(const float* __restrict__ h, const int* __restrict__ batch,
            float* __restrict__ sums, float* __restrict__ cnts, int n) {
    int c = threadIdx.x & 63;
    int rq = threadIdx.x >> 6;  // 0..3
    int r0 = blockIdx.x * THREADS;
    int rend = min(r0 + THREADS, n);
    int curg = -1;
    float acc = 0.f, cacc = 0.f;
    for (int r = r0 + rq; r < rend; r += 4) {
        int g = batch[r];
        if (g != curg) {
            if (curg >= 0) {
                atomicAdd(&sums[(size_t)curg * 64 + c], acc);
                if (c == 0) atomicAdd(&cnts[curg], cacc);
            }
            curg = g; acc = 0.f; cacc = 0.f;
        }
        acc += h[(size_t)r * 64 + c];
        cacc += 1.f;
    }
    if (curg >= 0) {
        atomicAdd(&sums[(size_t)curg * 64 + c], acc);
        if (c == 0) atomicAdd(&cnts[curg], cacc);
    }
}

__global__ __launch_bounds__(THREADS)
void k_div(const float* __restrict__ sums, const float* __restrict__ cnts,
           float* __restrict__ out, int total) {
    int i = blockIdx.x * THREADS + threadIdx.x;
    if (i < total) out[i] = sums[i] / cnts[i >> 6];
}

// ---------------------------------------------------------------------------
static inline size_t alignup(size_t v) { return (v + 255) & ~(size_t)255; }

extern "C" void kernel_launch(void* const* d_in, const int* in_sizes, int n_in,
                              void* d_out, int out_size, void* d_ws, size_t ws_size,
                              hipStream_t stream) {
    const float* ev_f  = (const float*)d_in[0];
    const float* cs_f  = (const float*)d_in[1];
    const float* tr_f  = (const float*)d_in[2];
    const float* env_f = (const float*)d_in[3];
    const int*   ei    = (const int*)d_in[4];
    const int*   ev_i  = (const int*)d_in[5];
    const int*   cs_i  = (const int*)d_in[6];
    const int*   tr_i  = (const int*)d_in[7];
    const int*   env_i = (const int*)d_in[8];
    const int*   batch = (const int*)d_in[9];
    const float* W_ev = (const float*)d_in[10]; const float* b_ev = (const float*)d_in[11];
    const float* W_cs = (const float*)d_in[12]; const float* b_cs = (const float*)d_in[13];
    const float* W_tr = (const float*)d_in[14]; const float* b_tr = (const float*)d_in[15];
    const float* W_env= (const float*)d_in[16]; const float* b_env= (const float*)d_in[17];
    const float* W1 = (const float*)d_in[18]; const float* b1 = (const float*)d_in[19];
    const float* W2 = (const float*)d_in[20]; const float* b2 = (const float*)d_in[21];
    const float* W3 = (const float*)d_in[22]; const float* b3 = (const float*)d_in[23];

    const int E_ = in_sizes[4] / 2;
    const int N_ = in_sizes[9];
    const int n_ev  = in_sizes[5];
    const int n_cs  = in_sizes[6];
    const int n_tr  = in_sizes[7];
    const int n_env = in_sizes[8];
    const int ngr   = out_size / 64;  // 100 graphs

    const int* e_src = ei;
    const int* e_dst = ei + E_;

    const int NB   = (N_ + (1 << BINSHIFT) - 1) >> BINSHIFT;  // 98 bins
    const int ablk = (E_ + EPBA - 1) / EPBA;                  // 782 partition blocks

    // ---- workspace carve-up ----
    char* p = (char*)d_ws;
    int*      counts = (int*)p;      p += alignup((size_t)NB * ablk * 4);
    int*      bintot = (int*)p;      p += alignup((size_t)NB * 4);
    int*      binptr = (int*)p;      p += alignup(((size_t)NB + 1) * 4);
    int*      rowptr = (int*)p;      p += alignup(((size_t)N_ + 1) * 4);
    float*    dinv   = (float*)p;    p += alignup((size_t)N_ * 4);
    int*      srcs   = (int*)p;      p += alignup((size_t)E_ * 4);
    unsigned* xb     = (unsigned*)p; p += alignup((size_t)N_ * 16 * 4);   // bf16 [N,32]
    unsigned* x1b    = (unsigned*)p; p += alignup((size_t)N_ * 32 * 4);   // bf16 [N,64] raw x1
    float*    bufB   = (float*)p;    p += alignup((size_t)N_ * 64 * 4);
    float*    bufA   = (float*)p;    p += alignup((size_t)N_ * 128 * 4);
    float*    sums   = (float*)p;    p += alignup((size_t)ngr * 64 * 4);
    float*    cnts   = (float*)p;    p += alignup((size_t)ngr * 4);

    // Aliases into dead regions of bufA / bufB:
    //  pairs  (E u32 = 12.8MB)   -> bufA (dies at k_bincsr; bufA next written by mm2)
    //  x1s_bf (N*32 u32 = 12.8MB)-> bufA (mm1 -> gather2; mm2 writes bufA after)
    //  t3s_bf (N*32 u32 = 12.8MB)-> bufB (bufB dead after mm2 reads it; mm3 writes,
    //                               gather3 reads; gather3 writes bufA)
    unsigned* pairs  = (unsigned*)bufA;
    unsigned* x1s_bf = (unsigned*)bufA;
    unsigned* t3s_bf = (unsigned*)bufB;

    const int nblk = (N_ + THREADS - 1) / THREADS;
    const int mblk = (N_ + 63) / 64;                                // 64 rows/block
    const int gblk = ((size_t)N_ * 64 + THREADS - 1) / THREADS;     // wave/node

    // ---- zero accumulated buffers (fresh every call) ----
    hipMemsetAsync(sums, 0, (size_t)ngr * 64 * 4, stream);
    hipMemsetAsync(cnts, 0, (size_t)ngr * 4, stream);

    // ---- CSR build (atomic-free partition) ----
    k_partcnt<<<ablk, THREADS, (size_t)NB * 4, stream>>>(e_dst, counts, ablk, NB, E_);
    k_scanrows<<<NB, THREADS, 0, stream>>>(counts, bintot, ablk);
    k_binscan<<<1, 128, 0, stream>>>(bintot, binptr, NB, E_);
    k_partwrite<<<ablk, THREADS, (size_t)NB * 8, stream>>>(e_src, e_dst, binptr, counts, ablk, pairs, NB, E_);
    k_bincsr<<<NB, THREADS, 0, stream>>>(pairs, binptr, rowptr, dinv, srcs, N_, NB, E_);

    // ---- embeddings -> xb [N,32] bf16 (pre-scaled by dinv) ----
    k_embed<6><<<((size_t)n_ev  * 16 + THREADS - 1) / THREADS, THREADS, 0, stream>>>(ev_f,  W_ev,  b_ev,  ev_i,  dinv, n_ev,  xb);
    k_embed<4><<<((size_t)n_cs  * 16 + THREADS - 1) / THREADS, THREADS, 0, stream>>>(cs_f,  W_cs,  b_cs,  cs_i,  dinv, n_cs,  xb);
    k_embed<2><<<((size_t)n_tr  * 16 + THREADS - 1) / THREADS, THREADS, 0, stream>>>(tr_f,  W_tr,  b_tr,  tr_i,  dinv, n_tr,  xb);
    k_embed<5><<<((size_t)n_env * 16 + THREADS - 1) / THREADS, THREADS, 0, stream>>>(env_f, W_env, b_env, env_i, dinv, n_env, xb);

    // ---- conv1: agg(xb) -> bufB f32; mm1: x1b = bf16(x1), x1s_bf = bf16(dinv*relu(x1)) ----
    k_gather32<<<gblk, THREADS, 0, stream>>>(xb, rowptr, srcs, dinv, bufB, N_);
    k_mmt<32, 64, true, false, 1><<<mblk, THREADS, 0, stream>>>(
        bufB, W1, b1, dinv, nullptr, x1b, x1s_bf, N_);

    // ---- conv2: agg(x1s_bf) -> bufB; mm2: relu(bufB @ W2 + b2) -> bufA [N,128] ----
    k_gather64<false, false, false><<<gblk, THREADS, 0, stream>>>(
        x1s_bf, rowptr, srcs, dinv, nullptr, nullptr, bufB, N_);
    k_mmt<64, 128, true, true, 0><<<mblk, THREADS, 0, stream>>>(
        bufB, W2, b2, nullptr, bufA, nullptr, nullptr, N_);

    // ---- conv3: mm3: t3s_bf = bf16(dinv*(bufA @ W3)); gather3: relu(agg+b3)+x1b -> bufA ----
    k_mmt<128, 64, false, false, 2><<<mblk, THREADS, 0, stream>>>(
        bufA, W3, nullptr, dinv, nullptr, t3s_bf, nullptr, N_);
    k_gather64<true, true, true><<<gblk, THREADS, 0, stream>>>(
        t3s_bf, rowptr, srcs, dinv, b3, x1b, bufA, N_);

    // ---- pool ----
    k_pool<<<nblk, THREADS, 0, stream>>>(bufA, batch, sums, cnts, N_);
    k_div<<<(out_size + THREADS - 1) / THREADS, THREADS, 0, stream>>>(sums, cnts, (float*)d_out, out_size);
}

// Round 9
// 567.573 us; speedup vs baseline: 1.0769x; 1.0769x over previous
//
#include <hip/hip_runtime.h>
#include <hip/hip_bf16.h>

// ---------------------------------------------------------------------------
// GNN Residual Feature Extractor
//   x = embed(type features)                       [N,32]
//   x1 = gcn(x, W1)+b1                             [N,64]
//   h  = relu(gcn(relu(x1),W2)+b2)                 [N,128]
//   h  = relu(gcn(h,W3)+b3) + x1                   [N,64]
//   out = segment_mean(h, batch)                   [100,64]
//
// gcn agg commutes with weight multiply; aggregate on narrow side.
// ALL N-wide intermediates are packed bf16 (u32 pairs); f32 accumulation.
// Gather tables pre-scaled by dinv / pre-activated by producers.
//
// CSR build: atomic-free two-pass radix partition (bin = dst>>10), pairs
// packed into one u32 (src<<10 | dst&1023). (R4-validated.)
//
// k_mm: R6-proven structure — thread-per-row, row in registers (bf16 u32s,
// half the VGPRs of f32), W/bias via blockIdx.y-uniform SCALAR loads, no LDS.
// R7 lesson: threadIdx-derived column base kills s_load. R8 lesson: LDS
// float4 tiles conflict 4-8-way and the unrolled variant hits VGPR 144.
// ---------------------------------------------------------------------------

#define THREADS 256
#define BINSHIFT 10
#define EPBA 4096        // edges per partition block
#define SCANCH 8         // k_scanrows: values per thread (supports <=2048 blocks)

// ---------------- bf16 helpers ----------------
__device__ __forceinline__ unsigned bfpack2(float lo, float hi) {
    unsigned ul = __float_as_uint(lo);
    unsigned uh = __float_as_uint(hi);
    ul = (ul + 0x7fffu + ((ul >> 16) & 1u)) >> 16;          // rne, low half
    uh = (uh + 0x7fffu + ((uh >> 16) & 1u)) & 0xffff0000u;  // rne, high half
    return ul | uh;
}

__device__ __forceinline__ void bfacc(uint2 v, float& a0, float& a1,
                                      float& a2, float& a3) {
    a0 += __uint_as_float(v.x << 16);
    a1 += __uint_as_float(v.x & 0xffff0000u);
    a2 += __uint_as_float(v.y << 16);
    a3 += __uint_as_float(v.y & 0xffff0000u);
}

// ---------------- pass 1: per-(block,bin) exact counts ----------------
__global__ __launch_bounds__(THREADS)
void k_partcnt(const int* __restrict__ dst, int* __restrict__ counts,
               int nblk_part, int nb, int e) {
    extern __shared__ int h[];
    int t = threadIdx.x;
    for (int i = t; i < nb; i += THREADS) h[i] = 0;
    __syncthreads();
    int lo = blockIdx.x * EPBA;
    int hi = min(lo + EPBA, e);
    for (int i = lo + t; i < hi; i += THREADS)
        atomicAdd(&h[dst[i] >> BINSHIFT], 1);
    __syncthreads();
    for (int i = t; i < nb; i += THREADS)
        counts[(size_t)i * nblk_part + blockIdx.x] = h[i];
}

// ---------------- scan each bin's row of per-block counts ----------------
__global__ __launch_bounds__(THREADS)
void k_scanrows(int* __restrict__ counts, int* __restrict__ bintot, int nblk_part) {
    __shared__ int wsum[THREADS];
    int* row = counts + (size_t)blockIdx.x * nblk_part;
    int t = threadIdx.x;
    int base = t * SCANCH;
    int v[SCANCH];
    int s = 0;
#pragma unroll
    for (int k = 0; k < SCANCH; ++k) {
        v[k] = (base + k < nblk_part) ? row[base + k] : 0;
        s += v[k];
    }
    wsum[t] = s;
    __syncthreads();
    for (int off = 1; off < THREADS; off <<= 1) {
        int a = (t >= off) ? wsum[t - off] : 0;
        __syncthreads();
        wsum[t] += a;
        __syncthreads();
    }
    int run = wsum[t] - s;  // exclusive
#pragma unroll
    for (int k = 0; k < SCANCH; ++k) {
        int c = v[k];
        if (base + k < nblk_part) row[base + k] = run;
        run += c;
    }
    if (t == THREADS - 1) bintot[blockIdx.x] = run;
}

// ---------------- scan bin totals (single block, nb<=128) ----------------
__global__ __launch_bounds__(128)
void k_binscan(const int* __restrict__ bintot, int* __restrict__ binptr,
               int nb, int e) {
    __shared__ int lds[128];
    int t = threadIdx.x;
    int v = (t < nb) ? bintot[t] : 0;
    lds[t] = v;
    __syncthreads();
    for (int off = 1; off < 128; off <<= 1) {
        int a = (t >= off) ? lds[t - off] : 0;
        __syncthreads();
        lds[t] += a;
        __syncthreads();
    }
    if (t < nb) binptr[t] = lds[t] - v;  // exclusive
    if (t == 0) binptr[nb] = e;
}

// ---------------- pass 2: deterministic partition write (packed u32) --------
__global__ __launch_bounds__(THREADS)
void k_partwrite(const int* __restrict__ src, const int* __restrict__ dst,
                 const int* __restrict__ binptr, const int* __restrict__ counts,
                 int nblk_part, unsigned* __restrict__ pairs, int nb, int e) {
    extern __shared__ int smem[];
    int* base = smem;       // nb
    int* cnt  = smem + nb;  // nb
    int t = threadIdx.x;
    for (int i = t; i < nb; i += THREADS) {
        base[i] = binptr[i] + counts[(size_t)i * nblk_part + blockIdx.x];
        cnt[i] = 0;
    }
    __syncthreads();
    int lo = blockIdx.x * EPBA;
    int hi = min(lo + EPBA, e);
    for (int i = lo + t; i < hi; i += THREADS) {
        int s = src[i], d = dst[i];
        int b = d >> BINSHIFT;
        int pos = atomicAdd(&cnt[b], 1);   // LDS only
        pairs[base[b] + pos] = ((unsigned)s << BINSHIFT) | (unsigned)(d & ((1 << BINSHIFT) - 1));
    }
}

// ---------------- per-bin CSR finalize ----------------
__global__ __launch_bounds__(THREADS)
void k_bincsr(const unsigned* __restrict__ pairs, const int* __restrict__ binptr,
              int* __restrict__ rowptr, float* __restrict__ dinv,
              int* __restrict__ srcs, int n, int nb, int e) {
    __shared__ int lcnt[1024];
    __shared__ int lofs[1024];
    __shared__ int wsum[THREADS];
    int b = blockIdx.x, t = threadIdx.x;
    int e0 = binptr[b], e1 = binptr[b + 1];
    int n0 = b << BINSHIFT;
    for (int i = t; i < 1024; i += THREADS) lcnt[i] = 0;
    __syncthreads();
    for (int j = e0 + t; j < e1; j += THREADS)
        atomicAdd(&lcnt[pairs[j] & 1023u], 1);
    __syncthreads();
    int c0 = lcnt[4 * t + 0], c1 = lcnt[4 * t + 1];
    int c2 = lcnt[4 * t + 2], c3 = lcnt[4 * t + 3];
    int s = c0 + c1 + c2 + c3;
    wsum[t] = s;
    __syncthreads();
    for (int off = 1; off < THREADS; off <<= 1) {
        int a = (t >= off) ? wsum[t - off] : 0;
        __syncthreads();
        wsum[t] += a;
        __syncthreads();
    }
    int excl = wsum[t] - s;
    lofs[4 * t + 0] = excl;
    lofs[4 * t + 1] = excl + c0;
    lofs[4 * t + 2] = excl + c0 + c1;
    lofs[4 * t + 3] = excl + c0 + c1 + c2;
    __syncthreads();
    for (int i = t; i < 1024; i += THREADS) {
        int node = n0 + i;
        if (node < n) {
            rowptr[node] = e0 + lofs[i];
            dinv[node] = rsqrtf((float)lcnt[i] + 1.0f);
        }
    }
    if (b == nb - 1 && t == 0) rowptr[n] = e;
    __syncthreads();
    for (int j = e0 + t; j < e1; j += THREADS) {
        unsigned pp = pairs[j];
        int pos = e0 + atomicAdd(&lofs[pp & 1023u], 1);
        srcs[pos] = (int)(pp >> BINSHIFT);
    }
}

// ---------------- embedding: xb[idx[r]] = bf16(dinv * (f[r] @ W + b)) --------
template <int K>
__global__ __launch_bounds__(THREADS)
void k_embed(const float* __restrict__ f, const float* __restrict__ W,
             const float* __restrict__ b, const int* __restrict__ idx,
             const float* __restrict__ dinv, int rows, unsigned* __restrict__ xb) {
    int g = blockIdx.x * THREADS + threadIdx.x;
    int r = g >> 4, cp = g & 15;
    if (r >= rows) return;
    int node = idx[r];
    float dv = dinv[node];
    float a0 = b[2 * cp], a1 = b[2 * cp + 1];
#pragma unroll
    for (int k = 0; k < K; ++k) {
        float fv = f[r * K + k];
        a0 += fv * W[k * 32 + 2 * cp];
        a1 += fv * W[k * 32 + 2 * cp + 1];
    }
    xb[(size_t)node * 16 + cp] = bfpack2(dv * a0, dv * a1);
}

// ---------------- gather (bf16 table, row=128B): one wave per node ----------
// 4 quarter-groups of 16 lanes; each quarter owns one edge's full row.
// out[i] = dv_i * (tbl[i] + sum_s tbl[s])  [+bias][relu][+resid(bf16)].
// OUTBF: write packed bf16 (uint2/lane); else f32 float4/lane.
template <bool HASBIAS, bool OUTRELU, bool HASRES, bool OUTBF>
__global__ __launch_bounds__(THREADS)
void k_gather64(const unsigned* __restrict__ tblb, const int* __restrict__ rowptr,
                const int* __restrict__ srcs, const float* __restrict__ dinv,
                const float* __restrict__ bias, const unsigned* __restrict__ resid,
                void* __restrict__ outp, int n) {
    int gt = blockIdx.x * THREADS + threadIdx.x;
    int node = gt >> 6;
    int lane = threadIdx.x & 63;
    if (node >= n) return;
    int qw = lane >> 4, li = lane & 15;
    const uint2* t2 = reinterpret_cast<const uint2*>(tblb);
    float a0 = 0.f, a1 = 0.f, a2 = 0.f, a3 = 0.f;
    int beg = rowptr[node], end = rowptr[node + 1];
    int j = beg;
    for (; j + 16 <= end; j += 16) {          // 16 edges, 4 rows in flight
        int i0 = srcs[j + qw];
        int i1 = srcs[j + 4 + qw];
        int i2 = srcs[j + 8 + qw];
        int i3 = srcs[j + 12 + qw];
        uint2 v0 = t2[(size_t)i0 * 16 + li];
        uint2 v1 = t2[(size_t)i1 * 16 + li];
        uint2 v2 = t2[(size_t)i2 * 16 + li];
        uint2 v3 = t2[(size_t)i3 * 16 + li];
        bfacc(v0, a0, a1, a2, a3);
        bfacc(v1, a0, a1, a2, a3);
        bfacc(v2, a0, a1, a2, a3);
        bfacc(v3, a0, a1, a2, a3);
    }
    for (; j + 8 <= end; j += 8) {
        int i0 = srcs[j + qw];
        int i1 = srcs[j + 4 + qw];
        uint2 v0 = t2[(size_t)i0 * 16 + li];
        uint2 v1 = t2[(size_t)i1 * 16 + li];
        bfacc(v0, a0, a1, a2, a3);
        bfacc(v1, a0, a1, a2, a3);
    }
    int rem = end - j;
    if (qw < rem) {
        uint2 v = t2[(size_t)srcs[j + qw] * 16 + li];
        bfacc(v, a0, a1, a2, a3);
    }
    if (qw + 4 < rem) {
        uint2 v = t2[(size_t)srcs[j + 4 + qw] * 16 + li];
        bfacc(v, a0, a1, a2, a3);
    }
    a0 += __shfl_down(a0, 32, 64); a1 += __shfl_down(a1, 32, 64);
    a2 += __shfl_down(a2, 32, 64); a3 += __shfl_down(a3, 32, 64);
    a0 += __shfl_down(a0, 16, 64); a1 += __shfl_down(a1, 16, 64);
    a2 += __shfl_down(a2, 16, 64); a3 += __shfl_down(a3, 16, 64);
    if (lane < 16) {
        uint2 sv = t2[(size_t)node * 16 + li];
        bfacc(sv, a0, a1, a2, a3);
        float dv = dinv[node];
        float r0 = dv * a0, r1 = dv * a1, r2 = dv * a2, r3 = dv * a3;
        if (HASBIAS) {
            float4 bv = *reinterpret_cast<const float4*>(bias + 4 * li);
            r0 += bv.x; r1 += bv.y; r2 += bv.z; r3 += bv.w;
        }
        if (OUTRELU) {
            r0 = fmaxf(r0, 0.f); r1 = fmaxf(r1, 0.f);
            r2 = fmaxf(r2, 0.f); r3 = fmaxf(r3, 0.f);
        }
        if (HASRES) {
            uint2 rv = reinterpret_cast<const uint2*>(resid)[(size_t)node * 16 + li];
            bfacc(rv, r0, r1, r2, r3);
        }
        if (OUTBF) {
            uint2 o = {bfpack2(r0, r1), bfpack2(r2, r3)};
            reinterpret_cast<uint2*>(outp)[(size_t)node * 16 + li] = o;
        } else {
            float4 o = {r0, r1, r2, r3};
            reinterpret_cast<float4*>(outp)[(size_t)node * 16 + li] = o;
        }
    }
}

// ---------------- gather (bf16 table, row=64B): 8 groups of 8 lanes ---------
// bf16 packed output (feeds mm1).
__global__ __launch_bounds__(THREADS)
void k_gather32(const unsigned* __restrict__ tblb, const int* __restrict__ rowptr,
                const int* __restrict__ srcs, const float* __restrict__ dinv,
                unsigned* __restrict__ outb, int n) {
    int gt = blockIdx.x * THREADS + threadIdx.x;
    int node = gt >> 6;
    int lane = threadIdx.x & 63;
    if (node >= n) return;
    int og = lane >> 3, li = lane & 7;
    const uint2* t2 = reinterpret_cast<const uint2*>(tblb);
    float a0 = 0.f, a1 = 0.f, a2 = 0.f, a3 = 0.f;
    int beg = rowptr[node], end = rowptr[node + 1];
    int j = beg;
    for (; j + 16 <= end; j += 16) {          // 16 edges, 2 rows in flight/lane
        int i0 = srcs[j + og];
        int i1 = srcs[j + 8 + og];
        uint2 v0 = t2[(size_t)i0 * 8 + li];
        uint2 v1 = t2[(size_t)i1 * 8 + li];
        bfacc(v0, a0, a1, a2, a3);
        bfacc(v1, a0, a1, a2, a3);
    }
    for (; j + 8 <= end; j += 8) {
        int i0 = srcs[j + og];
        uint2 v0 = t2[(size_t)i0 * 8 + li];
        bfacc(v0, a0, a1, a2, a3);
    }
    int rem = end - j;
    if (og < rem) {
        uint2 v = t2[(size_t)srcs[j + og] * 8 + li];
        bfacc(v, a0, a1, a2, a3);
    }
    a0 += __shfl_down(a0, 32, 64); a1 += __shfl_down(a1, 32, 64);
    a2 += __shfl_down(a2, 32, 64); a3 += __shfl_down(a3, 32, 64);
    a0 += __shfl_down(a0, 16, 64); a1 += __shfl_down(a1, 16, 64);
    a2 += __shfl_down(a2, 16, 64); a3 += __shfl_down(a3, 16, 64);
    a0 += __shfl_down(a0, 8, 64);  a1 += __shfl_down(a1, 8, 64);
    a2 += __shfl_down(a2, 8, 64);  a3 += __shfl_down(a3, 8, 64);
    if (lane < 8) {
        uint2 sv = t2[(size_t)node * 8 + li];
        bfacc(sv, a0, a1, a2, a3);
        float dv = dinv[node];
        uint2 o = {bfpack2(dv * a0, dv * a1), bfpack2(dv * a2, dv * a3)};
        reinterpret_cast<uint2*>(outb)[(size_t)node * 8 + li] = o;
    }
}

// ---------------- dense matmul (bf16-packed input rows) ----------------------
// out[N,FOUT] = unpack(xinb)[N,FIN] @ W + b. Thread-per-row; row held as
// FIN/2 u32 regs; W/bias via blockIdx.y-UNIFORM scalar loads (no LDS).
// EXTRA: 1 = outb=bf16(acc), outb2=bf16(dinv*relu(acc))   [mm1]
//        2 = outb=bf16(dinv*acc)                           [mm3]
//        3 = outb=bf16(acc after relu)                      [mm2]
template <int FIN, int FOUT, int CPB, bool HASBIAS, bool OUTRELU, int EXTRA>
__global__ __launch_bounds__(THREADS)
void k_mm(const unsigned* __restrict__ xinb, const float* __restrict__ W,
          const float* __restrict__ bias, const float* __restrict__ dinv,
          unsigned* __restrict__ outb, unsigned* __restrict__ outb2, int nrows) {
    constexpr int FH = FIN / 2;       // u32 per row
    int row = blockIdx.x * THREADS + threadIdx.x;
    if (row >= nrows) return;
    int cbase = blockIdx.y * CPB;

    unsigned xr[FH];
    const uint4* xr4 = reinterpret_cast<const uint4*>(xinb + (size_t)row * FH);
#pragma unroll
    for (int q = 0; q < FH / 4; ++q) {
        uint4 v = xr4[q];
        xr[4 * q + 0] = v.x; xr[4 * q + 1] = v.y;
        xr[4 * q + 2] = v.z; xr[4 * q + 3] = v.w;
    }
    float dv = (EXTRA != 3) ? dinv[row] : 0.f;

#pragma unroll 1
    for (int cc = 0; cc < CPB; cc += 8) {
        int c0 = cbase + cc;
        float a[8];
#pragma unroll
        for (int i = 0; i < 8; ++i) a[i] = HASBIAS ? bias[c0 + i] : 0.f;
#pragma unroll
        for (int q = 0; q < FIN / 4; ++q) {   // 4 k-values from 2 u32
            unsigned p0 = xr[2 * q], p1 = xr[2 * q + 1];
            float x0 = __uint_as_float(p0 << 16);
            float x1 = __uint_as_float(p0 & 0xffff0000u);
            float x2 = __uint_as_float(p1 << 16);
            float x3 = __uint_as_float(p1 & 0xffff0000u);
            const float* w0 = W + (size_t)(4 * q + 0) * FOUT + c0;
            const float* w1 = W + (size_t)(4 * q + 1) * FOUT + c0;
            const float* w2 = W + (size_t)(4 * q + 2) * FOUT + c0;
            const float* w3 = W + (size_t)(4 * q + 3) * FOUT + c0;
#pragma unroll
            for (int i = 0; i < 8; ++i) {
                a[i] = fmaf(x0, w0[i], a[i]);
                a[i] = fmaf(x1, w1[i], a[i]);
                a[i] = fmaf(x2, w2[i], a[i]);
                a[i] = fmaf(x3, w3[i], a[i]);
            }
        }
        if (OUTRELU) {
#pragma unroll
            for (int i = 0; i < 8; ++i) a[i] = fmaxf(a[i], 0.f);
        }
        int cb = c0;
        if (EXTRA == 1) {
            uint4 b4 = {bfpack2(a[0], a[1]), bfpack2(a[2], a[3]),
                        bfpack2(a[4], a[5]), bfpack2(a[6], a[7])};
            uint4 s4 = {bfpack2(dv * fmaxf(a[0], 0.f), dv * fmaxf(a[1], 0.f)),
                        bfpack2(dv * fmaxf(a[2], 0.f), dv * fmaxf(a[3], 0.f)),
                        bfpack2(dv * fmaxf(a[4], 0.f), dv * fmaxf(a[5], 0.f)),
                        bfpack2(dv * fmaxf(a[6], 0.f), dv * fmaxf(a[7], 0.f))};
            *reinterpret_cast<uint4*>(outb + (size_t)row * (FOUT / 2) + cb / 2) = b4;
            *reinterpret_cast<uint4*>(outb2 + (size_t)row * (FOUT / 2) + cb / 2) = s4;
        }
        if (EXTRA == 2) {
            uint4 b4 = {bfpack2(dv * a[0], dv * a[1]), bfpack2(dv * a[2], dv * a[3]),
                        bfpack2(dv * a[4], dv * a[5]), bfpack2(dv * a[6], dv * a[7])};
            *reinterpret_cast<uint4*>(outb + (size_t)row * (FOUT / 2) + cb / 2) = b4;
        }
        if (EXTRA == 3) {
            uint4 b4 = {bfpack2(a[0], a[1]), bfpack2(a[2], a[3]),
                        bfpack2(a[4], a[5]), bfpack2(a[6], a[7])};
            *reinterpret_cast<uint4*>(outb + (size_t)row * (FOUT / 2) + cb / 2) = b4;
        }
    }
}

// ---------------- segment mean pool ----------------
__global__ __launch_bounds__(THREADS)
void k_pool(const float* __restrict__ h, const int* __restrict__ batch,
            float* __restrict__ sums, float* __restrict__ cnts, int n) {
    int c = threadIdx.x & 63;
    int rq = threadIdx.x >> 6;  // 0..3
    int r0 = blockIdx.x * THREADS;
    int rend = min(r0 + THREADS, n);
    int curg = -1;
    float acc = 0.f, cacc = 0.f;
    for (int r = r0 + rq; r < rend; r += 4) {
        int g = batch[r];
        if (g != curg) {
            if (curg >= 0) {
                atomicAdd(&sums[(size_t)curg * 64 + c], acc);
                if (c == 0) atomicAdd(&cnts[curg], cacc);
            }
            curg = g; acc = 0.f; cacc = 0.f;
        }
        acc += h[(size_t)r * 64 + c];
        cacc += 1.f;
    }
    if (curg >= 0) {
        atomicAdd(&sums[(size_t)curg * 64 + c], acc);
        if (c == 0) atomicAdd(&cnts[curg], cacc);
    }
}

__global__ __launch_bounds__(THREADS)
void k_div(const float* __restrict__ sums, const float* __restrict__ cnts,
           float* __restrict__ out, int total) {
    int i = blockIdx.x * THREADS + threadIdx.x;
    if (i < total) out[i] = sums[i] / cnts[i >> 6];
}

// ---------------------------------------------------------------------------
static inline size_t alignup(size_t v) { return (v + 255) & ~(size_t)255; }

extern "C" void kernel_launch(void* const* d_in, const int* in_sizes, int n_in,
                              void* d_out, int out_size, void* d_ws, size_t ws_size,
                              hipStream_t stream) {
    const float* ev_f  = (const float*)d_in[0];
    const float* cs_f  = (const float*)d_in[1];
    const float* tr_f  = (const float*)d_in[2];
    const float* env_f = (const float*)d_in[3];
    const int*   ei    = (const int*)d_in[4];
    const int*   ev_i  = (const int*)d_in[5];
    const int*   cs_i  = (const int*)d_in[6];
    const int*   tr_i  = (const int*)d_in[7];
    const int*   env_i = (const int*)d_in[8];
    const int*   batch = (const int*)d_in[9];
    const float* W_ev = (const float*)d_in[10]; const float* b_ev = (const float*)d_in[11];
    const float* W_cs = (const float*)d_in[12]; const float* b_cs = (const float*)d_in[13];
    const float* W_tr = (const float*)d_in[14]; const float* b_tr = (const float*)d_in[15];
    const float* W_env= (const float*)d_in[16]; const float* b_env= (const float*)d_in[17];
    const float* W1 = (const float*)d_in[18]; const float* b1 = (const float*)d_in[19];
    const float* W2 = (const float*)d_in[20]; const float* b2 = (const float*)d_in[21];
    const float* W3 = (const float*)d_in[22]; const float* b3 = (const float*)d_in[23];

    const int E_ = in_sizes[4] / 2;
    const int N_ = in_sizes[9];
    const int n_ev  = in_sizes[5];
    const int n_cs  = in_sizes[6];
    const int n_tr  = in_sizes[7];
    const int n_env = in_sizes[8];
    const int ngr   = out_size / 64;  // 100 graphs

    const int* e_src = ei;
    const int* e_dst = ei + E_;

    const int NB   = (N_ + (1 << BINSHIFT) - 1) >> BINSHIFT;  // 98 bins
    const int ablk = (E_ + EPBA - 1) / EPBA;                  // 782 partition blocks

    // ---- workspace carve-up ----
    char* p = (char*)d_ws;
    int*      counts = (int*)p;      p += alignup((size_t)NB * ablk * 4);
    int*      bintot = (int*)p;      p += alignup((size_t)NB * 4);
    int*      binptr = (int*)p;      p += alignup(((size_t)NB + 1) * 4);
    int*      rowptr = (int*)p;      p += alignup(((size_t)N_ + 1) * 4);
    float*    dinv   = (float*)p;    p += alignup((size_t)N_ * 4);
    int*      srcs   = (int*)p;      p += alignup((size_t)E_ * 4);
    unsigned* xb     = (unsigned*)p; p += alignup((size_t)N_ * 16 * 4);   // bf16 [N,32]
    unsigned* x1b    = (unsigned*)p; p += alignup((size_t)N_ * 32 * 4);   // bf16 [N,64] raw x1
    unsigned* x1s_bf = (unsigned*)p; p += alignup((size_t)N_ * 32 * 4);   // bf16 conv2 table
    unsigned* aggb   = (unsigned*)p; p += alignup((size_t)N_ * 32 * 4);   // bf16 gather out
    unsigned* hA     = (unsigned*)p; p += alignup((size_t)N_ * 64 * 4);   // bf16 [N,128] mm2 out
    unsigned* t3s_bf = (unsigned*)p; p += alignup((size_t)N_ * 32 * 4);   // bf16 conv3 table
    float*    hfin   = (float*)p;    p += alignup((size_t)N_ * 64 * 4);   // f32 pool input
    float*    sums   = (float*)p;    p += alignup((size_t)ngr * 64 * 4);
    float*    cnts   = (float*)p;    p += alignup((size_t)ngr * 4);

    // pairs (E u32 = 12.8MB) aliases hA (25.6MB): dead at k_bincsr, hA first
    // written by mm2 (after bincsr).
    unsigned* pairs = hA;

    const int nblk = (N_ + THREADS - 1) / THREADS;
    const int gblk = ((size_t)N_ * 64 + THREADS - 1) / THREADS;     // wave/node

    // ---- zero accumulated buffers (fresh every call) ----
    hipMemsetAsync(sums, 0, (size_t)ngr * 64 * 4, stream);
    hipMemsetAsync(cnts, 0, (size_t)ngr * 4, stream);

    // ---- CSR build (atomic-free partition) ----
    k_partcnt<<<ablk, THREADS, (size_t)NB * 4, stream>>>(e_dst, counts, ablk, NB, E_);
    k_scanrows<<<NB, THREADS, 0, stream>>>(counts, bintot, ablk);
    k_binscan<<<1, 128, 0, stream>>>(bintot, binptr, NB, E_);
    k_partwrite<<<ablk, THREADS, (size_t)NB * 8, stream>>>(e_src, e_dst, binptr, counts, ablk, pairs, NB, E_);
    k_bincsr<<<NB, THREADS, 0, stream>>>(pairs, binptr, rowptr, dinv, srcs, N_, NB, E_);

    // ---- embeddings -> xb [N,32] bf16 (pre-scaled by dinv) ----
    k_embed<6><<<((size_t)n_ev  * 16 + THREADS - 1) / THREADS, THREADS, 0, stream>>>(ev_f,  W_ev,  b_ev,  ev_i,  dinv, n_ev,  xb);
    k_embed<4><<<((size_t)n_cs  * 16 + THREADS - 1) / THREADS, THREADS, 0, stream>>>(cs_f,  W_cs,  b_cs,  cs_i,  dinv, n_cs,  xb);
    k_embed<2><<<((size_t)n_tr  * 16 + THREADS - 1) / THREADS, THREADS, 0, stream>>>(tr_f,  W_tr,  b_tr,  tr_i,  dinv, n_tr,  xb);
    k_embed<5><<<((size_t)n_env * 16 + THREADS - 1) / THREADS, THREADS, 0, stream>>>(env_f, W_env, b_env, env_i, dinv, n_env, xb);

    // ---- conv1: agg(xb) -> aggb bf16; mm1: x1b=bf16(x1), x1s_bf=bf16(dinv*relu(x1)) ----
    k_gather32<<<gblk, THREADS, 0, stream>>>(xb, rowptr, srcs, dinv, aggb, N_);
    k_mm<32, 64, 16, true, false, 1><<<dim3(nblk, 4), THREADS, 0, stream>>>(
        aggb, W1, b1, dinv, x1b, x1s_bf, N_);

    // ---- conv2: agg(x1s_bf) -> aggb bf16; mm2: relu(@W2+b2) -> hA bf16 [N,128] ----
    k_gather64<false, false, false, true><<<gblk, THREADS, 0, stream>>>(
        x1s_bf, rowptr, srcs, dinv, nullptr, nullptr, aggb, N_);
    k_mm<64, 128, 32, true, true, 3><<<dim3(nblk, 4), THREADS, 0, stream>>>(
        aggb, W2, b2, nullptr, hA, nullptr, N_);

    // ---- conv3: mm3: t3s_bf = bf16(dinv*(hA @ W3)); gather3: relu(agg+b3)+x1b -> hfin ----
    k_mm<128, 64, 16, false, false, 2><<<dim3(nblk, 4), THREADS, 0, stream>>>(
        hA, W3, nullptr, dinv, t3s_bf, nullptr, N_);
    k_gather64<true, true, true, false><<<gblk, THREADS, 0, stream>>>(
        t3s_bf, rowptr, srcs, dinv, b3, x1b, hfin, N_);

    // ---- pool ----
    k_pool<<<nblk, THREADS, 0, stream>>>(hfin, batch, sums, cnts, N_);
    k_div<<<(out_size + THREADS - 1) / THREADS, THREADS, 0, stream>>>(sums, cnts, (float*)d_out, out_size);
}

// Round 10
// 397.662 us; speedup vs baseline: 1.5371x; 1.4273x over previous
//
#include <hip/hip_runtime.h>
#include <hip/hip_bf16.h>

// ---------------------------------------------------------------------------
// GNN Residual Feature Extractor
//   x = embed(type features)                       [N,32]
//   x1 = gcn(x, W1)+b1                             [N,64]
//   h  = relu(gcn(relu(x1),W2)+b2)                 [N,128]
//   h  = relu(gcn(h,W3)+b3) + x1                   [N,64]
//   out = segment_mean(h, batch)                   [100,64]
//
// gcn agg commutes with weight multiply; aggregate on narrow side.
// ALL N-wide intermediates are packed bf16; f32 accumulation.
// Gather tables pre-scaled by dinv / pre-activated by producers.
//
// CSR build: atomic-free two-pass radix partition (bin = dst>>10).
//
// R10: mm via MFMA (mfma_f32_16x16x32_bf16), swapped operands
// (A = bf16 W^T tiles, B = node rows) so lane output is [node][4 cols]
// -> uint2 packed-bf16 writes. R6-R9 showed every VALU mm variant is
// latency-bound (VGPR/occupancy or LDS conflicts); this is matmul-shaped
// compute -> matrix cores (16 rows/wave, K-loop FIN/32, VGPR ~70).
// ---------------------------------------------------------------------------

#define THREADS 256
#define BINSHIFT 10
#define EPBA 4096        // edges per partition block
#define SCANCH 8         // k_scanrows: values per thread

typedef __attribute__((ext_vector_type(8))) short short8;
typedef __attribute__((ext_vector_type(4))) float f32x4;

// ---------------- bf16 helpers ----------------
__device__ __forceinline__ unsigned bfpack2(float lo, float hi) {
    unsigned ul = __float_as_uint(lo);
    unsigned uh = __float_as_uint(hi);
    ul = (ul + 0x7fffu + ((ul >> 16) & 1u)) >> 16;          // rne, low half
    uh = (uh + 0x7fffu + ((uh >> 16) & 1u)) & 0xffff0000u;  // rne, high half
    return ul | uh;
}

__device__ __forceinline__ void bfacc(uint2 v, float& a0, float& a1,
                                      float& a2, float& a3) {
    a0 += __uint_as_float(v.x << 16);
    a1 += __uint_as_float(v.x & 0xffff0000u);
    a2 += __uint_as_float(v.y << 16);
    a3 += __uint_as_float(v.y & 0xffff0000u);
}

__device__ __forceinline__ short8 as_short8(uint4 u) {
    union { uint4 u; short8 s; } c; c.u = u; return c.s;
}

// ---------------- pass 1: per-(block,bin) exact counts ----------------
__global__ __launch_bounds__(THREADS)
void k_partcnt(const int* __restrict__ dst, int* __restrict__ counts,
               int nblk_part, int nb, int e) {
    extern __shared__ int h[];
    int t = threadIdx.x;
    for (int i = t; i < nb; i += THREADS) h[i] = 0;
    __syncthreads();
    int lo = blockIdx.x * EPBA;
    int hi = min(lo + EPBA, e);
    for (int i = lo + t; i < hi; i += THREADS)
        atomicAdd(&h[dst[i] >> BINSHIFT], 1);
    __syncthreads();
    for (int i = t; i < nb; i += THREADS)
        counts[(size_t)i * nblk_part + blockIdx.x] = h[i];
}

// ---------------- scan each bin's row of per-block counts ----------------
__global__ __launch_bounds__(THREADS)
void k_scanrows(int* __restrict__ counts, int* __restrict__ bintot, int nblk_part) {
    __shared__ int wsum[THREADS];
    int* row = counts + (size_t)blockIdx.x * nblk_part;
    int t = threadIdx.x;
    int base = t * SCANCH;
    int v[SCANCH];
    int s = 0;
#pragma unroll
    for (int k = 0; k < SCANCH; ++k) {
        v[k] = (base + k < nblk_part) ? row[base + k] : 0;
        s += v[k];
    }
    wsum[t] = s;
    __syncthreads();
    for (int off = 1; off < THREADS; off <<= 1) {
        int a = (t >= off) ? wsum[t - off] : 0;
        __syncthreads();
        wsum[t] += a;
        __syncthreads();
    }
    int run = wsum[t] - s;  // exclusive
#pragma unroll
    for (int k = 0; k < SCANCH; ++k) {
        int c = v[k];
        if (base + k < nblk_part) row[base + k] = run;
        run += c;
    }
    if (t == THREADS - 1) bintot[blockIdx.x] = run;
}

// ---------------- scan bin totals (single block, nb<=128) ----------------
__global__ __launch_bounds__(128)
void k_binscan(const int* __restrict__ bintot, int* __restrict__ binptr,
               int nb, int e) {
    __shared__ int lds[128];
    int t = threadIdx.x;
    int v = (t < nb) ? bintot[t] : 0;
    lds[t] = v;
    __syncthreads();
    for (int off = 1; off < 128; off <<= 1) {
        int a = (t >= off) ? lds[t - off] : 0;
        __syncthreads();
        lds[t] += a;
        __syncthreads();
    }
    if (t < nb) binptr[t] = lds[t] - v;  // exclusive
    if (t == 0) binptr[nb] = e;
}

// ---------------- pass 2: deterministic partition write (packed u32) --------
__global__ __launch_bounds__(THREADS)
void k_partwrite(const int* __restrict__ src, const int* __restrict__ dst,
                 const int* __restrict__ binptr, const int* __restrict__ counts,
                 int nblk_part, unsigned* __restrict__ pairs, int nb, int e) {
    extern __shared__ int smem[];
    int* base = smem;       // nb
    int* cnt  = smem + nb;  // nb
    int t = threadIdx.x;
    for (int i = t; i < nb; i += THREADS) {
        base[i] = binptr[i] + counts[(size_t)i * nblk_part + blockIdx.x];
        cnt[i] = 0;
    }
    __syncthreads();
    int lo = blockIdx.x * EPBA;
    int hi = min(lo + EPBA, e);
    for (int i = lo + t; i < hi; i += THREADS) {
        int s = src[i], d = dst[i];
        int b = d >> BINSHIFT;
        int pos = atomicAdd(&cnt[b], 1);   // LDS only
        pairs[base[b] + pos] = ((unsigned)s << BINSHIFT) | (unsigned)(d & ((1 << BINSHIFT) - 1));
    }
}

// ---------------- per-bin CSR finalize ----------------
__global__ __launch_bounds__(THREADS)
void k_bincsr(const unsigned* __restrict__ pairs, const int* __restrict__ binptr,
              int* __restrict__ rowptr, float* __restrict__ dinv,
              int* __restrict__ srcs, int n, int nb, int e) {
    __shared__ int lcnt[1024];
    __shared__ int lofs[1024];
    __shared__ int wsum[THREADS];
    int b = blockIdx.x, t = threadIdx.x;
    int e0 = binptr[b], e1 = binptr[b + 1];
    int n0 = b << BINSHIFT;
    for (int i = t; i < 1024; i += THREADS) lcnt[i] = 0;
    __syncthreads();
    for (int j = e0 + t; j < e1; j += THREADS)
        atomicAdd(&lcnt[pairs[j] & 1023u], 1);
    __syncthreads();
    int c0 = lcnt[4 * t + 0], c1 = lcnt[4 * t + 1];
    int c2 = lcnt[4 * t + 2], c3 = lcnt[4 * t + 3];
    int s = c0 + c1 + c2 + c3;
    wsum[t] = s;
    __syncthreads();
    for (int off = 1; off < THREADS; off <<= 1) {
        int a = (t >= off) ? wsum[t - off] : 0;
        __syncthreads();
        wsum[t] += a;
        __syncthreads();
    }
    int excl = wsum[t] - s;
    lofs[4 * t + 0] = excl;
    lofs[4 * t + 1] = excl + c0;
    lofs[4 * t + 2] = excl + c0 + c1;
    lofs[4 * t + 3] = excl + c0 + c1 + c2;
    __syncthreads();
    for (int i = t; i < 1024; i += THREADS) {
        int node = n0 + i;
        if (node < n) {
            rowptr[node] = e0 + lofs[i];
            dinv[node] = rsqrtf((float)lcnt[i] + 1.0f);
        }
    }
    if (b == nb - 1 && t == 0) rowptr[n] = e;
    __syncthreads();
    for (int j = e0 + t; j < e1; j += THREADS) {
        unsigned pp = pairs[j];
        int pos = e0 + atomicAdd(&lofs[pp & 1023u], 1);
        srcs[pos] = (int)(pp >> BINSHIFT);
    }
}

// ---------------- embedding: xb[idx[r]] = bf16(dinv * (f[r] @ W + b)) --------
template <int K>
__global__ __launch_bounds__(THREADS)
void k_embed(const float* __restrict__ f, const float* __restrict__ W,
             const float* __restrict__ b, const int* __restrict__ idx,
             const float* __restrict__ dinv, int rows, unsigned* __restrict__ xb) {
    int g = blockIdx.x * THREADS + threadIdx.x;
    int r = g >> 4, cp = g & 15;
    if (r >= rows) return;
    int node = idx[r];
    float dv = dinv[node];
    float a0 = b[2 * cp], a1 = b[2 * cp + 1];
#pragma unroll
    for (int k = 0; k < K; ++k) {
        float fv = f[r * K + k];
        a0 += fv * W[k * 32 + 2 * cp];
        a1 += fv * W[k * 32 + 2 * cp + 1];
    }
    xb[(size_t)node * 16 + cp] = bfpack2(dv * a0, dv * a1);
}

// ---------------- gather (bf16 table, row=128B): one wave per node ----------
template <bool HASBIAS, bool OUTRELU, bool HASRES, bool OUTBF>
__global__ __launch_bounds__(THREADS)
void k_gather64(const unsigned* __restrict__ tblb, const int* __restrict__ rowptr,
                const int* __restrict__ srcs, const float* __restrict__ dinv,
                const float* __restrict__ bias, const unsigned* __restrict__ resid,
                void* __restrict__ outp, int n) {
    int gt = blockIdx.x * THREADS + threadIdx.x;
    int node = gt >> 6;
    int lane = threadIdx.x & 63;
    if (node >= n) return;
    int qw = lane >> 4, li = lane & 15;
    const uint2* t2 = reinterpret_cast<const uint2*>(tblb);
    float a0 = 0.f, a1 = 0.f, a2 = 0.f, a3 = 0.f;
    int beg = rowptr[node], end = rowptr[node + 1];
    int j = beg;
    for (; j + 16 <= end; j += 16) {          // 16 edges, 4 rows in flight
        int i0 = srcs[j + qw];
        int i1 = srcs[j + 4 + qw];
        int i2 = srcs[j + 8 + qw];
        int i3 = srcs[j + 12 + qw];
        uint2 v0 = t2[(size_t)i0 * 16 + li];
        uint2 v1 = t2[(size_t)i1 * 16 + li];
        uint2 v2 = t2[(size_t)i2 * 16 + li];
        uint2 v3 = t2[(size_t)i3 * 16 + li];
        bfacc(v0, a0, a1, a2, a3);
        bfacc(v1, a0, a1, a2, a3);
        bfacc(v2, a0, a1, a2, a3);
        bfacc(v3, a0, a1, a2, a3);
    }
    for (; j + 8 <= end; j += 8) {
        int i0 = srcs[j + qw];
        int i1 = srcs[j + 4 + qw];
        uint2 v0 = t2[(size_t)i0 * 16 + li];
        uint2 v1 = t2[(size_t)i1 * 16 + li];
        bfacc(v0, a0, a1, a2, a3);
        bfacc(v1, a0, a1, a2, a3);
    }
    int rem = end - j;
    if (qw < rem) {
        uint2 v = t2[(size_t)srcs[j + qw] * 16 + li];
        bfacc(v, a0, a1, a2, a3);
    }
    if (qw + 4 < rem) {
        uint2 v = t2[(size_t)srcs[j + 4 + qw] * 16 + li];
        bfacc(v, a0, a1, a2, a3);
    }
    a0 += __shfl_down(a0, 32, 64); a1 += __shfl_down(a1, 32, 64);
    a2 += __shfl_down(a2, 32, 64); a3 += __shfl_down(a3, 32, 64);
    a0 += __shfl_down(a0, 16, 64); a1 += __shfl_down(a1, 16, 64);
    a2 += __shfl_down(a2, 16, 64); a3 += __shfl_down(a3, 16, 64);
    if (lane < 16) {
        uint2 sv = t2[(size_t)node * 16 + li];
        bfacc(sv, a0, a1, a2, a3);
        float dv = dinv[node];
        float r0 = dv * a0, r1 = dv * a1, r2 = dv * a2, r3 = dv * a3;
        if (HASBIAS) {
            float4 bv = *reinterpret_cast<const float4*>(bias + 4 * li);
            r0 += bv.x; r1 += bv.y; r2 += bv.z; r3 += bv.w;
        }
        if (OUTRELU) {
            r0 = fmaxf(r0, 0.f); r1 = fmaxf(r1, 0.f);
            r2 = fmaxf(r2, 0.f); r3 = fmaxf(r3, 0.f);
        }
        if (HASRES) {
            uint2 rv = reinterpret_cast<const uint2*>(resid)[(size_t)node * 16 + li];
            bfacc(rv, r0, r1, r2, r3);
        }
        if (OUTBF) {
            uint2 o = {bfpack2(r0, r1), bfpack2(r2, r3)};
            reinterpret_cast<uint2*>(outp)[(size_t)node * 16 + li] = o;
        } else {
            float4 o = {r0, r1, r2, r3};
            reinterpret_cast<float4*>(outp)[(size_t)node * 16 + li] = o;
        }
    }
}

// ---------------- gather (bf16 table, row=64B): 8 groups of 8 lanes ---------
__global__ __launch_bounds__(THREADS)
void k_gather32(const unsigned* __restrict__ tblb, const int* __restrict__ rowptr,
                const int* __restrict__ srcs, const float* __restrict__ dinv,
                unsigned* __restrict__ outb, int n) {
    int gt = blockIdx.x * THREADS + threadIdx.x;
    int node = gt >> 6;
    int lane = threadIdx.x & 63;
    if (node >= n) return;
    int og = lane >> 3, li = lane & 7;
    const uint2* t2 = reinterpret_cast<const uint2*>(tblb);
    float a0 = 0.f, a1 = 0.f, a2 = 0.f, a3 = 0.f;
    int beg = rowptr[node], end = rowptr[node + 1];
    int j = beg;
    for (; j + 16 <= end; j += 16) {
        int i0 = srcs[j + og];
        int i1 = srcs[j + 8 + og];
        uint2 v0 = t2[(size_t)i0 * 8 + li];
        uint2 v1 = t2[(size_t)i1 * 8 + li];
        bfacc(v0, a0, a1, a2, a3);
        bfacc(v1, a0, a1, a2, a3);
    }
    for (; j + 8 <= end; j += 8) {
        int i0 = srcs[j + og];
        uint2 v0 = t2[(size_t)i0 * 8 + li];
        bfacc(v0, a0, a1, a2, a3);
    }
    int rem = end - j;
    if (og < rem) {
        uint2 v = t2[(size_t)srcs[j + og] * 8 + li];
        bfacc(v, a0, a1, a2, a3);
    }
    a0 += __shfl_down(a0, 32, 64); a1 += __shfl_down(a1, 32, 64);
    a2 += __shfl_down(a2, 32, 64); a3 += __shfl_down(a3, 32, 64);
    a0 += __shfl_down(a0, 16, 64); a1 += __shfl_down(a1, 16, 64);
    a2 += __shfl_down(a2, 16, 64); a3 += __shfl_down(a3, 16, 64);
    a0 += __shfl_down(a0, 8, 64);  a1 += __shfl_down(a1, 8, 64);
    a2 += __shfl_down(a2, 8, 64);  a3 += __shfl_down(a3, 8, 64);
    if (lane < 8) {
        uint2 sv = t2[(size_t)node * 8 + li];
        bfacc(sv, a0, a1, a2, a3);
        float dv = dinv[node];
        uint2 o = {bfpack2(dv * a0, dv * a1), bfpack2(dv * a2, dv * a3)};
        reinterpret_cast<uint2*>(outb)[(size_t)node * 8 + li] = o;
    }
}

// ---------------- weight prep: Wtb[n][k] bf16 <- W[k][n] f32 ----------------
template <int FIN, int FOUT>
__global__ __launch_bounds__(THREADS)
void k_wprep(const float* __restrict__ W, unsigned* __restrict__ Wtb) {
    int g = blockIdx.x * THREADS + threadIdx.x;
    if (g >= FOUT * (FIN / 2)) return;
    int nn = g / (FIN / 2), kq = g % (FIN / 2);
    float lo = W[(size_t)(2 * kq) * FOUT + nn];
    float hi = W[(size_t)(2 * kq + 1) * FOUT + nn];
    Wtb[g] = bfpack2(lo, hi);
}

// ---------------- MFMA dense matmul ------------------------------------------
// out[node][FOUT] = row(xinb bf16) @ W + b via mfma_f32_16x16x32_bf16 with
// SWAPPED operands: A = Wt tiles (M=outcols), B = node rows (N=16 nodes).
// Lane l: node = base + (l&15); holds outcols (l>>4)*4+reg per 16-tile ->
// packed bf16 uint2 writes. Frag layout: k = 8*(l>>4)+j (contiguous 8,
// m92-validated "bf16x8 vec-load of B^T" pattern).
// EXTRA: 1 = outb=bf16(v+b), outb2=bf16(dinv*relu(v+b))   [mm1]
//        2 = outb=bf16(dinv*v)                             [mm3]
//        3 = outb=bf16(relu(v+b))                          [mm2]
template <int FIN, int FOUT, int EXTRA>
__global__ __launch_bounds__(THREADS)
void k_mmfa(const unsigned* __restrict__ xinb, const unsigned* __restrict__ wtb,
            const float* __restrict__ bias, const float* __restrict__ dinv,
            unsigned* __restrict__ outb, unsigned* __restrict__ outb2, int nrows) {
    constexpr int FH = FIN / 2;   // u32 per row
    constexpr int KS = FIN / 32;  // K-steps
    constexpr int MT = FOUT / 16; // out-col tiles
    int tid = threadIdx.x;
    int lane = tid & 63;
    int lg = lane >> 4, li = lane & 15;
    int node = blockIdx.x * 64 + (tid >> 6) * 16 + li;
    int nc = min(node, nrows - 1);

    const uint4* xr = reinterpret_cast<const uint4*>(xinb + (size_t)nc * FH);
    short8 bf[KS];
#pragma unroll
    for (int ks = 0; ks < KS; ++ks) bf[ks] = as_short8(xr[ks * 4 + lg]);

    f32x4 acc[MT];
#pragma unroll
    for (int mt = 0; mt < MT; ++mt) acc[mt] = (f32x4){0.f, 0.f, 0.f, 0.f};

#pragma unroll
    for (int ks = 0; ks < KS; ++ks) {
#pragma unroll
        for (int mt = 0; mt < MT; ++mt) {
            uint4 wu = *reinterpret_cast<const uint4*>(
                wtb + (size_t)(mt * 16 + li) * FH + ks * 16 + lg * 4);
            acc[mt] = __builtin_amdgcn_mfma_f32_16x16x32_bf16(
                as_short8(wu), bf[ks], acc[mt], 0, 0, 0);
        }
    }

    if (node >= nrows) return;
    float dv = (EXTRA != 3) ? dinv[node] : 0.f;
#pragma unroll
    for (int mt = 0; mt < MT; ++mt) {
        float v0 = acc[mt][0], v1 = acc[mt][1], v2 = acc[mt][2], v3 = acc[mt][3];
        int m0 = mt * 16 + lg * 4;
        if (EXTRA == 1 || EXTRA == 3) {
            float4 bv = *reinterpret_cast<const float4*>(bias + m0);
            v0 += bv.x; v1 += bv.y; v2 += bv.z; v3 += bv.w;
        }
        size_t ob = (size_t)node * (FOUT / 2) + mt * 8 + lg * 2;
        if (EXTRA == 1) {
            uint2 o = {bfpack2(v0, v1), bfpack2(v2, v3)};
            *reinterpret_cast<uint2*>(outb + ob) = o;
            uint2 s = {bfpack2(dv * fmaxf(v0, 0.f), dv * fmaxf(v1, 0.f)),
                       bfpack2(dv * fmaxf(v2, 0.f), dv * fmaxf(v3, 0.f))};
            *reinterpret_cast<uint2*>(outb2 + ob) = s;
        }
        if (EXTRA == 3) {
            uint2 o = {bfpack2(fmaxf(v0, 0.f), fmaxf(v1, 0.f)),
                       bfpack2(fmaxf(v2, 0.f), fmaxf(v3, 0.f))};
            *reinterpret_cast<uint2*>(outb + ob) = o;
        }
        if (EXTRA == 2) {
            uint2 o = {bfpack2(dv * v0, dv * v1), bfpack2(dv * v2, dv * v3)};
            *reinterpret_cast<uint2*>(outb + ob) = o;
        }
    }
}

// ---------------- segment mean pool ----------------
__global__ __launch_bounds__(THREADS)
void k_pool(const float* __restrict__ h, const int* __restrict__ batch,
            float* __restrict__ sums, float* __restrict__ cnts, int n) {
    int c = threadIdx.x & 63;
    int rq = threadIdx.x >> 6;  // 0..3
    int r0 = blockIdx.x * THREADS;
    int rend = min(r0 + THREADS, n);
    int curg = -1;
    float acc = 0.f, cacc = 0.f;
    for (int r = r0 + rq; r < rend; r += 4) {
        int g = batch[r];
        if (g != curg) {
            if (curg >= 0) {
                atomicAdd(&sums[(size_t)curg * 64 + c], acc);
                if (c == 0) atomicAdd(&cnts[curg], cacc);
            }
            curg = g; acc = 0.f; cacc = 0.f;
        }
        acc += h[(size_t)r * 64 + c];
        cacc += 1.f;
    }
    if (curg >= 0) {
        atomicAdd(&sums[(size_t)curg * 64 + c], acc);
        if (c == 0) atomicAdd(&cnts[curg], cacc);
    }
}

__global__ __launch_bounds__(THREADS)
void k_div(const float* __restrict__ sums, const float* __restrict__ cnts,
           float* __restrict__ out, int total) {
    int i = blockIdx.x * THREADS + threadIdx.x;
    if (i < total) out[i] = sums[i] / cnts[i >> 6];
}

// ---------------------------------------------------------------------------
static inline size_t alignup(size_t v) { return (v + 255) & ~(size_t)255; }

extern "C" void kernel_launch(void* const* d_in, const int* in_sizes, int n_in,
                              void* d_out, int out_size, void* d_ws, size_t ws_size,
                              hipStream_t stream) {
    const float* ev_f  = (const float*)d_in[0];
    const float* cs_f  = (const float*)d_in[1];
    const float* tr_f  = (const float*)d_in[2];
    const float* env_f = (const float*)d_in[3];
    const int*   ei    = (const int*)d_in[4];
    const int*   ev_i  = (const int*)d_in[5];
    const int*   cs_i  = (const int*)d_in[6];
    const int*   tr_i  = (const int*)d_in[7];
    const int*   env_i = (const int*)d_in[8];
    const int*   batch = (const int*)d_in[9];
    const float* W_ev = (const float*)d_in[10]; const float* b_ev = (const float*)d_in[11];
    const float* W_cs = (const float*)d_in[12]; const float* b_cs = (const float*)d_in[13];
    const float* W_tr = (const float*)d_in[14]; const float* b_tr = (const float*)d_in[15];
    const float* W_env= (const float*)d_in[16]; const float* b_env= (const float*)d_in[17];
    const float* W1 = (const float*)d_in[18]; const float* b1 = (const float*)d_in[19];
    const float* W2 = (const float*)d_in[20]; const float* b2 = (const float*)d_in[21];
    const float* W3 = (const float*)d_in[22]; const float* b3 = (const float*)d_in[23];

    const int E_ = in_sizes[4] / 2;
    const int N_ = in_sizes[9];
    const int n_ev  = in_sizes[5];
    const int n_cs  = in_sizes[6];
    const int n_tr  = in_sizes[7];
    const int n_env = in_sizes[8];
    const int ngr   = out_size / 64;  // 100 graphs

    const int* e_src = ei;
    const int* e_dst = ei + E_;

    const int NB   = (N_ + (1 << BINSHIFT) - 1) >> BINSHIFT;  // 98 bins
    const int ablk = (E_ + EPBA - 1) / EPBA;                  // 782 partition blocks

    // ---- workspace carve-up ----
    char* p = (char*)d_ws;
    int*      counts = (int*)p;      p += alignup((size_t)NB * ablk * 4);
    int*      bintot = (int*)p;      p += alignup((size_t)NB * 4);
    int*      binptr = (int*)p;      p += alignup(((size_t)NB + 1) * 4);
    int*      rowptr = (int*)p;      p += alignup(((size_t)N_ + 1) * 4);
    float*    dinv   = (float*)p;    p += alignup((size_t)N_ * 4);
    int*      srcs   = (int*)p;      p += alignup((size_t)E_ * 4);
    unsigned* xb     = (unsigned*)p; p += alignup((size_t)N_ * 16 * 4);   // bf16 [N,32]
    unsigned* x1b    = (unsigned*)p; p += alignup((size_t)N_ * 32 * 4);   // bf16 [N,64] raw x1
    unsigned* x1s_bf = (unsigned*)p; p += alignup((size_t)N_ * 32 * 4);   // bf16 conv2 table
    unsigned* aggb   = (unsigned*)p; p += alignup((size_t)N_ * 32 * 4);   // bf16 gather out
    unsigned* hA     = (unsigned*)p; p += alignup((size_t)N_ * 64 * 4);   // bf16 [N,128] mm2 out
    unsigned* t3s_bf = (unsigned*)p; p += alignup((size_t)N_ * 32 * 4);   // bf16 conv3 table
    float*    hfin   = (float*)p;    p += alignup((size_t)N_ * 64 * 4);   // f32 pool input
    unsigned* w1t    = (unsigned*)p; p += alignup((size_t)64 * 16 * 4);   // bf16 W1^T [64][32]
    unsigned* w2t    = (unsigned*)p; p += alignup((size_t)128 * 32 * 4);  // bf16 W2^T [128][64]
    unsigned* w3t    = (unsigned*)p; p += alignup((size_t)64 * 64 * 4);   // bf16 W3^T [64][128]
    float*    sums   = (float*)p;    p += alignup((size_t)ngr * 64 * 4);
    float*    cnts   = (float*)p;    p += alignup((size_t)ngr * 4);

    // pairs (E u32 = 12.8MB) aliases hA (25.6MB): dead at k_bincsr, hA first
    // written by mm2 (after bincsr).
    unsigned* pairs = hA;

    const int nblk  = (N_ + THREADS - 1) / THREADS;
    const int mfblk = (N_ + 63) / 64;                               // 64 rows/block
    const int gblk  = ((size_t)N_ * 64 + THREADS - 1) / THREADS;    // wave/node

    // ---- zero accumulated buffers (fresh every call) ----
    hipMemsetAsync(sums, 0, (size_t)ngr * 64 * 4, stream);
    hipMemsetAsync(cnts, 0, (size_t)ngr * 4, stream);

    // ---- CSR build (atomic-free partition) ----
    k_partcnt<<<ablk, THREADS, (size_t)NB * 4, stream>>>(e_dst, counts, ablk, NB, E_);
    k_scanrows<<<NB, THREADS, 0, stream>>>(counts, bintot, ablk);
    k_binscan<<<1, 128, 0, stream>>>(bintot, binptr, NB, E_);
    k_partwrite<<<ablk, THREADS, (size_t)NB * 8, stream>>>(e_src, e_dst, binptr, counts, ablk, pairs, NB, E_);
    k_bincsr<<<NB, THREADS, 0, stream>>>(pairs, binptr, rowptr, dinv, srcs, N_, NB, E_);

    // ---- weight prep (tiny) ----
    k_wprep<32, 64><<<(64 * 16 + THREADS - 1) / THREADS, THREADS, 0, stream>>>(W1, w1t);
    k_wprep<64, 128><<<(128 * 32 + THREADS - 1) / THREADS, THREADS, 0, stream>>>(W2, w2t);
    k_wprep<128, 64><<<(64 * 64 + THREADS - 1) / THREADS, THREADS, 0, stream>>>(W3, w3t);

    // ---- embeddings -> xb [N,32] bf16 (pre-scaled by dinv) ----
    k_embed<6><<<((size_t)n_ev  * 16 + THREADS - 1) / THREADS, THREADS, 0, stream>>>(ev_f,  W_ev,  b_ev,  ev_i,  dinv, n_ev,  xb);
    k_embed<4><<<((size_t)n_cs  * 16 + THREADS - 1) / THREADS, THREADS, 0, stream>>>(cs_f,  W_cs,  b_cs,  cs_i,  dinv, n_cs,  xb);
    k_embed<2><<<((size_t)n_tr  * 16 + THREADS - 1) / THREADS, THREADS, 0, stream>>>(tr_f,  W_tr,  b_tr,  tr_i,  dinv, n_tr,  xb);
    k_embed<5><<<((size_t)n_env * 16 + THREADS - 1) / THREADS, THREADS, 0, stream>>>(env_f, W_env, b_env, env_i, dinv, n_env, xb);

    // ---- conv1: agg(xb) -> aggb bf16; mm1: x1b=bf16(x1), x1s_bf=bf16(dinv*relu(x1)) ----
    k_gather32<<<gblk, THREADS, 0, stream>>>(xb, rowptr, srcs, dinv, aggb, N_);
    k_mmfa<32, 64, 1><<<mfblk, THREADS, 0, stream>>>(aggb, w1t, b1, dinv, x1b, x1s_bf, N_);

    // ---- conv2: agg(x1s_bf) -> aggb bf16; mm2: relu(@W2+b2) -> hA bf16 [N,128] ----
    k_gather64<false, false, false, true><<<gblk, THREADS, 0, stream>>>(
        x1s_bf, rowptr, srcs, dinv, nullptr, nullptr, aggb, N_);
    k_mmfa<64, 128, 3><<<mfblk, THREADS, 0, stream>>>(aggb, w2t, b2, nullptr, hA, nullptr, N_);

    // ---- conv3: mm3: t3s_bf = bf16(dinv*(hA @ W3)); gather3: relu(agg+b3)+x1b -> hfin ----
    k_mmfa<128, 64, 2><<<mfblk, THREADS, 0, stream>>>(hA, w3t, nullptr, dinv, t3s_bf, nullptr, N_);
    k_gather64<true, true, true, false><<<gblk, THREADS, 0, stream>>>(
        t3s_bf, rowptr, srcs, dinv, b3, x1b, hfin, N_);

    // ---- pool ----
    k_pool<<<nblk, THREADS, 0, stream>>>(hfin, batch, sums, cnts, N_);
    k_div<<<(out_size + THREADS - 1) / THREADS, THREADS, 0, stream>>>(sums, cnts, (float*)d_out, out_size);
}

// Round 11
// 360.969 us; speedup vs baseline: 1.6933x; 1.1017x over previous
//
#include <hip/hip_runtime.h>
#include <hip/hip_bf16.h>

// ---------------------------------------------------------------------------
// GNN Residual Feature Extractor
//   x = embed(type features)                       [N,32]
//   x1 = gcn(x, W1)+b1                             [N,64]
//   h  = relu(gcn(relu(x1),W2)+b2)                 [N,128]
//   h  = relu(gcn(h,W3)+b3) + x1                   [N,64]
//   out = segment_mean(h, batch)                   [100,64]
//
// gcn agg commutes with weight multiply; aggregate on narrow side.
// ALL N-wide intermediates are packed bf16; f32 accumulation.
// Gather tables pre-scaled by dinv / pre-activated by producers.
//
// CSR build: atomic-free two-pass radix partition. R11: BINSHIFT 10->8
// (391 bins of 256 nodes) — R10's k_bincsr ran 98 blocks (0.4/CU,
// occupancy 3.8%, 86us); 4x finer bins give 1.5 blocks/CU, 3KB LDS,
// one-count-per-thread scan, 32KB scatter windows.
//
// mm via MFMA (mfma_f32_16x16x32_bf16), swapped operands (A = bf16 W^T
// tiles, B = node rows) — R10-validated (mms fell out of top-5).
// ---------------------------------------------------------------------------

#define THREADS 256
#define BINSHIFT 8
#define EPBA 4096        // edges per partition block
#define SCANCH 8         // k_scanrows: values per thread (<=2048 blocks)

typedef __attribute__((ext_vector_type(8))) short short8;
typedef __attribute__((ext_vector_type(4))) float f32x4;

// ---------------- bf16 helpers ----------------
__device__ __forceinline__ unsigned bfpack2(float lo, float hi) {
    unsigned ul = __float_as_uint(lo);
    unsigned uh = __float_as_uint(hi);
    ul = (ul + 0x7fffu + ((ul >> 16) & 1u)) >> 16;          // rne, low half
    uh = (uh + 0x7fffu + ((uh >> 16) & 1u)) & 0xffff0000u;  // rne, high half
    return ul | uh;
}

__device__ __forceinline__ void bfacc(uint2 v, float& a0, float& a1,
                                      float& a2, float& a3) {
    a0 += __uint_as_float(v.x << 16);
    a1 += __uint_as_float(v.x & 0xffff0000u);
    a2 += __uint_as_float(v.y << 16);
    a3 += __uint_as_float(v.y & 0xffff0000u);
}

__device__ __forceinline__ short8 as_short8(uint4 u) {
    union { uint4 u; short8 s; } c; c.u = u; return c.s;
}

// ---------------- pass 1: per-(block,bin) exact counts ----------------
__global__ __launch_bounds__(THREADS)
void k_partcnt(const int* __restrict__ dst, int* __restrict__ counts,
               int nblk_part, int nb, int e) {
    extern __shared__ int h[];
    int t = threadIdx.x;
    for (int i = t; i < nb; i += THREADS) h[i] = 0;
    __syncthreads();
    int lo = blockIdx.x * EPBA;
    int hi = min(lo + EPBA, e);
    for (int i = lo + t; i < hi; i += THREADS)
        atomicAdd(&h[dst[i] >> BINSHIFT], 1);
    __syncthreads();
    for (int i = t; i < nb; i += THREADS)
        counts[(size_t)i * nblk_part + blockIdx.x] = h[i];
}

// ---------------- scan each bin's row of per-block counts ----------------
__global__ __launch_bounds__(THREADS)
void k_scanrows(int* __restrict__ counts, int* __restrict__ bintot, int nblk_part) {
    __shared__ int wsum[THREADS];
    int* row = counts + (size_t)blockIdx.x * nblk_part;
    int t = threadIdx.x;
    int base = t * SCANCH;
    int v[SCANCH];
    int s = 0;
#pragma unroll
    for (int k = 0; k < SCANCH; ++k) {
        v[k] = (base + k < nblk_part) ? row[base + k] : 0;
        s += v[k];
    }
    wsum[t] = s;
    __syncthreads();
    for (int off = 1; off < THREADS; off <<= 1) {
        int a = (t >= off) ? wsum[t - off] : 0;
        __syncthreads();
        wsum[t] += a;
        __syncthreads();
    }
    int run = wsum[t] - s;  // exclusive
#pragma unroll
    for (int k = 0; k < SCANCH; ++k) {
        int c = v[k];
        if (base + k < nblk_part) row[base + k] = run;
        run += c;
    }
    if (t == THREADS - 1) bintot[blockIdx.x] = run;
}

// ---------------- scan bin totals (single block, nb<=512) ----------------
__global__ __launch_bounds__(512)
void k_binscan(const int* __restrict__ bintot, int* __restrict__ binptr,
               int nb, int e) {
    __shared__ int lds[512];
    int t = threadIdx.x;
    int v = (t < nb) ? bintot[t] : 0;
    lds[t] = v;
    __syncthreads();
    for (int off = 1; off < 512; off <<= 1) {
        int a = (t >= off) ? lds[t - off] : 0;
        __syncthreads();
        lds[t] += a;
        __syncthreads();
    }
    if (t < nb) binptr[t] = lds[t] - v;  // exclusive
    if (t == 0) binptr[nb] = e;
}

// ---------------- pass 2: deterministic partition write (packed u32) --------
__global__ __launch_bounds__(THREADS)
void k_partwrite(const int* __restrict__ src, const int* __restrict__ dst,
                 const int* __restrict__ binptr, const int* __restrict__ counts,
                 int nblk_part, unsigned* __restrict__ pairs, int nb, int e) {
    extern __shared__ int smem[];
    int* base = smem;       // nb
    int* cnt  = smem + nb;  // nb
    int t = threadIdx.x;
    for (int i = t; i < nb; i += THREADS) {
        base[i] = binptr[i] + counts[(size_t)i * nblk_part + blockIdx.x];
        cnt[i] = 0;
    }
    __syncthreads();
    int lo = blockIdx.x * EPBA;
    int hi = min(lo + EPBA, e);
    for (int i = lo + t; i < hi; i += THREADS) {
        int s = src[i], d = dst[i];
        int b = d >> BINSHIFT;
        int pos = atomicAdd(&cnt[b], 1);   // LDS only
        pairs[base[b] + pos] = ((unsigned)s << BINSHIFT) | (unsigned)(d & ((1 << BINSHIFT) - 1));
    }
}

// ---------------- per-bin CSR finalize (256-node bins) ----------------
__global__ __launch_bounds__(THREADS)
void k_bincsr(const unsigned* __restrict__ pairs, const int* __restrict__ binptr,
              int* __restrict__ rowptr, float* __restrict__ dinv,
              int* __restrict__ srcs, int n, int nb, int e) {
    __shared__ int lcnt[256];
    __shared__ int lofs[256];
    int b = blockIdx.x, t = threadIdx.x;
    int e0 = binptr[b], e1 = binptr[b + 1];
    int n0 = b << BINSHIFT;
    constexpr unsigned NMASK = (1u << BINSHIFT) - 1u;
    lcnt[t] = 0;
    __syncthreads();
    for (int j = e0 + t; j < e1; j += THREADS)
        atomicAdd(&lcnt[pairs[j] & NMASK], 1);
    __syncthreads();
    int c = lcnt[t];
    lofs[t] = c;
    __syncthreads();
    for (int off = 1; off < THREADS; off <<= 1) {
        int a = (t >= off) ? lofs[t - off] : 0;
        __syncthreads();
        lofs[t] += a;
        __syncthreads();
    }
    int excl = lofs[t] - c;
    __syncthreads();
    lofs[t] = excl;
    int node = n0 + t;
    if (node < n) {
        rowptr[node] = e0 + excl;
        dinv[node] = rsqrtf((float)c + 1.0f);
    }
    if (b == nb - 1 && t == 0) rowptr[n] = e;
    __syncthreads();
    for (int j = e0 + t; j < e1; j += THREADS) {
        unsigned pp = pairs[j];
        int pos = e0 + atomicAdd(&lofs[pp & NMASK], 1);
        srcs[pos] = (int)(pp >> BINSHIFT);
    }
}

// ---------------- embedding: xb[idx[r]] = bf16(dinv * (f[r] @ W + b)) --------
template <int K>
__global__ __launch_bounds__(THREADS)
void k_embed(const float* __restrict__ f, const float* __restrict__ W,
             const float* __restrict__ b, const int* __restrict__ idx,
             const float* __restrict__ dinv, int rows, unsigned* __restrict__ xb) {
    int g = blockIdx.x * THREADS + threadIdx.x;
    int r = g >> 4, cp = g & 15;
    if (r >= rows) return;
    int node = idx[r];
    float dv = dinv[node];
    float a0 = b[2 * cp], a1 = b[2 * cp + 1];
#pragma unroll
    for (int k = 0; k < K; ++k) {
        float fv = f[r * K + k];
        a0 += fv * W[k * 32 + 2 * cp];
        a1 += fv * W[k * 32 + 2 * cp + 1];
    }
    xb[(size_t)node * 16 + cp] = bfpack2(dv * a0, dv * a1);
}

// ---------------- gather (bf16 table, row=128B): one wave per node ----------
template <bool HASBIAS, bool OUTRELU, bool HASRES, bool OUTBF>
__global__ __launch_bounds__(THREADS)
void k_gather64(const unsigned* __restrict__ tblb, const int* __restrict__ rowptr,
                const int* __restrict__ srcs, const float* __restrict__ dinv,
                const float* __restrict__ bias, const unsigned* __restrict__ resid,
                void* __restrict__ outp, int n) {
    int gt = blockIdx.x * THREADS + threadIdx.x;
    int node = gt >> 6;
    int lane = threadIdx.x & 63;
    if (node >= n) return;
    int qw = lane >> 4, li = lane & 15;
    const uint2* t2 = reinterpret_cast<const uint2*>(tblb);
    float a0 = 0.f, a1 = 0.f, a2 = 0.f, a3 = 0.f;
    int beg = rowptr[node], end = rowptr[node + 1];
    int j = beg;
    for (; j + 16 <= end; j += 16) {          // 16 edges, 4 rows in flight
        int i0 = srcs[j + qw];
        int i1 = srcs[j + 4 + qw];
        int i2 = srcs[j + 8 + qw];
        int i3 = srcs[j + 12 + qw];
        uint2 v0 = t2[(size_t)i0 * 16 + li];
        uint2 v1 = t2[(size_t)i1 * 16 + li];
        uint2 v2 = t2[(size_t)i2 * 16 + li];
        uint2 v3 = t2[(size_t)i3 * 16 + li];
        bfacc(v0, a0, a1, a2, a3);
        bfacc(v1, a0, a1, a2, a3);
        bfacc(v2, a0, a1, a2, a3);
        bfacc(v3, a0, a1, a2, a3);
    }
    for (; j + 8 <= end; j += 8) {
        int i0 = srcs[j + qw];
        int i1 = srcs[j + 4 + qw];
        uint2 v0 = t2[(size_t)i0 * 16 + li];
        uint2 v1 = t2[(size_t)i1 * 16 + li];
        bfacc(v0, a0, a1, a2, a3);
        bfacc(v1, a0, a1, a2, a3);
    }
    int rem = end - j;
    if (qw < rem) {
        uint2 v = t2[(size_t)srcs[j + qw] * 16 + li];
        bfacc(v, a0, a1, a2, a3);
    }
    if (qw + 4 < rem) {
        uint2 v = t2[(size_t)srcs[j + 4 + qw] * 16 + li];
        bfacc(v, a0, a1, a2, a3);
    }
    a0 += __shfl_down(a0, 32, 64); a1 += __shfl_down(a1, 32, 64);
    a2 += __shfl_down(a2, 32, 64); a3 += __shfl_down(a3, 32, 64);
    a0 += __shfl_down(a0, 16, 64); a1 += __shfl_down(a1, 16, 64);
    a2 += __shfl_down(a2, 16, 64); a3 += __shfl_down(a3, 16, 64);
    if (lane < 16) {
        uint2 sv = t2[(size_t)node * 16 + li];
        bfacc(sv, a0, a1, a2, a3);
        float dv = dinv[node];
        float r0 = dv * a0, r1 = dv * a1, r2 = dv * a2, r3 = dv * a3;
        if (HASBIAS) {
            float4 bv = *reinterpret_cast<const float4*>(bias + 4 * li);
            r0 += bv.x; r1 += bv.y; r2 += bv.z; r3 += bv.w;
        }
        if (OUTRELU) {
            r0 = fmaxf(r0, 0.f); r1 = fmaxf(r1, 0.f);
            r2 = fmaxf(r2, 0.f); r3 = fmaxf(r3, 0.f);
        }
        if (HASRES) {
            uint2 rv = reinterpret_cast<const uint2*>(resid)[(size_t)node * 16 + li];
            bfacc(rv, r0, r1, r2, r3);
        }
        if (OUTBF) {
            uint2 o = {bfpack2(r0, r1), bfpack2(r2, r3)};
            reinterpret_cast<uint2*>(outp)[(size_t)node * 16 + li] = o;
        } else {
            float4 o = {r0, r1, r2, r3};
            reinterpret_cast<float4*>(outp)[(size_t)node * 16 + li] = o;
        }
    }
}

// ---------------- gather (bf16 table, row=64B): 8 groups of 8 lanes ---------
__global__ __launch_bounds__(THREADS)
void k_gather32(const unsigned* __restrict__ tblb, const int* __restrict__ rowptr,
                const int* __restrict__ srcs, const float* __restrict__ dinv,
                unsigned* __restrict__ outb, int n) {
    int gt = blockIdx.x * THREADS + threadIdx.x;
    int node = gt >> 6;
    int lane = threadIdx.x & 63;
    if (node >= n) return;
    int og = lane >> 3, li = lane & 7;
    const uint2* t2 = reinterpret_cast<const uint2*>(tblb);
    float a0 = 0.f, a1 = 0.f, a2 = 0.f, a3 = 0.f;
    int beg = rowptr[node], end = rowptr[node + 1];
    int j = beg;
    for (; j + 16 <= end; j += 16) {
        int i0 = srcs[j + og];
        int i1 = srcs[j + 8 + og];
        uint2 v0 = t2[(size_t)i0 * 8 + li];
        uint2 v1 = t2[(size_t)i1 * 8 + li];
        bfacc(v0, a0, a1, a2, a3);
        bfacc(v1, a0, a1, a2, a3);
    }
    for (; j + 8 <= end; j += 8) {
        int i0 = srcs[j + og];
        uint2 v0 = t2[(size_t)i0 * 8 + li];
        bfacc(v0, a0, a1, a2, a3);
    }
    int rem = end - j;
    if (og < rem) {
        uint2 v = t2[(size_t)srcs[j + og] * 8 + li];
        bfacc(v, a0, a1, a2, a3);
    }
    a0 += __shfl_down(a0, 32, 64); a1 += __shfl_down(a1, 32, 64);
    a2 += __shfl_down(a2, 32, 64); a3 += __shfl_down(a3, 32, 64);
    a0 += __shfl_down(a0, 16, 64); a1 += __shfl_down(a1, 16, 64);
    a2 += __shfl_down(a2, 16, 64); a3 += __shfl_down(a3, 16, 64);
    a0 += __shfl_down(a0, 8, 64);  a1 += __shfl_down(a1, 8, 64);
    a2 += __shfl_down(a2, 8, 64);  a3 += __shfl_down(a3, 8, 64);
    if (lane < 8) {
        uint2 sv = t2[(size_t)node * 8 + li];
        bfacc(sv, a0, a1, a2, a3);
        float dv = dinv[node];
        uint2 o = {bfpack2(dv * a0, dv * a1), bfpack2(dv * a2, dv * a3)};
        reinterpret_cast<uint2*>(outb)[(size_t)node * 8 + li] = o;
    }
}

// ---------------- weight prep: Wtb[n][k] bf16 <- W[k][n] f32 ----------------
template <int FIN, int FOUT>
__global__ __launch_bounds__(THREADS)
void k_wprep(const float* __restrict__ W, unsigned* __restrict__ Wtb) {
    int g = blockIdx.x * THREADS + threadIdx.x;
    if (g >= FOUT * (FIN / 2)) return;
    int nn = g / (FIN / 2), kq = g % (FIN / 2);
    float lo = W[(size_t)(2 * kq) * FOUT + nn];
    float hi = W[(size_t)(2 * kq + 1) * FOUT + nn];
    Wtb[g] = bfpack2(lo, hi);
}

// ---------------- MFMA dense matmul ------------------------------------------
// out[node][FOUT] = row(xinb bf16) @ W + b via mfma_f32_16x16x32_bf16 with
// SWAPPED operands: A = Wt tiles (M=outcols), B = node rows (N=16 nodes).
// EXTRA: 1 = outb=bf16(v+b), outb2=bf16(dinv*relu(v+b))   [mm1]
//        2 = outb=bf16(dinv*v)                             [mm3]
//        3 = outb=bf16(relu(v+b))                          [mm2]
template <int FIN, int FOUT, int EXTRA>
__global__ __launch_bounds__(THREADS)
void k_mmfa(const unsigned* __restrict__ xinb, const unsigned* __restrict__ wtb,
            const float* __restrict__ bias, const float* __restrict__ dinv,
            unsigned* __restrict__ outb, unsigned* __restrict__ outb2, int nrows) {
    constexpr int FH = FIN / 2;   // u32 per row
    constexpr int KS = FIN / 32;  // K-steps
    constexpr int MT = FOUT / 16; // out-col tiles
    int tid = threadIdx.x;
    int lane = tid & 63;
    int lg = lane >> 4, li = lane & 15;
    int node = blockIdx.x * 64 + (tid >> 6) * 16 + li;
    int nc = min(node, nrows - 1);

    const uint4* xr = reinterpret_cast<const uint4*>(xinb + (size_t)nc * FH);
    short8 bf[KS];
#pragma unroll
    for (int ks = 0; ks < KS; ++ks) bf[ks] = as_short8(xr[ks * 4 + lg]);

    f32x4 acc[MT];
#pragma unroll
    for (int mt = 0; mt < MT; ++mt) acc[mt] = (f32x4){0.f, 0.f, 0.f, 0.f};

#pragma unroll
    for (int ks = 0; ks < KS; ++ks) {
#pragma unroll
        for (int mt = 0; mt < MT; ++mt) {
            uint4 wu = *reinterpret_cast<const uint4*>(
                wtb + (size_t)(mt * 16 + li) * FH + ks * 16 + lg * 4);
            acc[mt] = __builtin_amdgcn_mfma_f32_16x16x32_bf16(
                as_short8(wu), bf[ks], acc[mt], 0, 0, 0);
        }
    }

    if (node >= nrows) return;
    float dv = (EXTRA != 3) ? dinv[node] : 0.f;
#pragma unroll
    for (int mt = 0; mt < MT; ++mt) {
        float v0 = acc[mt][0], v1 = acc[mt][1], v2 = acc[mt][2], v3 = acc[mt][3];
        int m0 = mt * 16 + lg * 4;
        if (EXTRA == 1 || EXTRA == 3) {
            float4 bv = *reinterpret_cast<const float4*>(bias + m0);
            v0 += bv.x; v1 += bv.y; v2 += bv.z; v3 += bv.w;
        }
        size_t ob = (size_t)node * (FOUT / 2) + mt * 8 + lg * 2;
        if (EXTRA == 1) {
            uint2 o = {bfpack2(v0, v1), bfpack2(v2, v3)};
            *reinterpret_cast<uint2*>(outb + ob) = o;
            uint2 s = {bfpack2(dv * fmaxf(v0, 0.f), dv * fmaxf(v1, 0.f)),
                       bfpack2(dv * fmaxf(v2, 0.f), dv * fmaxf(v3, 0.f))};
            *reinterpret_cast<uint2*>(outb2 + ob) = s;
        }
        if (EXTRA == 3) {
            uint2 o = {bfpack2(fmaxf(v0, 0.f), fmaxf(v1, 0.f)),
                       bfpack2(fmaxf(v2, 0.f), fmaxf(v3, 0.f))};
            *reinterpret_cast<uint2*>(outb + ob) = o;
        }
        if (EXTRA == 2) {
            uint2 o = {bfpack2(dv * v0, dv * v1), bfpack2(dv * v2, dv * v3)};
            *reinterpret_cast<uint2*>(outb + ob) = o;
        }
    }
}

// ---------------- segment mean pool ----------------
__global__ __launch_bounds__(THREADS)
void k_pool(const float* __restrict__ h, const int* __restrict__ batch,
            float* __restrict__ sums, float* __restrict__ cnts, int n) {
    int c = threadIdx.x & 63;
    int rq = threadIdx.x >> 6;  // 0..3
    int r0 = blockIdx.x * THREADS;
    int rend = min(r0 + THREADS, n);
    int curg = -1;
    float acc = 0.f, cacc = 0.f;
    for (int r = r0 + rq; r < rend; r += 4) {
        int g = batch[r];
        if (g != curg) {
            if (curg >= 0) {
                atomicAdd(&sums[(size_t)curg * 64 + c], acc);
                if (c == 0) atomicAdd(&cnts[curg], cacc);
            }
            curg = g; acc = 0.f; cacc = 0.f;
        }
        acc += h[(size_t)r * 64 + c];
        cacc += 1.f;
    }
    if (curg >= 0) {
        atomicAdd(&sums[(size_t)curg * 64 + c], acc);
        if (c == 0) atomicAdd(&cnts[curg], cacc);
    }
}

__global__ __launch_bounds__(THREADS)
void k_div(const float* __restrict__ sums, const float* __restrict__ cnts,
           float* __restrict__ out, int total) {
    int i = blockIdx.x * THREADS + threadIdx.x;
    if (i < total) out[i] = sums[i] / cnts[i >> 6];
}

// ---------------------------------------------------------------------------
static inline size_t alignup(size_t v) { return (v + 255) & ~(size_t)255; }

extern "C" void kernel_launch(void* const* d_in, const int* in_sizes, int n_in,
                              void* d_out, int out_size, void* d_ws, size_t ws_size,
                              hipStream_t stream) {
    const float* ev_f  = (const float*)d_in[0];
    const float* cs_f  = (const float*)d_in[1];
    const float* tr_f  = (const float*)d_in[2];
    const float* env_f = (const float*)d_in[3];
    const int*   ei    = (const int*)d_in[4];
    const int*   ev_i  = (const int*)d_in[5];
    const int*   cs_i  = (const int*)d_in[6];
    const int*   tr_i  = (const int*)d_in[7];
    const int*   env_i = (const int*)d_in[8];
    const int*   batch = (const int*)d_in[9];
    const float* W_ev = (const float*)d_in[10]; const float* b_ev = (const float*)d_in[11];
    const float* W_cs = (const float*)d_in[12]; const float* b_cs = (const float*)d_in[13];
    const float* W_tr = (const float*)d_in[14]; const float* b_tr = (const float*)d_in[15];
    const float* W_env= (const float*)d_in[16]; const float* b_env= (const float*)d_in[17];
    const float* W1 = (const float*)d_in[18]; const float* b1 = (const float*)d_in[19];
    const float* W2 = (const float*)d_in[20]; const float* b2 = (const float*)d_in[21];
    const float* W3 = (const float*)d_in[22]; const float* b3 = (const float*)d_in[23];

    const int E_ = in_sizes[4] / 2;
    const int N_ = in_sizes[9];
    const int n_ev  = in_sizes[5];
    const int n_cs  = in_sizes[6];
    const int n_tr  = in_sizes[7];
    const int n_env = in_sizes[8];
    const int ngr   = out_size / 64;  // 100 graphs

    const int* e_src = ei;
    const int* e_dst = ei + E_;

    const int NB   = (N_ + (1 << BINSHIFT) - 1) >> BINSHIFT;  // 391 bins
    const int ablk = (E_ + EPBA - 1) / EPBA;                  // 782 partition blocks

    // ---- workspace carve-up ----
    char* p = (char*)d_ws;
    int*      counts = (int*)p;      p += alignup((size_t)NB * ablk * 4);
    int*      bintot = (int*)p;      p += alignup((size_t)NB * 4);
    int*      binptr = (int*)p;      p += alignup(((size_t)NB + 1) * 4);
    int*      rowptr = (int*)p;      p += alignup(((size_t)N_ + 1) * 4);
    float*    dinv   = (float*)p;    p += alignup((size_t)N_ * 4);
    int*      srcs   = (int*)p;      p += alignup((size_t)E_ * 4);
    unsigned* xb     = (unsigned*)p; p += alignup((size_t)N_ * 16 * 4);   // bf16 [N,32]
    unsigned* x1b    = (unsigned*)p; p += alignup((size_t)N_ * 32 * 4);   // bf16 [N,64] raw x1
    unsigned* x1s_bf = (unsigned*)p; p += alignup((size_t)N_ * 32 * 4);   // bf16 conv2 table
    unsigned* aggb   = (unsigned*)p; p += alignup((size_t)N_ * 32 * 4);   // bf16 gather out
    unsigned* hA     = (unsigned*)p; p += alignup((size_t)N_ * 64 * 4);   // bf16 [N,128] mm2 out
    unsigned* t3s_bf = (unsigned*)p; p += alignup((size_t)N_ * 32 * 4);   // bf16 conv3 table
    float*    hfin   = (float*)p;    p += alignup((size_t)N_ * 64 * 4);   // f32 pool input
    unsigned* w1t    = (unsigned*)p; p += alignup((size_t)64 * 16 * 4);   // bf16 W1^T [64][32]
    unsigned* w2t    = (unsigned*)p; p += alignup((size_t)128 * 32 * 4);  // bf16 W2^T [128][64]
    unsigned* w3t    = (unsigned*)p; p += alignup((size_t)64 * 64 * 4);   // bf16 W3^T [64][128]
    float*    sums   = (float*)p;    p += alignup((size_t)ngr * 64 * 4);
    float*    cnts   = (float*)p;    p += alignup((size_t)ngr * 4);

    // pairs (E u32 = 12.8MB) aliases hA (25.6MB): dead at k_bincsr, hA first
    // written by mm2 (after bincsr).
    unsigned* pairs = hA;

    const int nblk  = (N_ + THREADS - 1) / THREADS;
    const int mfblk = (N_ + 63) / 64;                               // 64 rows/block
    const int gblk  = ((size_t)N_ * 64 + THREADS - 1) / THREADS;    // wave/node

    // ---- zero accumulated buffers (fresh every call) ----
    hipMemsetAsync(sums, 0, (size_t)ngr * 64 * 4, stream);
    hipMemsetAsync(cnts, 0, (size_t)ngr * 4, stream);

    // ---- CSR build (atomic-free partition) ----
    k_partcnt<<<ablk, THREADS, (size_t)NB * 4, stream>>>(e_dst, counts, ablk, NB, E_);
    k_scanrows<<<NB, THREADS, 0, stream>>>(counts, bintot, ablk);
    k_binscan<<<1, 512, 0, stream>>>(bintot, binptr, NB, E_);
    k_partwrite<<<ablk, THREADS, (size_t)NB * 8, stream>>>(e_src, e_dst, binptr, counts, ablk, pairs, NB, E_);
    k_bincsr<<<NB, THREADS, 0, stream>>>(pairs, binptr, rowptr, dinv, srcs, N_, NB, E_);

    // ---- weight prep (tiny) ----
    k_wprep<32, 64><<<(64 * 16 + THREADS - 1) / THREADS, THREADS, 0, stream>>>(W1, w1t);
    k_wprep<64, 128><<<(128 * 32 + THREADS - 1) / THREADS, THREADS, 0, stream>>>(W2, w2t);
    k_wprep<128, 64><<<(64 * 64 + THREADS - 1) / THREADS, THREADS, 0, stream>>>(W3, w3t);

    // ---- embeddings -> xb [N,32] bf16 (pre-scaled by dinv) ----
    k_embed<6><<<((size_t)n_ev  * 16 + THREADS - 1) / THREADS, THREADS, 0, stream>>>(ev_f,  W_ev,  b_ev,  ev_i,  dinv, n_ev,  xb);
    k_embed<4><<<((size_t)n_cs  * 16 + THREADS - 1) / THREADS, THREADS, 0, stream>>>(cs_f,  W_cs,  b_cs,  cs_i,  dinv, n_cs,  xb);
    k_embed<2><<<((size_t)n_tr  * 16 + THREADS - 1) / THREADS, THREADS, 0, stream>>>(tr_f,  W_tr,  b_tr,  tr_i,  dinv, n_tr,  xb);
    k_embed<5><<<((size_t)n_env * 16 + THREADS - 1) / THREADS, THREADS, 0, stream>>>(env_f, W_env, b_env, env_i, dinv, n_env, xb);

    // ---- conv1: agg(xb) -> aggb bf16; mm1: x1b=bf16(x1), x1s_bf=bf16(dinv*relu(x1)) ----
    k_gather32<<<gblk, THREADS, 0, stream>>>(xb, rowptr, srcs, dinv, aggb, N_);
    k_mmfa<32, 64, 1><<<mfblk, THREADS, 0, stream>>>(aggb, w1t, b1, dinv, x1b, x1s_bf, N_);

    // ---- conv2: agg(x1s_bf) -> aggb bf16; mm2: relu(@W2+b2) -> hA bf16 [N,128] ----
    k_gather64<false, false, false, true><<<gblk, THREADS, 0, stream>>>(
        x1s_bf, rowptr, srcs, dinv, nullptr, nullptr, aggb, N_);
    k_mmfa<64, 128, 3><<<mfblk, THREADS, 0, stream>>>(aggb, w2t, b2, nullptr, hA, nullptr, N_);

    // ---- conv3: mm3: t3s_bf = bf16(dinv*(hA @ W3)); gather3: relu(agg+b3)+x1b -> hfin ----
    k_mmfa<128, 64, 2><<<mfblk, THREADS, 0, stream>>>(hA, w3t, nullptr, dinv, t3s_bf, nullptr, N_);
    k_gather64<true, true, true, false><<<gblk, THREADS, 0, stream>>>(
        t3s_bf, rowptr, srcs, dinv, b3, x1b, hfin, N_);

    // ---- pool ----
    k_pool<<<nblk, THREADS, 0, stream>>>(hfin, batch, sums, cnts, N_);
    k_div<<<(out_size + THREADS - 1) / THREADS, THREADS, 0, stream>>>(sums, cnts, (float*)d_out, out_size);
}

// Round 12
// 359.413 us; speedup vs baseline: 1.7006x; 1.0043x over previous
//
#include <hip/hip_runtime.h>
#include <hip/hip_bf16.h>

// ---------------------------------------------------------------------------
// GNN Residual Feature Extractor
//   x = embed(type features)                       [N,32]
//   x1 = gcn(x, W1)+b1                             [N,64]
//   h  = relu(gcn(relu(x1),W2)+b2)                 [N,128]
//   h  = relu(gcn(h,W3)+b3) + x1                   [N,64]
//   out = segment_mean(h, batch)                   [100,64]
//
// gcn agg commutes with weight multiply; aggregate on narrow side.
// ALL N-wide intermediates are packed bf16; f32 accumulation.
// Gather tables pre-scaled by dinv / pre-activated by producers.
//
// CSR build: atomic-free two-pass radix partition, BINSHIFT=8 (R11).
// mm via MFMA swapped-operand (R10). R12: gathers get 32-edge deep unroll
// (8 loads in flight/lane — R11 showed latency-bound at 44% VALU, 72% occ),
// merged embed/wprep launches, bf16 pool path.
// ---------------------------------------------------------------------------

#define THREADS 256
#define BINSHIFT 8
#define EPBA 4096        // edges per partition block
#define SCANCH 8         // k_scanrows: values per thread (<=2048 blocks)

typedef __attribute__((ext_vector_type(8))) short short8;
typedef __attribute__((ext_vector_type(4))) float f32x4;

// ---------------- bf16 helpers ----------------
__device__ __forceinline__ unsigned bfpack2(float lo, float hi) {
    unsigned ul = __float_as_uint(lo);
    unsigned uh = __float_as_uint(hi);
    ul = (ul + 0x7fffu + ((ul >> 16) & 1u)) >> 16;          // rne, low half
    uh = (uh + 0x7fffu + ((uh >> 16) & 1u)) & 0xffff0000u;  // rne, high half
    return ul | uh;
}

__device__ __forceinline__ void bfacc(uint2 v, float& a0, float& a1,
                                      float& a2, float& a3) {
    a0 += __uint_as_float(v.x << 16);
    a1 += __uint_as_float(v.x & 0xffff0000u);
    a2 += __uint_as_float(v.y << 16);
    a3 += __uint_as_float(v.y & 0xffff0000u);
}

__device__ __forceinline__ short8 as_short8(uint4 u) {
    union { uint4 u; short8 s; } c; c.u = u; return c.s;
}

// ---------------- pass 1: per-(block,bin) exact counts ----------------
__global__ __launch_bounds__(THREADS)
void k_partcnt(const int* __restrict__ dst, int* __restrict__ counts,
               int nblk_part, int nb, int e) {
    extern __shared__ int h[];
    int t = threadIdx.x;
    for (int i = t; i < nb; i += THREADS) h[i] = 0;
    __syncthreads();
    int lo = blockIdx.x * EPBA;
    int hi = min(lo + EPBA, e);
    for (int i = lo + t; i < hi; i += THREADS)
        atomicAdd(&h[dst[i] >> BINSHIFT], 1);
    __syncthreads();
    for (int i = t; i < nb; i += THREADS)
        counts[(size_t)i * nblk_part + blockIdx.x] = h[i];
}

// ---------------- scan each bin's row of per-block counts ----------------
__global__ __launch_bounds__(THREADS)
void k_scanrows(int* __restrict__ counts, int* __restrict__ bintot, int nblk_part) {
    __shared__ int wsum[THREADS];
    int* row = counts + (size_t)blockIdx.x * nblk_part;
    int t = threadIdx.x;
    int base = t * SCANCH;
    int v[SCANCH];
    int s = 0;
#pragma unroll
    for (int k = 0; k < SCANCH; ++k) {
        v[k] = (base + k < nblk_part) ? row[base + k] : 0;
        s += v[k];
    }
    wsum[t] = s;
    __syncthreads();
    for (int off = 1; off < THREADS; off <<= 1) {
        int a = (t >= off) ? wsum[t - off] : 0;
        __syncthreads();
        wsum[t] += a;
        __syncthreads();
    }
    int run = wsum[t] - s;  // exclusive
#pragma unroll
    for (int k = 0; k < SCANCH; ++k) {
        int c = v[k];
        if (base + k < nblk_part) row[base + k] = run;
        run += c;
    }
    if (t == THREADS - 1) bintot[blockIdx.x] = run;
}

// ---------------- scan bin totals (single block, nb<=512) ----------------
__global__ __launch_bounds__(512)
void k_binscan(const int* __restrict__ bintot, int* __restrict__ binptr,
               int nb, int e) {
    __shared__ int lds[512];
    int t = threadIdx.x;
    int v = (t < nb) ? bintot[t] : 0;
    lds[t] = v;
    __syncthreads();
    for (int off = 1; off < 512; off <<= 1) {
        int a = (t >= off) ? lds[t - off] : 0;
        __syncthreads();
        lds[t] += a;
        __syncthreads();
    }
    if (t < nb) binptr[t] = lds[t] - v;  // exclusive
    if (t == 0) binptr[nb] = e;
}

// ---------------- pass 2: deterministic partition write (packed u32) --------
__global__ __launch_bounds__(THREADS)
void k_partwrite(const int* __restrict__ src, const int* __restrict__ dst,
                 const int* __restrict__ binptr, const int* __restrict__ counts,
                 int nblk_part, unsigned* __restrict__ pairs, int nb, int e) {
    extern __shared__ int smem[];
    int* base = smem;       // nb
    int* cnt  = smem + nb;  // nb
    int t = threadIdx.x;
    for (int i = t; i < nb; i += THREADS) {
        base[i] = binptr[i] + counts[(size_t)i * nblk_part + blockIdx.x];
        cnt[i] = 0;
    }
    __syncthreads();
    int lo = blockIdx.x * EPBA;
    int hi = min(lo + EPBA, e);
    for (int i = lo + t; i < hi; i += THREADS) {
        int s = src[i], d = dst[i];
        int b = d >> BINSHIFT;
        int pos = atomicAdd(&cnt[b], 1);   // LDS only
        pairs[base[b] + pos] = ((unsigned)s << BINSHIFT) | (unsigned)(d & ((1 << BINSHIFT) - 1));
    }
}

// ---------------- per-bin CSR finalize (256-node bins) ----------------
__global__ __launch_bounds__(THREADS)
void k_bincsr(const unsigned* __restrict__ pairs, const int* __restrict__ binptr,
              int* __restrict__ rowptr, float* __restrict__ dinv,
              int* __restrict__ srcs, int n, int nb, int e) {
    __shared__ int lcnt[256];
    __shared__ int lofs[256];
    int b = blockIdx.x, t = threadIdx.x;
    int e0 = binptr[b], e1 = binptr[b + 1];
    int n0 = b << BINSHIFT;
    constexpr unsigned NMASK = (1u << BINSHIFT) - 1u;
    lcnt[t] = 0;
    __syncthreads();
    for (int j = e0 + t; j < e1; j += THREADS)
        atomicAdd(&lcnt[pairs[j] & NMASK], 1);
    __syncthreads();
    int c = lcnt[t];
    lofs[t] = c;
    __syncthreads();
    for (int off = 1; off < THREADS; off <<= 1) {
        int a = (t >= off) ? lofs[t - off] : 0;
        __syncthreads();
        lofs[t] += a;
        __syncthreads();
    }
    int excl = lofs[t] - c;
    __syncthreads();
    lofs[t] = excl;
    int node = n0 + t;
    if (node < n) {
        rowptr[node] = e0 + excl;
        dinv[node] = rsqrtf((float)c + 1.0f);
    }
    if (b == nb - 1 && t == 0) rowptr[n] = e;
    __syncthreads();
    for (int j = e0 + t; j < e1; j += THREADS) {
        unsigned pp = pairs[j];
        int pos = e0 + atomicAdd(&lofs[pp & NMASK], 1);
        srcs[pos] = (int)(pp >> BINSHIFT);
    }
}

// ---------------- merged embedding (all 4 node types) ----------------
struct EmbedArgs {
    const float* f[4];
    const float* W[4];
    const float* b[4];
    const int*   idx[4];
    int cum[5];
    int Kv[4];
};

__global__ __launch_bounds__(THREADS)
void k_embed_all(EmbedArgs ea, const float* __restrict__ dinv,
                 unsigned* __restrict__ xb) {
    int g = blockIdx.x * THREADS + threadIdx.x;
    int row = g >> 4, cp = g & 15;
    if (row >= ea.cum[4]) return;
    int t = (row >= ea.cum[1]) + (row >= ea.cum[2]) + (row >= ea.cum[3]);
    int r = row - ea.cum[t];
    int K = ea.Kv[t];
    const float* f  = ea.f[t];
    const float* W  = ea.W[t];
    const float* bb = ea.b[t];
    int node = ea.idx[t][r];
    float dv = dinv[node];
    float a0 = bb[2 * cp], a1 = bb[2 * cp + 1];
    for (int k = 0; k < K; ++k) {
        float fv = f[r * K + k];
        a0 += fv * W[k * 32 + 2 * cp];
        a1 += fv * W[k * 32 + 2 * cp + 1];
    }
    xb[(size_t)node * 16 + cp] = bfpack2(dv * a0, dv * a1);
}

// ---------------- gather (bf16 table, row=128B): one wave per node ----------
// 4 quarter-groups of 16 lanes; each quarter owns one edge's full row.
// 32-edge main loop: 8 srcs + 8 table loads in flight per lane (R12).
template <bool HASBIAS, bool OUTRELU, bool HASRES, bool OUTBF>
__global__ __launch_bounds__(THREADS)
void k_gather64(const unsigned* __restrict__ tblb, const int* __restrict__ rowptr,
                const int* __restrict__ srcs, const float* __restrict__ dinv,
                const float* __restrict__ bias, const unsigned* __restrict__ resid,
                void* __restrict__ outp, int n) {
    int gt = blockIdx.x * THREADS + threadIdx.x;
    int node = gt >> 6;
    int lane = threadIdx.x & 63;
    if (node >= n) return;
    int qw = lane >> 4, li = lane & 15;
    const uint2* t2 = reinterpret_cast<const uint2*>(tblb);
    float a0 = 0.f, a1 = 0.f, a2 = 0.f, a3 = 0.f;
    int beg = rowptr[node], end = rowptr[node + 1];
    int j = beg;
    for (; j + 32 <= end; j += 32) {          // 32 edges, 8 rows in flight/lane
        int s[8];
#pragma unroll
        for (int u = 0; u < 8; ++u) s[u] = srcs[j + 4 * u + qw];
        uint2 v[8];
#pragma unroll
        for (int u = 0; u < 8; ++u) v[u] = t2[(size_t)s[u] * 16 + li];
#pragma unroll
        for (int u = 0; u < 8; ++u) bfacc(v[u], a0, a1, a2, a3);
    }
    for (; j + 8 <= end; j += 8) {
        int s0 = srcs[j + qw];
        int s1 = srcs[j + 4 + qw];
        uint2 v0 = t2[(size_t)s0 * 16 + li];
        uint2 v1 = t2[(size_t)s1 * 16 + li];
        bfacc(v0, a0, a1, a2, a3);
        bfacc(v1, a0, a1, a2, a3);
    }
    int rem = end - j;
    if (qw < rem) {
        uint2 v = t2[(size_t)srcs[j + qw] * 16 + li];
        bfacc(v, a0, a1, a2, a3);
    }
    if (qw + 4 < rem) {
        uint2 v = t2[(size_t)srcs[j + 4 + qw] * 16 + li];
        bfacc(v, a0, a1, a2, a3);
    }
    a0 += __shfl_down(a0, 32, 64); a1 += __shfl_down(a1, 32, 64);
    a2 += __shfl_down(a2, 32, 64); a3 += __shfl_down(a3, 32, 64);
    a0 += __shfl_down(a0, 16, 64); a1 += __shfl_down(a1, 16, 64);
    a2 += __shfl_down(a2, 16, 64); a3 += __shfl_down(a3, 16, 64);
    if (lane < 16) {
        uint2 sv = t2[(size_t)node * 16 + li];
        bfacc(sv, a0, a1, a2, a3);
        float dv = dinv[node];
        float r0 = dv * a0, r1 = dv * a1, r2 = dv * a2, r3 = dv * a3;
        if (HASBIAS) {
            float4 bv = *reinterpret_cast<const float4*>(bias + 4 * li);
            r0 += bv.x; r1 += bv.y; r2 += bv.z; r3 += bv.w;
        }
        if (OUTRELU) {
            r0 = fmaxf(r0, 0.f); r1 = fmaxf(r1, 0.f);
            r2 = fmaxf(r2, 0.f); r3 = fmaxf(r3, 0.f);
        }
        if (HASRES) {
            uint2 rv = reinterpret_cast<const uint2*>(resid)[(size_t)node * 16 + li];
            bfacc(rv, r0, r1, r2, r3);
        }
        if (OUTBF) {
            uint2 o = {bfpack2(r0, r1), bfpack2(r2, r3)};
            reinterpret_cast<uint2*>(outp)[(size_t)node * 16 + li] = o;
        } else {
            float4 o = {r0, r1, r2, r3};
            reinterpret_cast<float4*>(outp)[(size_t)node * 16 + li] = o;
        }
    }
}

// ---------------- gather (bf16 table, row=64B): 8 groups of 8 lanes ---------
__global__ __launch_bounds__(THREADS)
void k_gather32(const unsigned* __restrict__ tblb, const int* __restrict__ rowptr,
                const int* __restrict__ srcs, const float* __restrict__ dinv,
                unsigned* __restrict__ outb, int n) {
    int gt = blockIdx.x * THREADS + threadIdx.x;
    int node = gt >> 6;
    int lane = threadIdx.x & 63;
    if (node >= n) return;
    int og = lane >> 3, li = lane & 7;
    const uint2* t2 = reinterpret_cast<const uint2*>(tblb);
    float a0 = 0.f, a1 = 0.f, a2 = 0.f, a3 = 0.f;
    int beg = rowptr[node], end = rowptr[node + 1];
    int j = beg;
    for (; j + 32 <= end; j += 32) {          // 32 edges, 4 rows in flight/lane
        int s[4];
#pragma unroll
        for (int u = 0; u < 4; ++u) s[u] = srcs[j + 8 * u + og];
        uint2 v[4];
#pragma unroll
        for (int u = 0; u < 4; ++u) v[u] = t2[(size_t)s[u] * 8 + li];
#pragma unroll
        for (int u = 0; u < 4; ++u) bfacc(v[u], a0, a1, a2, a3);
    }
    for (; j + 8 <= end; j += 8) {
        int s0 = srcs[j + og];
        uint2 v0 = t2[(size_t)s0 * 8 + li];
        bfacc(v0, a0, a1, a2, a3);
    }
    int rem = end - j;
    if (og < rem) {
        uint2 v = t2[(size_t)srcs[j + og] * 8 + li];
        bfacc(v, a0, a1, a2, a3);
    }
    a0 += __shfl_down(a0, 32, 64); a1 += __shfl_down(a1, 32, 64);
    a2 += __shfl_down(a2, 32, 64); a3 += __shfl_down(a3, 32, 64);
    a0 += __shfl_down(a0, 16, 64); a1 += __shfl_down(a1, 16, 64);
    a2 += __shfl_down(a2, 16, 64); a3 += __shfl_down(a3, 16, 64);
    a0 += __shfl_down(a0, 8, 64);  a1 += __shfl_down(a1, 8, 64);
    a2 += __shfl_down(a2, 8, 64);  a3 += __shfl_down(a3, 8, 64);
    if (lane < 8) {
        uint2 sv = t2[(size_t)node * 8 + li];
        bfacc(sv, a0, a1, a2, a3);
        float dv = dinv[node];
        uint2 o = {bfpack2(dv * a0, dv * a1), bfpack2(dv * a2, dv * a3)};
        reinterpret_cast<uint2*>(outb)[(size_t)node * 8 + li] = o;
    }
}

// ---------------- merged weight prep: all three W^T bf16 tables --------------
// wt layout: [0,1024) = W1t (64x[32]), [1024,5120) = W2t (128x[64]),
//            [5120,9216) = W3t (64x[128])   (u32 = 2 bf16 each)
__global__ __launch_bounds__(THREADS)
void k_wprep_all(const float* __restrict__ W1, const float* __restrict__ W2,
                 const float* __restrict__ W3, unsigned* __restrict__ wt) {
    int g = blockIdx.x * THREADS + threadIdx.x;
    if (g < 1024) {
        int nn = g >> 4, kq = g & 15;
        wt[g] = bfpack2(W1[(size_t)(2 * kq) * 64 + nn], W1[(size_t)(2 * kq + 1) * 64 + nn]);
    } else if (g < 5120) {
        int gg = g - 1024;
        int nn = gg >> 5, kq = gg & 31;
        wt[g] = bfpack2(W2[(size_t)(2 * kq) * 128 + nn], W2[(size_t)(2 * kq + 1) * 128 + nn]);
    } else if (g < 9216) {
        int gg = g - 5120;
        int nn = gg >> 6, kq = gg & 63;
        wt[g] = bfpack2(W3[(size_t)(2 * kq) * 64 + nn], W3[(size_t)(2 * kq + 1) * 64 + nn]);
    }
}

// ---------------- MFMA dense matmul ------------------------------------------
// out[node][FOUT] = row(xinb bf16) @ W + b via mfma_f32_16x16x32_bf16 with
// SWAPPED operands: A = Wt tiles (M=outcols), B = node rows (N=16 nodes).
// EXTRA: 1 = outb=bf16(v+b), outb2=bf16(dinv*relu(v+b))   [mm1]
//        2 = outb=bf16(dinv*v)                             [mm3]
//        3 = outb=bf16(relu(v+b))                          [mm2]
template <int FIN, int FOUT, int EXTRA>
__global__ __launch_bounds__(THREADS)
void k_mmfa(const unsigned* __restrict__ xinb, const unsigned* __restrict__ wtb,
            const float* __restrict__ bias, const float* __restrict__ dinv,
            unsigned* __restrict__ outb, unsigned* __restrict__ outb2, int nrows) {
    constexpr int FH = FIN / 2;   // u32 per row
    constexpr int KS = FIN / 32;  // K-steps
    constexpr int MT = FOUT / 16; // out-col tiles
    int tid = threadIdx.x;
    int lane = tid & 63;
    int lg = lane >> 4, li = lane & 15;
    int node = blockIdx.x * 64 + (tid >> 6) * 16 + li;
    int nc = min(node, nrows - 1);

    const uint4* xr = reinterpret_cast<const uint4*>(xinb + (size_t)nc * FH);
    short8 bf[KS];
#pragma unroll
    for (int ks = 0; ks < KS; ++ks) bf[ks] = as_short8(xr[ks * 4 + lg]);

    f32x4 acc[MT];
#pragma unroll
    for (int mt = 0; mt < MT; ++mt) acc[mt] = (f32x4){0.f, 0.f, 0.f, 0.f};

#pragma unroll
    for (int ks = 0; ks < KS; ++ks) {
#pragma unroll
        for (int mt = 0; mt < MT; ++mt) {
            uint4 wu = *reinterpret_cast<const uint4*>(
                wtb + (size_t)(mt * 16 + li) * FH + ks * 16 + lg * 4);
            acc[mt] = __builtin_amdgcn_mfma_f32_16x16x32_bf16(
                as_short8(wu), bf[ks], acc[mt], 0, 0, 0);
        }
    }

    if (node >= nrows) return;
    float dv = (EXTRA != 3) ? dinv[node] : 0.f;
#pragma unroll
    for (int mt = 0; mt < MT; ++mt) {
        float v0 = acc[mt][0], v1 = acc[mt][1], v2 = acc[mt][2], v3 = acc[mt][3];
        int m0 = mt * 16 + lg * 4;
        if (EXTRA == 1 || EXTRA == 3) {
            float4 bv = *reinterpret_cast<const float4*>(bias + m0);
            v0 += bv.x; v1 += bv.y; v2 += bv.z; v3 += bv.w;
        }
        size_t ob = (size_t)node * (FOUT / 2) + mt * 8 + lg * 2;
        if (EXTRA == 1) {
            uint2 o = {bfpack2(v0, v1), bfpack2(v2, v3)};
            *reinterpret_cast<uint2*>(outb + ob) = o;
            uint2 s = {bfpack2(dv * fmaxf(v0, 0.f), dv * fmaxf(v1, 0.f)),
                       bfpack2(dv * fmaxf(v2, 0.f), dv * fmaxf(v3, 0.f))};
            *reinterpret_cast<uint2*>(outb2 + ob) = s;
        }
        if (EXTRA == 3) {
            uint2 o = {bfpack2(fmaxf(v0, 0.f), fmaxf(v1, 0.f)),
                       bfpack2(fmaxf(v2, 0.f), fmaxf(v3, 0.f))};
            *reinterpret_cast<uint2*>(outb + ob) = o;
        }
        if (EXTRA == 2) {
            uint2 o = {bfpack2(dv * v0, dv * v1), bfpack2(dv * v2, dv * v3)};
            *reinterpret_cast<uint2*>(outb + ob) = o;
        }
    }
}

// ---------------- segment mean pool (bf16 input) ----------------
__global__ __launch_bounds__(THREADS)
void k_pool(const unsigned* __restrict__ hb, const int* __restrict__ batch,
            float* __restrict__ sums, float* __restrict__ cnts, int n) {
    int c = threadIdx.x & 31;          // u32 column (2 bf16)
    int rq = threadIdx.x >> 5;         // 0..7
    int r0 = blockIdx.x * THREADS;     // 256 rows per block
    int rend = min(r0 + THREADS, n);
    int curg = -1;
    float a0 = 0.f, a1 = 0.f, cacc = 0.f;
    for (int r = r0 + rq; r < rend; r += 8) {
        int g = batch[r];
        if (g != curg) {
            if (curg >= 0) {
                atomicAdd(&sums[(size_t)curg * 64 + 2 * c], a0);
                atomicAdd(&sums[(size_t)curg * 64 + 2 * c + 1], a1);
                if (c == 0) atomicAdd(&cnts[curg], cacc);
            }
            curg = g; a0 = 0.f; a1 = 0.f; cacc = 0.f;
        }
        unsigned u = hb[(size_t)r * 32 + c];
        a0 += __uint_as_float(u << 16);
        a1 += __uint_as_float(u & 0xffff0000u);
        cacc += 1.f;
    }
    if (curg >= 0) {
        atomicAdd(&sums[(size_t)curg * 64 + 2 * c], a0);
        atomicAdd(&sums[(size_t)curg * 64 + 2 * c + 1], a1);
        if (c == 0) atomicAdd(&cnts[curg], cacc);
    }
}

__global__ __launch_bounds__(THREADS)
void k_div(const float* __restrict__ sums, const float* __restrict__ cnts,
           float* __restrict__ out, int total) {
    int i = blockIdx.x * THREADS + threadIdx.x;
    if (i < total) out[i] = sums[i] / cnts[i >> 6];
}

// ---------------------------------------------------------------------------
static inline size_t alignup(size_t v) { return (v + 255) & ~(size_t)255; }

extern "C" void kernel_launch(void* const* d_in, const int* in_sizes, int n_in,
                              void* d_out, int out_size, void* d_ws, size_t ws_size,
                              hipStream_t stream) {
    const float* ev_f  = (const float*)d_in[0];
    const float* cs_f  = (const float*)d_in[1];
    const float* tr_f  = (const float*)d_in[2];
    const float* env_f = (const float*)d_in[3];
    const int*   ei    = (const int*)d_in[4];
    const int*   ev_i  = (const int*)d_in[5];
    const int*   cs_i  = (const int*)d_in[6];
    const int*   tr_i  = (const int*)d_in[7];
    const int*   env_i = (const int*)d_in[8];
    const int*   batch = (const int*)d_in[9];
    const float* W_ev = (const float*)d_in[10]; const float* b_ev = (const float*)d_in[11];
    const float* W_cs = (const float*)d_in[12]; const float* b_cs = (const float*)d_in[13];
    const float* W_tr = (const float*)d_in[14]; const float* b_tr = (const float*)d_in[15];
    const float* W_env= (const float*)d_in[16]; const float* b_env= (const float*)d_in[17];
    const float* W1 = (const float*)d_in[18]; const float* b1 = (const float*)d_in[19];
    const float* W2 = (const float*)d_in[20]; const float* b2 = (const float*)d_in[21];
    const float* W3 = (const float*)d_in[22]; const float* b3 = (const float*)d_in[23];

    const int E_ = in_sizes[4] / 2;
    const int N_ = in_sizes[9];
    const int n_ev  = in_sizes[5];
    const int n_cs  = in_sizes[6];
    const int n_tr  = in_sizes[7];
    const int n_env = in_sizes[8];
    const int ngr   = out_size / 64;  // 100 graphs

    const int* e_src = ei;
    const int* e_dst = ei + E_;

    const int NB   = (N_ + (1 << BINSHIFT) - 1) >> BINSHIFT;  // 391 bins
    const int ablk = (E_ + EPBA - 1) / EPBA;                  // 782 partition blocks

    // ---- workspace carve-up ----
    char* p = (char*)d_ws;
    int*      counts = (int*)p;      p += alignup((size_t)NB * ablk * 4);
    int*      bintot = (int*)p;      p += alignup((size_t)NB * 4);
    int*      binptr = (int*)p;      p += alignup(((size_t)NB + 1) * 4);
    int*      rowptr = (int*)p;      p += alignup(((size_t)N_ + 1) * 4);
    float*    dinv   = (float*)p;    p += alignup((size_t)N_ * 4);
    int*      srcs   = (int*)p;      p += alignup((size_t)E_ * 4);
    unsigned* xb     = (unsigned*)p; p += alignup((size_t)N_ * 16 * 4);   // bf16 [N,32]
    unsigned* x1b    = (unsigned*)p; p += alignup((size_t)N_ * 32 * 4);   // bf16 [N,64] raw x1
    unsigned* x1s_bf = (unsigned*)p; p += alignup((size_t)N_ * 32 * 4);   // bf16 conv2 table
    unsigned* aggb   = (unsigned*)p; p += alignup((size_t)N_ * 32 * 4);   // bf16 gather out
    unsigned* hA     = (unsigned*)p; p += alignup((size_t)N_ * 64 * 4);   // bf16 [N,128] mm2 out
    unsigned* t3s_bf = (unsigned*)p; p += alignup((size_t)N_ * 32 * 4);   // bf16 conv3 table
    unsigned* hfb    = (unsigned*)p; p += alignup((size_t)N_ * 32 * 4);   // bf16 pool input
    unsigned* wt     = (unsigned*)p; p += alignup((size_t)9216 * 4);      // all W^T bf16
    float*    sums   = (float*)p;    p += alignup((size_t)ngr * 64 * 4);
    float*    cnts   = (float*)p;    p += alignup((size_t)ngr * 4);

    unsigned* w1t = wt;
    unsigned* w2t = wt + 1024;
    unsigned* w3t = wt + 5120;

    // pairs (E u32 = 12.8MB) aliases hA (25.6MB): dead at k_bincsr, hA first
    // written by mm2 (after bincsr).
    unsigned* pairs = hA;

    const int nblk  = (N_ + THREADS - 1) / THREADS;
    const int mfblk = (N_ + 63) / 64;                               // 64 rows/block
    const int gblk  = ((size_t)N_ * 64 + THREADS - 1) / THREADS;    // wave/node

    // ---- zero accumulated buffers (fresh every call) ----
    hipMemsetAsync(sums, 0, (size_t)ngr * 64 * 4, stream);
    hipMemsetAsync(cnts, 0, (size_t)ngr * 4, stream);

    // ---- CSR build (atomic-free partition) ----
    k_partcnt<<<ablk, THREADS, (size_t)NB * 4, stream>>>(e_dst, counts, ablk, NB, E_);
    k_scanrows<<<NB, THREADS, 0, stream>>>(counts, bintot, ablk);
    k_binscan<<<1, 512, 0, stream>>>(bintot, binptr, NB, E_);
    k_partwrite<<<ablk, THREADS, (size_t)NB * 8, stream>>>(e_src, e_dst, binptr, counts, ablk, pairs, NB, E_);
    k_bincsr<<<NB, THREADS, 0, stream>>>(pairs, binptr, rowptr, dinv, srcs, N_, NB, E_);

    // ---- weight prep (one tiny kernel) ----
    k_wprep_all<<<(9216 + THREADS - 1) / THREADS, THREADS, 0, stream>>>(W1, W2, W3, wt);

    // ---- embeddings -> xb [N,32] bf16 (pre-scaled by dinv), one kernel ----
    EmbedArgs ea;
    ea.f[0] = ev_f;  ea.f[1] = cs_f;  ea.f[2] = tr_f;  ea.f[3] = env_f;
    ea.W[0] = W_ev;  ea.W[1] = W_cs;  ea.W[2] = W_tr;  ea.W[3] = W_env;
    ea.b[0] = b_ev;  ea.b[1] = b_cs;  ea.b[2] = b_tr;  ea.b[3] = b_env;
    ea.idx[0] = ev_i; ea.idx[1] = cs_i; ea.idx[2] = tr_i; ea.idx[3] = env_i;
    ea.cum[0] = 0;
    ea.cum[1] = n_ev;
    ea.cum[2] = n_ev + n_cs;
    ea.cum[3] = n_ev + n_cs + n_tr;
    ea.cum[4] = n_ev + n_cs + n_tr + n_env;
    ea.Kv[0] = in_sizes[0] / n_ev;
    ea.Kv[1] = in_sizes[1] / n_cs;
    ea.Kv[2] = in_sizes[2] / n_tr;
    ea.Kv[3] = in_sizes[3] / n_env;
    k_embed_all<<<((size_t)ea.cum[4] * 16 + THREADS - 1) / THREADS, THREADS, 0, stream>>>(ea, dinv, xb);

    // ---- conv1: agg(xb) -> aggb bf16; mm1: x1b=bf16(x1), x1s_bf=bf16(dinv*relu(x1)) ----
    k_gather32<<<gblk, THREADS, 0, stream>>>(xb, rowptr, srcs, dinv, aggb, N_);
    k_mmfa<32, 64, 1><<<mfblk, THREADS, 0, stream>>>(aggb, w1t, b1, dinv, x1b, x1s_bf, N_);

    // ---- conv2: agg(x1s_bf) -> aggb bf16; mm2: relu(@W2+b2) -> hA bf16 [N,128] ----
    k_gather64<false, false, false, true><<<gblk, THREADS, 0, stream>>>(
        x1s_bf, rowptr, srcs, dinv, nullptr, nullptr, aggb, N_);
    k_mmfa<64, 128, 3><<<mfblk, THREADS, 0, stream>>>(aggb, w2t, b2, nullptr, hA, nullptr, N_);

    // ---- conv3: mm3: t3s_bf = bf16(dinv*(hA @ W3)); gather3: relu(agg+b3)+x1b -> hfb bf16 ----
    k_mmfa<128, 64, 2><<<mfblk, THREADS, 0, stream>>>(hA, w3t, nullptr, dinv, t3s_bf, nullptr, N_);
    k_gather64<true, true, true, true><<<gblk, THREADS, 0, stream>>>(
        t3s_bf, rowptr, srcs, dinv, b3, x1b, hfb, N_);

    // ---- pool ----
    k_pool<<<nblk, THREADS, 0, stream>>>(hfb, batch, sums, cnts, N_);
    k_div<<<(out_size + THREADS - 1) / THREADS, THREADS, 0, stream>>>(sums, cnts, (float*)d_out, out_size);
}

// Round 13
// 353.258 us; speedup vs baseline: 1.7303x; 1.0174x over previous
//
#include <hip/hip_runtime.h>
#include <hip/hip_bf16.h>

// ---------------------------------------------------------------------------
// GNN Residual Feature Extractor
//   x = embed(type features)                       [N,32]
//   x1 = gcn(x, W1)+b1                             [N,64]
//   h  = relu(gcn(relu(x1),W2)+b2)                 [N,128]
//   h  = relu(gcn(h,W3)+b3) + x1                   [N,64]
//   out = segment_mean(h, batch)                   [100,64]
//
// gcn agg commutes with weight multiply; aggregate on narrow side.
// ALL N-wide intermediates are packed bf16; f32 accumulation.
// Gather tables pre-scaled by dinv / pre-activated by producers.
//
// CSR build: atomic-free two-pass radix partition, BINSHIFT=8.
// R13: k_partwrite LDS-staged (sub-line 42B runs -> dense coalesced flush,
// zero global atomics), EPBA 8192; gathers reverted to R11 16-edge loop
// (R12's 32-edge unroll measured slightly worse: 63.6 -> 65us).
// mm via MFMA swapped-operand (R10).
// ---------------------------------------------------------------------------

#define THREADS 256
#define BINSHIFT 8
#define EPBA 8192        // edges per partition block
#define SCANCH 8         // k_scanrows: values per thread (<=2048 blocks)
#define NBMAX 416        // >= number of bins (391)

typedef __attribute__((ext_vector_type(8))) short short8;
typedef __attribute__((ext_vector_type(4))) float f32x4;

// ---------------- bf16 helpers ----------------
__device__ __forceinline__ unsigned bfpack2(float lo, float hi) {
    unsigned ul = __float_as_uint(lo);
    unsigned uh = __float_as_uint(hi);
    ul = (ul + 0x7fffu + ((ul >> 16) & 1u)) >> 16;          // rne, low half
    uh = (uh + 0x7fffu + ((uh >> 16) & 1u)) & 0xffff0000u;  // rne, high half
    return ul | uh;
}

__device__ __forceinline__ void bfacc(uint2 v, float& a0, float& a1,
                                      float& a2, float& a3) {
    a0 += __uint_as_float(v.x << 16);
    a1 += __uint_as_float(v.x & 0xffff0000u);
    a2 += __uint_as_float(v.y << 16);
    a3 += __uint_as_float(v.y & 0xffff0000u);
}

__device__ __forceinline__ short8 as_short8(uint4 u) {
    union { uint4 u; short8 s; } c; c.u = u; return c.s;
}

// ---------------- pass 1: per-(block,bin) exact counts ----------------
__global__ __launch_bounds__(THREADS)
void k_partcnt(const int* __restrict__ dst, int* __restrict__ counts,
               int nblk_part, int nb, int e) {
    extern __shared__ int h[];
    int t = threadIdx.x;
    for (int i = t; i < nb; i += THREADS) h[i] = 0;
    __syncthreads();
    int lo = blockIdx.x * EPBA;
    int hi = min(lo + EPBA, e);
    for (int i = lo + t; i < hi; i += THREADS)
        atomicAdd(&h[dst[i] >> BINSHIFT], 1);
    __syncthreads();
    for (int i = t; i < nb; i += THREADS)
        counts[(size_t)i * nblk_part + blockIdx.x] = h[i];
}

// ---------------- scan each bin's row of per-block counts ----------------
__global__ __launch_bounds__(THREADS)
void k_scanrows(int* __restrict__ counts, int* __restrict__ bintot, int nblk_part) {
    __shared__ int wsum[THREADS];
    int* row = counts + (size_t)blockIdx.x * nblk_part;
    int t = threadIdx.x;
    int base = t * SCANCH;
    int v[SCANCH];
    int s = 0;
#pragma unroll
    for (int k = 0; k < SCANCH; ++k) {
        v[k] = (base + k < nblk_part) ? row[base + k] : 0;
        s += v[k];
    }
    wsum[t] = s;
    __syncthreads();
    for (int off = 1; off < THREADS; off <<= 1) {
        int a = (t >= off) ? wsum[t - off] : 0;
        __syncthreads();
        wsum[t] += a;
        __syncthreads();
    }
    int run = wsum[t] - s;  // exclusive
#pragma unroll
    for (int k = 0; k < SCANCH; ++k) {
        int c = v[k];
        if (base + k < nblk_part) row[base + k] = run;
        run += c;
    }
    if (t == THREADS - 1) bintot[blockIdx.x] = run;
}

// ---------------- scan bin totals (single block, nb<=512) ----------------
__global__ __launch_bounds__(512)
void k_binscan(const int* __restrict__ bintot, int* __restrict__ binptr,
               int nb, int e) {
    __shared__ int lds[512];
    int t = threadIdx.x;
    int v = (t < nb) ? bintot[t] : 0;
    lds[t] = v;
    __syncthreads();
    for (int off = 1; off < 512; off <<= 1) {
        int a = (t >= off) ? lds[t - off] : 0;
        __syncthreads();
        lds[t] += a;
        __syncthreads();
    }
    if (t < nb) binptr[t] = lds[t] - v;  // exclusive
    if (t == 0) binptr[nb] = e;
}

// ---------------- pass 2: LDS-staged deterministic partition write ----------
// Stage all EPBA edges bin-contiguously in LDS, then flush each bin's run
// coalesced to its deterministic global range. Zero global atomics; global
// writes are dense line-filling runs (vs 42B scattered sub-line runs).
__global__ __launch_bounds__(THREADS)
void k_partwrite(const int* __restrict__ src, const int* __restrict__ dst,
                 const int* __restrict__ binptr, const int* __restrict__ counts,
                 int nblk_part, unsigned* __restrict__ pairs, int nb, int e) {
    __shared__ int hist[NBMAX];
    __shared__ int lbase[NBMAX];
    __shared__ int gbase[NBMAX];
    __shared__ int cur[NBMAX];
    __shared__ int wsum[THREADS];
    __shared__ unsigned stage[EPBA];
    int t = threadIdx.x;
    for (int i = t; i < nb; i += THREADS) hist[i] = 0;
    __syncthreads();
    int lo = blockIdx.x * EPBA;
    int hi = min(lo + EPBA, e);
    for (int i = lo + t; i < hi; i += THREADS)
        atomicAdd(&hist[dst[i] >> BINSHIFT], 1);
    __syncthreads();
    // exclusive scan of hist[0..nb) -> lbase (2 values per thread covers 512)
    int v0 = (2 * t < nb) ? hist[2 * t] : 0;
    int v1 = (2 * t + 1 < nb) ? hist[2 * t + 1] : 0;
    int s = v0 + v1;
    wsum[t] = s;
    __syncthreads();
    for (int off = 1; off < THREADS; off <<= 1) {
        int a = (t >= off) ? wsum[t - off] : 0;
        __syncthreads();
        wsum[t] += a;
        __syncthreads();
    }
    int excl = wsum[t] - s;
    if (2 * t < nb) { lbase[2 * t] = excl; cur[2 * t] = excl; }
    if (2 * t + 1 < nb) { lbase[2 * t + 1] = excl + v0; cur[2 * t + 1] = excl + v0; }
    for (int i = t; i < nb; i += THREADS)
        gbase[i] = binptr[i] + counts[(size_t)i * nblk_part + blockIdx.x];
    __syncthreads();
    // scatter into LDS stage (bin-contiguous)
    for (int i = lo + t; i < hi; i += THREADS) {
        int s2 = src[i], d = dst[i];
        int b = d >> BINSHIFT;
        int pos = atomicAdd(&cur[b], 1);   // LDS only
        stage[pos] = ((unsigned)s2 << BINSHIFT) | (unsigned)(d & ((1 << BINSHIFT) - 1));
    }
    __syncthreads();
    // flush: wave per bin (strided), coalesced runs
    int wid = t >> 6, lane = t & 63;
    for (int b = wid; b < nb; b += (THREADS / 64)) {
        int n = hist[b];
        int lb = lbase[b];
        int gb = gbase[b];
        for (int k = lane; k < n; k += 64)
            pairs[gb + k] = stage[lb + k];
    }
}

// ---------------- per-bin CSR finalize (256-node bins) ----------------
__global__ __launch_bounds__(THREADS)
void k_bincsr(const unsigned* __restrict__ pairs, const int* __restrict__ binptr,
              int* __restrict__ rowptr, float* __restrict__ dinv,
              int* __restrict__ srcs, int n, int nb, int e) {
    __shared__ int lcnt[256];
    __shared__ int lofs[256];
    int b = blockIdx.x, t = threadIdx.x;
    int e0 = binptr[b], e1 = binptr[b + 1];
    int n0 = b << BINSHIFT;
    constexpr unsigned NMASK = (1u << BINSHIFT) - 1u;
    lcnt[t] = 0;
    __syncthreads();
    for (int j = e0 + t; j < e1; j += THREADS)
        atomicAdd(&lcnt[pairs[j] & NMASK], 1);
    __syncthreads();
    int c = lcnt[t];
    lofs[t] = c;
    __syncthreads();
    for (int off = 1; off < THREADS; off <<= 1) {
        int a = (t >= off) ? lofs[t - off] : 0;
        __syncthreads();
        lofs[t] += a;
        __syncthreads();
    }
    int excl = lofs[t] - c;
    __syncthreads();
    lofs[t] = excl;
    int node = n0 + t;
    if (node < n) {
        rowptr[node] = e0 + excl;
        dinv[node] = rsqrtf((float)c + 1.0f);
    }
    if (b == nb - 1 && t == 0) rowptr[n] = e;
    __syncthreads();
    for (int j = e0 + t; j < e1; j += THREADS) {
        unsigned pp = pairs[j];
        int pos = e0 + atomicAdd(&lofs[pp & NMASK], 1);
        srcs[pos] = (int)(pp >> BINSHIFT);
    }
}

// ---------------- merged embedding (all 4 node types) ----------------
struct EmbedArgs {
    const float* f[4];
    const float* W[4];
    const float* b[4];
    const int*   idx[4];
    int cum[5];
    int Kv[4];
};

__global__ __launch_bounds__(THREADS)
void k_embed_all(EmbedArgs ea, const float* __restrict__ dinv,
                 unsigned* __restrict__ xb) {
    int g = blockIdx.x * THREADS + threadIdx.x;
    int row = g >> 4, cp = g & 15;
    if (row >= ea.cum[4]) return;
    int t = (row >= ea.cum[1]) + (row >= ea.cum[2]) + (row >= ea.cum[3]);
    int r = row - ea.cum[t];
    int K = ea.Kv[t];
    const float* f  = ea.f[t];
    const float* W  = ea.W[t];
    const float* bb = ea.b[t];
    int node = ea.idx[t][r];
    float dv = dinv[node];
    float a0 = bb[2 * cp], a1 = bb[2 * cp + 1];
    for (int k = 0; k < K; ++k) {
        float fv = f[r * K + k];
        a0 += fv * W[k * 32 + 2 * cp];
        a1 += fv * W[k * 32 + 2 * cp + 1];
    }
    xb[(size_t)node * 16 + cp] = bfpack2(dv * a0, dv * a1);
}

// ---------------- gather (bf16 table, row=128B): one wave per node ----------
// 4 quarter-groups of 16 lanes; each quarter owns one edge's full row.
// 16-edge main loop (R11-proven; 32-edge measured worse in R12).
template <bool HASBIAS, bool OUTRELU, bool HASRES, bool OUTBF>
__global__ __launch_bounds__(THREADS)
void k_gather64(const unsigned* __restrict__ tblb, const int* __restrict__ rowptr,
                const int* __restrict__ srcs, const float* __restrict__ dinv,
                const float* __restrict__ bias, const unsigned* __restrict__ resid,
                void* __restrict__ outp, int n) {
    int gt = blockIdx.x * THREADS + threadIdx.x;
    int node = gt >> 6;
    int lane = threadIdx.x & 63;
    if (node >= n) return;
    int qw = lane >> 4, li = lane & 15;
    const uint2* t2 = reinterpret_cast<const uint2*>(tblb);
    float a0 = 0.f, a1 = 0.f, a2 = 0.f, a3 = 0.f;
    int beg = rowptr[node], end = rowptr[node + 1];
    int j = beg;
    for (; j + 16 <= end; j += 16) {          // 16 edges, 4 rows in flight
        int i0 = srcs[j + qw];
        int i1 = srcs[j + 4 + qw];
        int i2 = srcs[j + 8 + qw];
        int i3 = srcs[j + 12 + qw];
        uint2 v0 = t2[(size_t)i0 * 16 + li];
        uint2 v1 = t2[(size_t)i1 * 16 + li];
        uint2 v2 = t2[(size_t)i2 * 16 + li];
        uint2 v3 = t2[(size_t)i3 * 16 + li];
        bfacc(v0, a0, a1, a2, a3);
        bfacc(v1, a0, a1, a2, a3);
        bfacc(v2, a0, a1, a2, a3);
        bfacc(v3, a0, a1, a2, a3);
    }
    for (; j + 8 <= end; j += 8) {
        int i0 = srcs[j + qw];
        int i1 = srcs[j + 4 + qw];
        uint2 v0 = t2[(size_t)i0 * 16 + li];
        uint2 v1 = t2[(size_t)i1 * 16 + li];
        bfacc(v0, a0, a1, a2, a3);
        bfacc(v1, a0, a1, a2, a3);
    }
    int rem = end - j;
    if (qw < rem) {
        uint2 v = t2[(size_t)srcs[j + qw] * 16 + li];
        bfacc(v, a0, a1, a2, a3);
    }
    if (qw + 4 < rem) {
        uint2 v = t2[(size_t)srcs[j + 4 + qw] * 16 + li];
        bfacc(v, a0, a1, a2, a3);
    }
    a0 += __shfl_down(a0, 32, 64); a1 += __shfl_down(a1, 32, 64);
    a2 += __shfl_down(a2, 32, 64); a3 += __shfl_down(a3, 32, 64);
    a0 += __shfl_down(a0, 16, 64); a1 += __shfl_down(a1, 16, 64);
    a2 += __shfl_down(a2, 16, 64); a3 += __shfl_down(a3, 16, 64);
    if (lane < 16) {
        uint2 sv = t2[(size_t)node * 16 + li];
        bfacc(sv, a0, a1, a2, a3);
        float dv = dinv[node];
        float r0 = dv * a0, r1 = dv * a1, r2 = dv * a2, r3 = dv * a3;
        if (HASBIAS) {
            float4 bv = *reinterpret_cast<const float4*>(bias + 4 * li);
            r0 += bv.x; r1 += bv.y; r2 += bv.z; r3 += bv.w;
        }
        if (OUTRELU) {
            r0 = fmaxf(r0, 0.f); r1 = fmaxf(r1, 0.f);
            r2 = fmaxf(r2, 0.f); r3 = fmaxf(r3, 0.f);
        }
        if (HASRES) {
            uint2 rv = reinterpret_cast<const uint2*>(resid)[(size_t)node * 16 + li];
            bfacc(rv, r0, r1, r2, r3);
        }
        if (OUTBF) {
            uint2 o = {bfpack2(r0, r1), bfpack2(r2, r3)};
            reinterpret_cast<uint2*>(outp)[(size_t)node * 16 + li] = o;
        } else {
            float4 o = {r0, r1, r2, r3};
            reinterpret_cast<float4*>(outp)[(size_t)node * 16 + li] = o;
        }
    }
}

// ---------------- gather (bf16 table, row=64B): 8 groups of 8 lanes ---------
__global__ __launch_bounds__(THREADS)
void k_gather32(const unsigned* __restrict__ tblb, const int* __restrict__ rowptr,
                const int* __restrict__ srcs, const float* __restrict__ dinv,
                unsigned* __restrict__ outb, int n) {
    int gt = blockIdx.x * THREADS + threadIdx.x;
    int node = gt >> 6;
    int lane = threadIdx.x & 63;
    if (node >= n) return;
    int og = lane >> 3, li = lane & 7;
    const uint2* t2 = reinterpret_cast<const uint2*>(tblb);
    float a0 = 0.f, a1 = 0.f, a2 = 0.f, a3 = 0.f;
    int beg = rowptr[node], end = rowptr[node + 1];
    int j = beg;
    for (; j + 16 <= end; j += 16) {          // 16 edges, 2 rows in flight/lane
        int i0 = srcs[j + og];
        int i1 = srcs[j + 8 + og];
        uint2 v0 = t2[(size_t)i0 * 8 + li];
        uint2 v1 = t2[(size_t)i1 * 8 + li];
        bfacc(v0, a0, a1, a2, a3);
        bfacc(v1, a0, a1, a2, a3);
    }
    for (; j + 8 <= end; j += 8) {
        int i0 = srcs[j + og];
        uint2 v0 = t2[(size_t)i0 * 8 + li];
        bfacc(v0, a0, a1, a2, a3);
    }
    int rem = end - j;
    if (og < rem) {
        uint2 v = t2[(size_t)srcs[j + og] * 8 + li];
        bfacc(v, a0, a1, a2, a3);
    }
    a0 += __shfl_down(a0, 32, 64); a1 += __shfl_down(a1, 32, 64);
    a2 += __shfl_down(a2, 32, 64); a3 += __shfl_down(a3, 32, 64);
    a0 += __shfl_down(a0, 16, 64); a1 += __shfl_down(a1, 16, 64);
    a2 += __shfl_down(a2, 16, 64); a3 += __shfl_down(a3, 16, 64);
    a0 += __shfl_down(a0, 8, 64);  a1 += __shfl_down(a1, 8, 64);
    a2 += __shfl_down(a2, 8, 64);  a3 += __shfl_down(a3, 8, 64);
    if (lane < 8) {
        uint2 sv = t2[(size_t)node * 8 + li];
        bfacc(sv, a0, a1, a2, a3);
        float dv = dinv[node];
        uint2 o = {bfpack2(dv * a0, dv * a1), bfpack2(dv * a2, dv * a3)};
        reinterpret_cast<uint2*>(outb)[(size_t)node * 8 + li] = o;
    }
}

// ---------------- merged weight prep: all three W^T bf16 tables --------------
// wt layout: [0,1024) = W1t (64x[32]), [1024,5120) = W2t (128x[64]),
//            [5120,9216) = W3t (64x[128])   (u32 = 2 bf16 each)
__global__ __launch_bounds__(THREADS)
void k_wprep_all(const float* __restrict__ W1, const float* __restrict__ W2,
                 const float* __restrict__ W3, unsigned* __restrict__ wt) {
    int g = blockIdx.x * THREADS + threadIdx.x;
    if (g < 1024) {
        int nn = g >> 4, kq = g & 15;
        wt[g] = bfpack2(W1[(size_t)(2 * kq) * 64 + nn], W1[(size_t)(2 * kq + 1) * 64 + nn]);
    } else if (g < 5120) {
        int gg = g - 1024;
        int nn = gg >> 5, kq = gg & 31;
        wt[g] = bfpack2(W2[(size_t)(2 * kq) * 128 + nn], W2[(size_t)(2 * kq + 1) * 128 + nn]);
    } else if (g < 9216) {
        int gg = g - 5120;
        int nn = gg >> 6, kq = gg & 63;
        wt[g] = bfpack2(W3[(size_t)(2 * kq) * 64 + nn], W3[(size_t)(2 * kq + 1) * 64 + nn]);
    }
}

// ---------------- MFMA dense matmul ------------------------------------------
// out[node][FOUT] = row(xinb bf16) @ W + b via mfma_f32_16x16x32_bf16 with
// SWAPPED operands: A = Wt tiles (M=outcols), B = node rows (N=16 nodes).
// EXTRA: 1 = outb=bf16(v+b), outb2=bf16(dinv*relu(v+b))   [mm1]
//        2 = outb=bf16(dinv*v)                             [mm3]
//        3 = outb=bf16(relu(v+b))                          [mm2]
template <int FIN, int FOUT, int EXTRA>
__global__ __launch_bounds__(THREADS)
void k_mmfa(const unsigned* __restrict__ xinb, const unsigned* __restrict__ wtb,
            const float* __restrict__ bias, const float* __restrict__ dinv,
            unsigned* __restrict__ outb, unsigned* __restrict__ outb2, int nrows) {
    constexpr int FH = FIN / 2;   // u32 per row
    constexpr int KS = FIN / 32;  // K-steps
    constexpr int MT = FOUT / 16; // out-col tiles
    int tid = threadIdx.x;
    int lane = tid & 63;
    int lg = lane >> 4, li = lane & 15;
    int node = blockIdx.x * 64 + (tid >> 6) * 16 + li;
    int nc = min(node, nrows - 1);

    const uint4* xr = reinterpret_cast<const uint4*>(xinb + (size_t)nc * FH);
    short8 bf[KS];
#pragma unroll
    for (int ks = 0; ks < KS; ++ks) bf[ks] = as_short8(xr[ks * 4 + lg]);

    f32x4 acc[MT];
#pragma unroll
    for (int mt = 0; mt < MT; ++mt) acc[mt] = (f32x4){0.f, 0.f, 0.f, 0.f};

#pragma unroll
    for (int ks = 0; ks < KS; ++ks) {
#pragma unroll
        for (int mt = 0; mt < MT; ++mt) {
            uint4 wu = *reinterpret_cast<const uint4*>(
                wtb + (size_t)(mt * 16 + li) * FH + ks * 16 + lg * 4);
            acc[mt] = __builtin_amdgcn_mfma_f32_16x16x32_bf16(
                as_short8(wu), bf[ks], acc[mt], 0, 0, 0);
        }
    }

    if (node >= nrows) return;
    float dv = (EXTRA != 3) ? dinv[node] : 0.f;
#pragma unroll
    for (int mt = 0; mt < MT; ++mt) {
        float v0 = acc[mt][0], v1 = acc[mt][1], v2 = acc[mt][2], v3 = acc[mt][3];
        int m0 = mt * 16 + lg * 4;
        if (EXTRA == 1 || EXTRA == 3) {
            float4 bv = *reinterpret_cast<const float4*>(bias + m0);
            v0 += bv.x; v1 += bv.y; v2 += bv.z; v3 += bv.w;
        }
        size_t ob = (size_t)node * (FOUT / 2) + mt * 8 + lg * 2;
        if (EXTRA == 1) {
            uint2 o = {bfpack2(v0, v1), bfpack2(v2, v3)};
            *reinterpret_cast<uint2*>(outb + ob) = o;
            uint2 s = {bfpack2(dv * fmaxf(v0, 0.f), dv * fmaxf(v1, 0.f)),
                       bfpack2(dv * fmaxf(v2, 0.f), dv * fmaxf(v3, 0.f))};
            *reinterpret_cast<uint2*>(outb2 + ob) = s;
        }
        if (EXTRA == 3) {
            uint2 o = {bfpack2(fmaxf(v0, 0.f), fmaxf(v1, 0.f)),
                       bfpack2(fmaxf(v2, 0.f), fmaxf(v3, 0.f))};
            *reinterpret_cast<uint2*>(outb + ob) = o;
        }
        if (EXTRA == 2) {
            uint2 o = {bfpack2(dv * v0, dv * v1), bfpack2(dv * v2, dv * v3)};
            *reinterpret_cast<uint2*>(outb + ob) = o;
        }
    }
}

// ---------------- segment mean pool (bf16 input) ----------------
__global__ __launch_bounds__(THREADS)
void k_pool(const unsigned* __restrict__ hb, const int* __restrict__ batch,
            float* __restrict__ sums, float* __restrict__ cnts, int n) {
    int c = threadIdx.x & 31;          // u32 column (2 bf16)
    int rq = threadIdx.x >> 5;         // 0..7
    int r0 = blockIdx.x * THREADS;     // 256 rows per block
    int rend = min(r0 + THREADS, n);
    int curg = -1;
    float a0 = 0.f, a1 = 0.f, cacc = 0.f;
    for (int r = r0 + rq; r < rend; r += 8) {
        int g = batch[r];
        if (g != curg) {
            if (curg >= 0) {
                atomicAdd(&sums[(size_t)curg * 64 + 2 * c], a0);
                atomicAdd(&sums[(size_t)curg * 64 + 2 * c + 1], a1);
                if (c == 0) atomicAdd(&cnts[curg], cacc);
            }
            curg = g; a0 = 0.f; a1 = 0.f; cacc = 0.f;
        }
        unsigned u = hb[(size_t)r * 32 + c];
        a0 += __uint_as_float(u << 16);
        a1 += __uint_as_float(u & 0xffff0000u);
        cacc += 1.f;
    }
    if (curg >= 0) {
        atomicAdd(&sums[(size_t)curg * 64 + 2 * c], a0);
        atomicAdd(&sums[(size_t)curg * 64 + 2 * c + 1], a1);
        if (c == 0) atomicAdd(&cnts[curg], cacc);
    }
}

__global__ __launch_bounds__(THREADS)
void k_div(const float* __restrict__ sums, const float* __restrict__ cnts,
           float* __restrict__ out, int total) {
    int i = blockIdx.x * THREADS + threadIdx.x;
    if (i < total) out[i] = sums[i] / cnts[i >> 6];
}

// ---------------------------------------------------------------------------
static inline size_t alignup(size_t v) { return (v + 255) & ~(size_t)255; }

extern "C" void kernel_launch(void* const* d_in, const int* in_sizes, int n_in,
                              void* d_out, int out_size, void* d_ws, size_t ws_size,
                              hipStream_t stream) {
    const float* ev_f  = (const float*)d_in[0];
    const float* cs_f  = (const float*)d_in[1];
    const float* tr_f  = (const float*)d_in[2];
    const float* env_f = (const float*)d_in[3];
    const int*   ei    = (const int*)d_in[4];
    const int*   ev_i  = (const int*)d_in[5];
    const int*   cs_i  = (const int*)d_in[6];
    const int*   tr_i  = (const int*)d_in[7];
    const int*   env_i = (const int*)d_in[8];
    const int*   batch = (const int*)d_in[9];
    const float* W_ev = (const float*)d_in[10]; const float* b_ev = (const float*)d_in[11];
    const float* W_cs = (const float*)d_in[12]; const float* b_cs = (const float*)d_in[13];
    const float* W_tr = (const float*)d_in[14]; const float* b_tr = (const float*)d_in[15];
    const float* W_env= (const float*)d_in[16]; const float* b_env= (const float*)d_in[17];
    const float* W1 = (const float*)d_in[18]; const float* b1 = (const float*)d_in[19];
    const float* W2 = (const float*)d_in[20]; const float* b2 = (const float*)d_in[21];
    const float* W3 = (const float*)d_in[22]; const float* b3 = (const float*)d_in[23];

    const int E_ = in_sizes[4] / 2;
    const int N_ = in_sizes[9];
    const int n_ev  = in_sizes[5];
    const int n_cs  = in_sizes[6];
    const int n_tr  = in_sizes[7];
    const int n_env = in_sizes[8];
    const int ngr   = out_size / 64;  // 100 graphs

    const int* e_src = ei;
    const int* e_dst = ei + E_;

    const int NB   = (N_ + (1 << BINSHIFT) - 1) >> BINSHIFT;  // 391 bins
    const int ablk = (E_ + EPBA - 1) / EPBA;                  // 391 partition blocks

    // ---- workspace carve-up ----
    char* p = (char*)d_ws;
    int*      counts = (int*)p;      p += alignup((size_t)NB * ablk * 4);
    int*      bintot = (int*)p;      p += alignup((size_t)NB * 4);
    int*      binptr = (int*)p;      p += alignup(((size_t)NB + 1) * 4);
    int*      rowptr = (int*)p;      p += alignup(((size_t)N_ + 1) * 4);
    float*    dinv   = (float*)p;    p += alignup((size_t)N_ * 4);
    int*      srcs   = (int*)p;      p += alignup((size_t)E_ * 4);
    unsigned* xb     = (unsigned*)p; p += alignup((size_t)N_ * 16 * 4);   // bf16 [N,32]
    unsigned* x1b    = (unsigned*)p; p += alignup((size_t)N_ * 32 * 4);   // bf16 [N,64] raw x1
    unsigned* x1s_bf = (unsigned*)p; p += alignup((size_t)N_ * 32 * 4);   // bf16 conv2 table
    unsigned* aggb   = (unsigned*)p; p += alignup((size_t)N_ * 32 * 4);   // bf16 gather out
    unsigned* hA     = (unsigned*)p; p += alignup((size_t)N_ * 64 * 4);   // bf16 [N,128] mm2 out
    unsigned* t3s_bf = (unsigned*)p; p += alignup((size_t)N_ * 32 * 4);   // bf16 conv3 table
    unsigned* hfb    = (unsigned*)p; p += alignup((size_t)N_ * 32 * 4);   // bf16 pool input
    unsigned* wt     = (unsigned*)p; p += alignup((size_t)9216 * 4);      // all W^T bf16
    float*    sums   = (float*)p;    p += alignup((size_t)ngr * 64 * 4);
    float*    cnts   = (float*)p;    p += alignup((size_t)ngr * 4);

    unsigned* w1t = wt;
    unsigned* w2t = wt + 1024;
    unsigned* w3t = wt + 5120;

    // pairs (E u32 = 12.8MB) aliases hA (25.6MB): dead at k_bincsr, hA first
    // written by mm2 (after bincsr).
    unsigned* pairs = hA;

    const int nblk  = (N_ + THREADS - 1) / THREADS;
    const int mfblk = (N_ + 63) / 64;                               // 64 rows/block
    const int gblk  = ((size_t)N_ * 64 + THREADS - 1) / THREADS;    // wave/node

    // ---- zero accumulated buffers (fresh every call) ----
    hipMemsetAsync(sums, 0, (size_t)ngr * 64 * 4, stream);
    hipMemsetAsync(cnts, 0, (size_t)ngr * 4, stream);

    // ---- CSR build (atomic-free partition) ----
    k_partcnt<<<ablk, THREADS, (size_t)NB * 4, stream>>>(e_dst, counts, ablk, NB, E_);
    k_scanrows<<<NB, THREADS, 0, stream>>>(counts, bintot, ablk);
    k_binscan<<<1, 512, 0, stream>>>(bintot, binptr, NB, E_);
    k_partwrite<<<ablk, THREADS, 0, stream>>>(e_src, e_dst, binptr, counts, ablk, pairs, NB, E_);
    k_bincsr<<<NB, THREADS, 0, stream>>>(pairs, binptr, rowptr, dinv, srcs, N_, NB, E_);

    // ---- weight prep (one tiny kernel) ----
    k_wprep_all<<<(9216 + THREADS - 1) / THREADS, THREADS, 0, stream>>>(W1, W2, W3, wt);

    // ---- embeddings -> xb [N,32] bf16 (pre-scaled by dinv), one kernel ----
    EmbedArgs ea;
    ea.f[0] = ev_f;  ea.f[1] = cs_f;  ea.f[2] = tr_f;  ea.f[3] = env_f;
    ea.W[0] = W_ev;  ea.W[1] = W_cs;  ea.W[2] = W_tr;  ea.W[3] = W_env;
    ea.b[0] = b_ev;  ea.b[1] = b_cs;  ea.b[2] = b_tr;  ea.b[3] = b_env;
    ea.idx[0] = ev_i; ea.idx[1] = cs_i; ea.idx[2] = tr_i; ea.idx[3] = env_i;
    ea.cum[0] = 0;
    ea.cum[1] = n_ev;
    ea.cum[2] = n_ev + n_cs;
    ea.cum[3] = n_ev + n_cs + n_tr;
    ea.cum[4] = n_ev + n_cs + n_tr + n_env;
    ea.Kv[0] = in_sizes[0] / n_ev;
    ea.Kv[1] = in_sizes[1] / n_cs;
    ea.Kv[2] = in_sizes[2] / n_tr;
    ea.Kv[3] = in_sizes[3] / n_env;
    k_embed_all<<<((size_t)ea.cum[4] * 16 + THREADS - 1) / THREADS, THREADS, 0, stream>>>(ea, dinv, xb);

    // ---- conv1: agg(xb) -> aggb bf16; mm1: x1b=bf16(x1), x1s_bf=bf16(dinv*relu(x1)) ----
    k_gather32<<<gblk, THREADS, 0, stream>>>(xb, rowptr, srcs, dinv, aggb, N_);
    k_mmfa<32, 64, 1><<<mfblk, THREADS, 0, stream>>>(aggb, w1t, b1, dinv, x1b, x1s_bf, N_);

    // ---- conv2: agg(x1s_bf) -> aggb bf16; mm2: relu(@W2+b2) -> hA bf16 [N,128] ----
    k_gather64<false, false, false, true><<<gblk, THREADS, 0, stream>>>(
        x1s_bf, rowptr, srcs, dinv, nullptr, nullptr, aggb, N_);
    k_mmfa<64, 128, 3><<<mfblk, THREADS, 0, stream>>>(aggb, w2t, b2, nullptr, hA, nullptr, N_);

    // ---- conv3: mm3: t3s_bf = bf16(dinv*(hA @ W3)); gather3: relu(agg+b3)+x1b -> hfb bf16 ----
    k_mmfa<128, 64, 2><<<mfblk, THREADS, 0, stream>>>(hA, w3t, nullptr, dinv, t3s_bf, nullptr, N_);
    k_gather64<true, true, true, true><<<gblk, THREADS, 0, stream>>>(
        t3s_bf, rowptr, srcs, dinv, b3, x1b, hfb, N_);

    // ---- pool ----
    k_pool<<<nblk, THREADS, 0, stream>>>(hfb, batch, sums, cnts, N_);
    k_div<<<(out_size + THREADS - 1) / THREADS, THREADS, 0, stream>>>(sums, cnts, (float*)d_out, out_size);
}

// Round 15
// 349.698 us; speedup vs baseline: 1.7479x; 1.0102x over previous
//
#include <hip/hip_runtime.h>
#include <hip/hip_bf16.h>

// ---------------------------------------------------------------------------
// GNN Residual Feature Extractor
//   x = embed(type features)                       [N,32]
//   x1 = gcn(x, W1)+b1                             [N,64]
//   h  = relu(gcn(relu(x1),W2)+b2)                 [N,128]
//   h  = relu(gcn(h,W3)+b3) + x1                   [N,64]
//   out = segment_mean(h, batch)                   [100,64]
//
// gcn agg commutes with weight multiply; aggregate on narrow side.
// ALL N-wide intermediates are packed bf16; f32 accumulation.
// Gather tables pre-scaled by dinv / pre-activated by producers.
//
// CSR build: atomic-free two-pass radix partition, BINSHIFT=8, LDS-staged
// partwrite. srcs PRE-SCALED x8 (= row base in uint2 units for 32-col table
// AND in uint4 units for 64-col table: 64 bf16 = 8 uint4).
// R15: fixes R14's gather64 addressing bug (used src*4 not src*8 -> wrong
// rows, absmax 0.21). Keeps R14 structure: 8-lane groups x uint4 loads
// (1 load instr = 8 edges), v_pk_add_f32 accumulation.
// mm via MFMA swapped-operand (R10).
// ---------------------------------------------------------------------------

#define THREADS 256
#define BINSHIFT 8
#define EPBA 8192        // edges per partition block
#define SCANCH 8         // k_scanrows: values per thread (<=2048 blocks)
#define NBMAX 416        // >= number of bins (391)

typedef __attribute__((ext_vector_type(8))) short short8;
typedef __attribute__((ext_vector_type(4))) float f32x4;
typedef __attribute__((ext_vector_type(2))) float f32x2;

// ---------------- bf16 helpers ----------------
__device__ __forceinline__ unsigned bfpack2(float lo, float hi) {
    unsigned ul = __float_as_uint(lo);
    unsigned uh = __float_as_uint(hi);
    ul = (ul + 0x7fffu + ((ul >> 16) & 1u)) >> 16;          // rne, low half
    uh = (uh + 0x7fffu + ((uh >> 16) & 1u)) & 0xffff0000u;  // rne, high half
    return ul | uh;
}

// acc(pair) += unpack(u32 of 2 bf16)   — packed f32 add
__device__ __forceinline__ void pk2(f32x2& acc, unsigned u) {
    f32x2 v;
    v.x = __uint_as_float(u << 16);
    v.y = __uint_as_float(u & 0xffff0000u);
    asm("v_pk_add_f32 %0, %0, %1" : "+v"(acc) : "v"(v));
}

__device__ __forceinline__ short8 as_short8(uint4 u) {
    union { uint4 u; short8 s; } c; c.u = u; return c.s;
}

// ---------------- pass 1: per-(block,bin) exact counts ----------------
__global__ __launch_bounds__(THREADS)
void k_partcnt(const int* __restrict__ dst, int* __restrict__ counts,
               int nblk_part, int nb, int e) {
    extern __shared__ int h[];
    int t = threadIdx.x;
    for (int i = t; i < nb; i += THREADS) h[i] = 0;
    __syncthreads();
    int lo = blockIdx.x * EPBA;
    int hi = min(lo + EPBA, e);
    for (int i = lo + t; i < hi; i += THREADS)
        atomicAdd(&h[dst[i] >> BINSHIFT], 1);
    __syncthreads();
    for (int i = t; i < nb; i += THREADS)
        counts[(size_t)i * nblk_part + blockIdx.x] = h[i];
}

// ---------------- scan each bin's row of per-block counts ----------------
__global__ __launch_bounds__(THREADS)
void k_scanrows(int* __restrict__ counts, int* __restrict__ bintot, int nblk_part) {
    __shared__ int wsum[THREADS];
    int* row = counts + (size_t)blockIdx.x * nblk_part;
    int t = threadIdx.x;
    int base = t * SCANCH;
    int v[SCANCH];
    int s = 0;
#pragma unroll
    for (int k = 0; k < SCANCH; ++k) {
        v[k] = (base + k < nblk_part) ? row[base + k] : 0;
        s += v[k];
    }
    wsum[t] = s;
    __syncthreads();
    for (int off = 1; off < THREADS; off <<= 1) {
        int a = (t >= off) ? wsum[t - off] : 0;
        __syncthreads();
        wsum[t] += a;
        __syncthreads();
    }
    int run = wsum[t] - s;  // exclusive
#pragma unroll
    for (int k = 0; k < SCANCH; ++k) {
        int c = v[k];
        if (base + k < nblk_part) row[base + k] = run;
        run += c;
    }
    if (t == THREADS - 1) bintot[blockIdx.x] = run;
}

// ---------------- scan bin totals (single block, nb<=512) ----------------
__global__ __launch_bounds__(512)
void k_binscan(const int* __restrict__ bintot, int* __restrict__ binptr,
               int nb, int e) {
    __shared__ int lds[512];
    int t = threadIdx.x;
    int v = (t < nb) ? bintot[t] : 0;
    lds[t] = v;
    __syncthreads();
    for (int off = 1; off < 512; off <<= 1) {
        int a = (t >= off) ? lds[t - off] : 0;
        __syncthreads();
        lds[t] += a;
        __syncthreads();
    }
    if (t < nb) binptr[t] = lds[t] - v;  // exclusive
    if (t == 0) binptr[nb] = e;
}

// ---------------- pass 2: LDS-staged deterministic partition write ----------
__global__ __launch_bounds__(THREADS)
void k_partwrite(const int* __restrict__ src, const int* __restrict__ dst,
                 const int* __restrict__ binptr, const int* __restrict__ counts,
                 int nblk_part, unsigned* __restrict__ pairs, int nb, int e) {
    __shared__ int hist[NBMAX];
    __shared__ int lbase[NBMAX];
    __shared__ int gbase[NBMAX];
    __shared__ int cur[NBMAX];
    __shared__ int wsum[THREADS];
    __shared__ unsigned stage[EPBA];
    int t = threadIdx.x;
    for (int i = t; i < nb; i += THREADS) hist[i] = 0;
    __syncthreads();
    int lo = blockIdx.x * EPBA;
    int hi = min(lo + EPBA, e);
    for (int i = lo + t; i < hi; i += THREADS)
        atomicAdd(&hist[dst[i] >> BINSHIFT], 1);
    __syncthreads();
    int v0 = (2 * t < nb) ? hist[2 * t] : 0;
    int v1 = (2 * t + 1 < nb) ? hist[2 * t + 1] : 0;
    int s = v0 + v1;
    wsum[t] = s;
    __syncthreads();
    for (int off = 1; off < THREADS; off <<= 1) {
        int a = (t >= off) ? wsum[t - off] : 0;
        __syncthreads();
        wsum[t] += a;
        __syncthreads();
    }
    int excl = wsum[t] - s;
    if (2 * t < nb) { lbase[2 * t] = excl; cur[2 * t] = excl; }
    if (2 * t + 1 < nb) { lbase[2 * t + 1] = excl + v0; cur[2 * t + 1] = excl + v0; }
    for (int i = t; i < nb; i += THREADS)
        gbase[i] = binptr[i] + counts[(size_t)i * nblk_part + blockIdx.x];
    __syncthreads();
    for (int i = lo + t; i < hi; i += THREADS) {
        int s2 = src[i], d = dst[i];
        int b = d >> BINSHIFT;
        int pos = atomicAdd(&cur[b], 1);   // LDS only
        stage[pos] = ((unsigned)s2 << BINSHIFT) | (unsigned)(d & ((1 << BINSHIFT) - 1));
    }
    __syncthreads();
    int wid = t >> 6, lane = t & 63;
    for (int b = wid; b < nb; b += (THREADS / 64)) {
        int n = hist[b];
        int lb = lbase[b];
        int gb = gbase[b];
        for (int k = lane; k < n; k += 64)
            pairs[gb + k] = stage[lb + k];
    }
}

// ---------------- per-bin CSR finalize (256-node bins) ----------------
// srcs written PRE-SCALED by 8.
__global__ __launch_bounds__(THREADS)
void k_bincsr(const unsigned* __restrict__ pairs, const int* __restrict__ binptr,
              int* __restrict__ rowptr, float* __restrict__ dinv,
              int* __restrict__ srcs, int n, int nb, int e) {
    __shared__ int lcnt[256];
    __shared__ int lofs[256];
    int b = blockIdx.x, t = threadIdx.x;
    int e0 = binptr[b], e1 = binptr[b + 1];
    int n0 = b << BINSHIFT;
    constexpr unsigned NMASK = (1u << BINSHIFT) - 1u;
    lcnt[t] = 0;
    __syncthreads();
    for (int j = e0 + t; j < e1; j += THREADS)
        atomicAdd(&lcnt[pairs[j] & NMASK], 1);
    __syncthreads();
    int c = lcnt[t];
    lofs[t] = c;
    __syncthreads();
    for (int off = 1; off < THREADS; off <<= 1) {
        int a = (t >= off) ? lofs[t - off] : 0;
        __syncthreads();
        lofs[t] += a;
        __syncthreads();
    }
    int excl = lofs[t] - c;
    __syncthreads();
    lofs[t] = excl;
    int node = n0 + t;
    if (node < n) {
        rowptr[node] = e0 + excl;
        dinv[node] = rsqrtf((float)c + 1.0f);
    }
    if (b == nb - 1 && t == 0) rowptr[n] = e;
    __syncthreads();
    for (int j = e0 + t; j < e1; j += THREADS) {
        unsigned pp = pairs[j];
        int pos = e0 + atomicAdd(&lofs[pp & NMASK], 1);
        srcs[pos] = (int)((pp >> BINSHIFT) << 3);   // pre-scaled x8
    }
}

// ---------------- merged embedding (all 4 node types) ----------------
struct EmbedArgs {
    const float* f[4];
    const float* W[4];
    const float* b[4];
    const int*   idx[4];
    int cum[5];
    int Kv[4];
};

__global__ __launch_bounds__(THREADS)
void k_embed_all(EmbedArgs ea, const float* __restrict__ dinv,
                 unsigned* __restrict__ xb) {
    int g = blockIdx.x * THREADS + threadIdx.x;
    int row = g >> 4, cp = g & 15;
    if (row >= ea.cum[4]) return;
    int t = (row >= ea.cum[1]) + (row >= ea.cum[2]) + (row >= ea.cum[3]);
    int r = row - ea.cum[t];
    int K = ea.Kv[t];
    const float* f  = ea.f[t];
    const float* W  = ea.W[t];
    const float* bb = ea.b[t];
    int node = ea.idx[t][r];
    float dv = dinv[node];
    float a0 = bb[2 * cp], a1 = bb[2 * cp + 1];
    for (int k = 0; k < K; ++k) {
        float fv = f[r * K + k];
        a0 += fv * W[k * 32 + 2 * cp];
        a1 += fv * W[k * 32 + 2 * cp + 1];
    }
    xb[(size_t)node * 16 + cp] = bfpack2(dv * a0, dv * a1);
}

// ---------------- gather (bf16 table, row=128B): one wave per node ----------
// 8 groups x 8 lanes, uint4 per lane (one load instr = 8 edge rows);
// v_pk_add_f32 accumulation; srcs pre-scaled x8 = uint4-unit row base
// (row = 64 bf16 = 8 uint4). out bf16 packed (uint4 per lane, lanes 0-7).
template <bool HASBIAS, bool OUTRELU, bool HASRES>
__global__ __launch_bounds__(THREADS)
void k_gather64(const unsigned* __restrict__ tblb, const int* __restrict__ rowptr,
                const int* __restrict__ srcs, const float* __restrict__ dinv,
                const float* __restrict__ bias, const unsigned* __restrict__ resid,
                unsigned* __restrict__ outb, int n) {
    int gt = blockIdx.x * THREADS + threadIdx.x;
    int node = gt >> 6;
    int lane = threadIdx.x & 63;
    if (node >= n) return;
    int og = lane >> 3, li = lane & 7;
    const uint4* t4 = reinterpret_cast<const uint4*>(tblb);
    f32x2 ac0 = {0.f, 0.f}, ac1 = {0.f, 0.f}, ac2 = {0.f, 0.f}, ac3 = {0.f, 0.f};
    int beg = rowptr[node], end = rowptr[node + 1];
    int j = beg;
    for (; j + 16 <= end; j += 16) {          // 16 edges, 2 uint4 rows/lane
        int s0 = srcs[j + og];                // s0 = src*8 = uint4-unit row base
        int s1 = srcs[j + 8 + og];
        uint4 v0 = t4[(size_t)s0 + li];
        uint4 v1 = t4[(size_t)s1 + li];
        pk2(ac0, v0.x); pk2(ac1, v0.y); pk2(ac2, v0.z); pk2(ac3, v0.w);
        pk2(ac0, v1.x); pk2(ac1, v1.y); pk2(ac2, v1.z); pk2(ac3, v1.w);
    }
    for (; j + 8 <= end; j += 8) {
        int s0 = srcs[j + og];
        uint4 v0 = t4[(size_t)s0 + li];
        pk2(ac0, v0.x); pk2(ac1, v0.y); pk2(ac2, v0.z); pk2(ac3, v0.w);
    }
    int rem = end - j;
    if (og < rem) {
        uint4 v = t4[(size_t)srcs[j + og] + li];
        pk2(ac0, v.x); pk2(ac1, v.y); pk2(ac2, v.z); pk2(ac3, v.w);
    }
    float a[8] = {ac0.x, ac0.y, ac1.x, ac1.y, ac2.x, ac2.y, ac3.x, ac3.y};
#pragma unroll
    for (int i = 0; i < 8; ++i) {
        a[i] += __shfl_down(a[i], 32, 64);
        a[i] += __shfl_down(a[i], 16, 64);
        a[i] += __shfl_down(a[i], 8, 64);
    }
    if (lane < 8) {
        uint4 sv = t4[(size_t)node * 8 + li];
        a[0] += __uint_as_float(sv.x << 16);
        a[1] += __uint_as_float(sv.x & 0xffff0000u);
        a[2] += __uint_as_float(sv.y << 16);
        a[3] += __uint_as_float(sv.y & 0xffff0000u);
        a[4] += __uint_as_float(sv.z << 16);
        a[5] += __uint_as_float(sv.z & 0xffff0000u);
        a[6] += __uint_as_float(sv.w << 16);
        a[7] += __uint_as_float(sv.w & 0xffff0000u);
        float dv = dinv[node];
#pragma unroll
        for (int i = 0; i < 8; ++i) a[i] *= dv;
        if (HASBIAS) {
            float4 b0 = *reinterpret_cast<const float4*>(bias + 8 * li);
            float4 b1 = *reinterpret_cast<const float4*>(bias + 8 * li + 4);
            a[0] += b0.x; a[1] += b0.y; a[2] += b0.z; a[3] += b0.w;
            a[4] += b1.x; a[5] += b1.y; a[6] += b1.z; a[7] += b1.w;
        }
        if (OUTRELU) {
#pragma unroll
            for (int i = 0; i < 8; ++i) a[i] = fmaxf(a[i], 0.f);
        }
        if (HASRES) {
            uint4 rv = reinterpret_cast<const uint4*>(resid)[(size_t)node * 8 + li];
            a[0] += __uint_as_float(rv.x << 16);
            a[1] += __uint_as_float(rv.x & 0xffff0000u);
            a[2] += __uint_as_float(rv.y << 16);
            a[3] += __uint_as_float(rv.y & 0xffff0000u);
            a[4] += __uint_as_float(rv.z << 16);
            a[5] += __uint_as_float(rv.z & 0xffff0000u);
            a[6] += __uint_as_float(rv.w << 16);
            a[7] += __uint_as_float(rv.w & 0xffff0000u);
        }
        uint4 o = {bfpack2(a[0], a[1]), bfpack2(a[2], a[3]),
                   bfpack2(a[4], a[5]), bfpack2(a[6], a[7])};
        reinterpret_cast<uint4*>(outb)[(size_t)node * 8 + li] = o;
    }
}

// ---------------- gather (bf16 table, row=64B): 8 groups of 8 lanes ---------
// srcs pre-scaled x8 = exact uint2-unit row base (row = 32 bf16 = 8 uint2).
__global__ __launch_bounds__(THREADS)
void k_gather32(const unsigned* __restrict__ tblb, const int* __restrict__ rowptr,
                const int* __restrict__ srcs, const float* __restrict__ dinv,
                unsigned* __restrict__ outb, int n) {
    int gt = blockIdx.x * THREADS + threadIdx.x;
    int node = gt >> 6;
    int lane = threadIdx.x & 63;
    if (node >= n) return;
    int og = lane >> 3, li = lane & 7;
    const uint2* t2 = reinterpret_cast<const uint2*>(tblb);
    f32x2 ac0 = {0.f, 0.f}, ac1 = {0.f, 0.f};
    int beg = rowptr[node], end = rowptr[node + 1];
    int j = beg;
    for (; j + 16 <= end; j += 16) {
        int s0 = srcs[j + og];
        int s1 = srcs[j + 8 + og];
        uint2 v0 = t2[(size_t)s0 + li];
        uint2 v1 = t2[(size_t)s1 + li];
        pk2(ac0, v0.x); pk2(ac1, v0.y);
        pk2(ac0, v1.x); pk2(ac1, v1.y);
    }
    for (; j + 8 <= end; j += 8) {
        int s0 = srcs[j + og];
        uint2 v0 = t2[(size_t)s0 + li];
        pk2(ac0, v0.x); pk2(ac1, v0.y);
    }
    int rem = end - j;
    if (og < rem) {
        uint2 v = t2[(size_t)srcs[j + og] + li];
        pk2(ac0, v.x); pk2(ac1, v.y);
    }
    float a0 = ac0.x, a1 = ac0.y, a2 = ac1.x, a3 = ac1.y;
    a0 += __shfl_down(a0, 32, 64); a1 += __shfl_down(a1, 32, 64);
    a2 += __shfl_down(a2, 32, 64); a3 += __shfl_down(a3, 32, 64);
    a0 += __shfl_down(a0, 16, 64); a1 += __shfl_down(a1, 16, 64);
    a2 += __shfl_down(a2, 16, 64); a3 += __shfl_down(a3, 16, 64);
    a0 += __shfl_down(a0, 8, 64);  a1 += __shfl_down(a1, 8, 64);
    a2 += __shfl_down(a2, 8, 64);  a3 += __shfl_down(a3, 8, 64);
    if (lane < 8) {
        uint2 sv = t2[(size_t)node * 8 + li];
        a0 += __uint_as_float(sv.x << 16);
        a1 += __uint_as_float(sv.x & 0xffff0000u);
        a2 += __uint_as_float(sv.y << 16);
        a3 += __uint_as_float(sv.y & 0xffff0000u);
        float dv = dinv[node];
        uint2 o = {bfpack2(dv * a0, dv * a1), bfpack2(dv * a2, dv * a3)};
        reinterpret_cast<uint2*>(outb)[(size_t)node * 8 + li] = o;
    }
}

// ---------------- merged weight prep: all three W^T bf16 tables --------------
__global__ __launch_bounds__(THREADS)
void k_wprep_all(const float* __restrict__ W1, const float* __restrict__ W2,
                 const float* __restrict__ W3, unsigned* __restrict__ wt) {
    int g = blockIdx.x * THREADS + threadIdx.x;
    if (g < 1024) {
        int nn = g >> 4, kq = g & 15;
        wt[g] = bfpack2(W1[(size_t)(2 * kq) * 64 + nn], W1[(size_t)(2 * kq + 1) * 64 + nn]);
    } else if (g < 5120) {
        int gg = g - 1024;
        int nn = gg >> 5, kq = gg & 31;
        wt[g] = bfpack2(W2[(size_t)(2 * kq) * 128 + nn], W2[(size_t)(2 * kq + 1) * 128 + nn]);
    } else if (g < 9216) {
        int gg = g - 5120;
        int nn = gg >> 6, kq = gg & 63;
        wt[g] = bfpack2(W3[(size_t)(2 * kq) * 64 + nn], W3[(size_t)(2 * kq + 1) * 64 + nn]);
    }
}

// ---------------- MFMA dense matmul ------------------------------------------
// EXTRA: 1 = outb=bf16(v+b), outb2=bf16(dinv*relu(v+b))   [mm1]
//        2 = outb=bf16(dinv*v)                             [mm3]
//        3 = outb=bf16(relu(v+b))                          [mm2]
template <int FIN, int FOUT, int EXTRA>
__global__ __launch_bounds__(THREADS)
void k_mmfa(const unsigned* __restrict__ xinb, const unsigned* __restrict__ wtb,
            const float* __restrict__ bias, const float* __restrict__ dinv,
            unsigned* __restrict__ outb, unsigned* __restrict__ outb2, int nrows) {
    constexpr int FH = FIN / 2;   // u32 per row
    constexpr int KS = FIN / 32;  // K-steps
    constexpr int MT = FOUT / 16; // out-col tiles
    int tid = threadIdx.x;
    int lane = tid & 63;
    int lg = lane >> 4, li = lane & 15;
    int node = blockIdx.x * 64 + (tid >> 6) * 16 + li;
    int nc = min(node, nrows - 1);

    const uint4* xr = reinterpret_cast<const uint4*>(xinb + (size_t)nc * FH);
    short8 bf[KS];
#pragma unroll
    for (int ks = 0; ks < KS; ++ks) bf[ks] = as_short8(xr[ks * 4 + lg]);

    f32x4 acc[MT];
#pragma unroll
    for (int mt = 0; mt < MT; ++mt) acc[mt] = (f32x4){0.f, 0.f, 0.f, 0.f};

#pragma unroll
    for (int ks = 0; ks < KS; ++ks) {
#pragma unroll
        for (int mt = 0; mt < MT; ++mt) {
            uint4 wu = *reinterpret_cast<const uint4*>(
                wtb + (size_t)(mt * 16 + li) * FH + ks * 16 + lg * 4);
            acc[mt] = __builtin_amdgcn_mfma_f32_16x16x32_bf16(
                as_short8(wu), bf[ks], acc[mt], 0, 0, 0);
        }
    }

    if (node >= nrows) return;
    float dv = (EXTRA != 3) ? dinv[node] : 0.f;
#pragma unroll
    for (int mt = 0; mt < MT; ++mt) {
        float v0 = acc[mt][0], v1 = acc[mt][1], v2 = acc[mt][2], v3 = acc[mt][3];
        int m0 = mt * 16 + lg * 4;
        if (EXTRA == 1 || EXTRA == 3) {
            float4 bv = *reinterpret_cast<const float4*>(bias + m0);
            v0 += bv.x; v1 += bv.y; v2 += bv.z; v3 += bv.w;
        }
        size_t ob = (size_t)node * (FOUT / 2) + mt * 8 + lg * 2;
        if (EXTRA == 1) {
            uint2 o = {bfpack2(v0, v1), bfpack2(v2, v3)};
            *reinterpret_cast<uint2*>(outb + ob) = o;
            uint2 s = {bfpack2(dv * fmaxf(v0, 0.f), dv * fmaxf(v1, 0.f)),
                       bfpack2(dv * fmaxf(v2, 0.f), dv * fmaxf(v3, 0.f))};
            *reinterpret_cast<uint2*>(outb2 + ob) = s;
        }
        if (EXTRA == 3) {
            uint2 o = {bfpack2(fmaxf(v0, 0.f), fmaxf(v1, 0.f)),
                       bfpack2(fmaxf(v2, 0.f), fmaxf(v3, 0.f))};
            *reinterpret_cast<uint2*>(outb + ob) = o;
        }
        if (EXTRA == 2) {
            uint2 o = {bfpack2(dv * v0, dv * v1), bfpack2(dv * v2, dv * v3)};
            *reinterpret_cast<uint2*>(outb + ob) = o;
        }
    }
}

// ---------------- segment mean pool (bf16 input) ----------------
__global__ __launch_bounds__(THREADS)
void k_pool(const unsigned* __restrict__ hb, const int* __restrict__ batch,
            float* __restrict__ sums, float* __restrict__ cnts, int n) {
    int c = threadIdx.x & 31;          // u32 column (2 bf16)
    int rq = threadIdx.x >> 5;         // 0..7
    int r0 = blockIdx.x * THREADS;     // 256 rows per block
    int rend = min(r0 + THREADS, n);
    int curg = -1;
    float a0 = 0.f, a1 = 0.f, cacc = 0.f;
    for (int r = r0 + rq; r < rend; r += 8) {
        int g = batch[r];
        if (g != curg) {
            if (curg >= 0) {
                atomicAdd(&sums[(size_t)curg * 64 + 2 * c], a0);
                atomicAdd(&sums[(size_t)curg * 64 + 2 * c + 1], a1);
                if (c == 0) atomicAdd(&cnts[curg], cacc);
            }
            curg = g; a0 = 0.f; a1 = 0.f; cacc = 0.f;
        }
        unsigned u = hb[(size_t)r * 32 + c];
        a0 += __uint_as_float(u << 16);
        a1 += __uint_as_float(u & 0xffff0000u);
        cacc += 1.f;
    }
    if (curg >= 0) {
        atomicAdd(&sums[(size_t)curg * 64 + 2 * c], a0);
        atomicAdd(&sums[(size_t)curg * 64 + 2 * c + 1], a1);
        if (c == 0) atomicAdd(&cnts[curg], cacc);
    }
}

__global__ __launch_bounds__(THREADS)
void k_div(const float* __restrict__ sums, const float* __restrict__ cnts,
           float* __restrict__ out, int total) {
    int i = blockIdx.x * THREADS + threadIdx.x;
    if (i < total) out[i] = sums[i] / cnts[i >> 6];
}

// ---------------------------------------------------------------------------
static inline size_t alignup(size_t v) { return (v + 255) & ~(size_t)255; }

extern "C" void kernel_launch(void* const* d_in, const int* in_sizes, int n_in,
                              void* d_out, int out_size, void* d_ws, size_t ws_size,
                              hipStream_t stream) {
    const float* ev_f  = (const float*)d_in[0];
    const float* cs_f  = (const float*)d_in[1];
    const float* tr_f  = (const float*)d_in[2];
    const float* env_f = (const float*)d_in[3];
    const int*   ei    = (const int*)d_in[4];
    const int*   ev_i  = (const int*)d_in[5];
    const int*   cs_i  = (const int*)d_in[6];
    const int*   tr_i  = (const int*)d_in[7];
    const int*   env_i = (const int*)d_in[8];
    const int*   batch = (const int*)d_in[9];
    const float* W_ev = (const float*)d_in[10]; const float* b_ev = (const float*)d_in[11];
    const float* W_cs = (const float*)d_in[12]; const float* b_cs = (const float*)d_in[13];
    const float* W_tr = (const float*)d_in[14]; const float* b_tr = (const float*)d_in[15];
    const float* W_env= (const float*)d_in[16]; const float* b_env= (const float*)d_in[17];
    const float* W1 = (const float*)d_in[18]; const float* b1 = (const float*)d_in[19];
    const float* W2 = (const float*)d_in[20]; const float* b2 = (const float*)d_in[21];
    const float* W3 = (const float*)d_in[22]; const float* b3 = (const float*)d_in[23];

    const int E_ = in_sizes[4] / 2;
    const int N_ = in_sizes[9];
    const int n_ev  = in_sizes[5];
    const int n_cs  = in_sizes[6];
    const int n_tr  = in_sizes[7];
    const int n_env = in_sizes[8];
    const int ngr   = out_size / 64;  // 100 graphs

    const int* e_src = ei;
    const int* e_dst = ei + E_;

    const int NB   = (N_ + (1 << BINSHIFT) - 1) >> BINSHIFT;  // 391 bins
    const int ablk = (E_ + EPBA - 1) / EPBA;                  // 391 partition blocks

    // ---- workspace carve-up ----
    char* p = (char*)d_ws;
    int*      counts = (int*)p;      p += alignup((size_t)NB * ablk * 4);
    int*      bintot = (int*)p;      p += alignup((size_t)NB * 4);
    int*      binptr = (int*)p;      p += alignup(((size_t)NB + 1) * 4);
    int*      rowptr = (int*)p;      p += alignup(((size_t)N_ + 1) * 4);
    float*    dinv   = (float*)p;    p += alignup((size_t)N_ * 4);
    int*      srcs   = (int*)p;      p += alignup((size_t)E_ * 4);
    unsigned* xb     = (unsigned*)p; p += alignup((size_t)N_ * 16 * 4);   // bf16 [N,32]
    unsigned* x1b    = (unsigned*)p; p += alignup((size_t)N_ * 32 * 4);   // bf16 [N,64] raw x1
    unsigned* x1s_bf = (unsigned*)p; p += alignup((size_t)N_ * 32 * 4);   // bf16 conv2 table
    unsigned* aggb   = (unsigned*)p; p += alignup((size_t)N_ * 32 * 4);   // bf16 gather out
    unsigned* hA     = (unsigned*)p; p += alignup((size_t)N_ * 64 * 4);   // bf16 [N,128] mm2 out
    unsigned* t3s_bf = (unsigned*)p; p += alignup((size_t)N_ * 32 * 4);   // bf16 conv3 table
    unsigned* hfb    = (unsigned*)p; p += alignup((size_t)N_ * 32 * 4);   // bf16 pool input
    unsigned* wt     = (unsigned*)p; p += alignup((size_t)9216 * 4);      // all W^T bf16
    float*    sums   = (float*)p;    p += alignup((size_t)ngr * 64 * 4);
    float*    cnts   = (float*)p;    p += alignup((size_t)ngr * 4);

    unsigned* w1t = wt;
    unsigned* w2t = wt + 1024;
    unsigned* w3t = wt + 5120;

    // pairs (E u32 = 12.8MB) aliases hA (25.6MB): dead at k_bincsr, hA first
    // written by mm2 (after bincsr).
    unsigned* pairs = hA;

    const int nblk  = (N_ + THREADS - 1) / THREADS;
    const int mfblk = (N_ + 63) / 64;                               // 64 rows/block
    const int gblk  = ((size_t)N_ * 64 + THREADS - 1) / THREADS;    // wave/node

    // ---- zero accumulated buffers (fresh every call) ----
    hipMemsetAsync(sums, 0, (size_t)ngr * 64 * 4, stream);
    hipMemsetAsync(cnts, 0, (size_t)ngr * 4, stream);

    // ---- CSR build (atomic-free partition) ----
    k_partcnt<<<ablk, THREADS, (size_t)NB * 4, stream>>>(e_dst, counts, ablk, NB, E_);
    k_scanrows<<<NB, THREADS, 0, stream>>>(counts, bintot, ablk);
    k_binscan<<<1, 512, 0, stream>>>(bintot, binptr, NB, E_);
    k_partwrite<<<ablk, THREADS, 0, stream>>>(e_src, e_dst, binptr, counts, ablk, pairs, NB, E_);
    k_bincsr<<<NB, THREADS, 0, stream>>>(pairs, binptr, rowptr, dinv, srcs, N_, NB, E_);

    // ---- weight prep (one tiny kernel) ----
    k_wprep_all<<<(9216 + THREADS - 1) / THREADS, THREADS, 0, stream>>>(W1, W2, W3, wt);

    // ---- embeddings -> xb [N,32] bf16 (pre-scaled by dinv), one kernel ----
    EmbedArgs ea;
    ea.f[0] = ev_f;  ea.f[1] = cs_f;  ea.f[2] = tr_f;  ea.f[3] = env_f;
    ea.W[0] = W_ev;  ea.W[1] = W_cs;  ea.W[2] = W_tr;  ea.W[3] = W_env;
    ea.b[0] = b_ev;  ea.b[1] = b_cs;  ea.b[2] = b_tr;  ea.b[3] = b_env;
    ea.idx[0] = ev_i; ea.idx[1] = cs_i; ea.idx[2] = tr_i; ea.idx[3] = env_i;
    ea.cum[0] = 0;
    ea.cum[1] = n_ev;
    ea.cum[2] = n_ev + n_cs;
    ea.cum[3] = n_ev + n_cs + n_tr;
    ea.cum[4] = n_ev + n_cs + n_tr + n_env;
    ea.Kv[0] = in_sizes[0] / n_ev;
    ea.Kv[1] = in_sizes[1] / n_cs;
    ea.Kv[2] = in_sizes[2] / n_tr;
    ea.Kv[3] = in_sizes[3] / n_env;
    k_embed_all<<<((size_t)ea.cum[4] * 16 + THREADS - 1) / THREADS, THREADS, 0, stream>>>(ea, dinv, xb);

    // ---- conv1: agg(xb) -> aggb bf16; mm1: x1b=bf16(x1), x1s_bf=bf16(dinv*relu(x1)) ----
    k_gather32<<<gblk, THREADS, 0, stream>>>(xb, rowptr, srcs, dinv, aggb, N_);
    k_mmfa<32, 64, 1><<<mfblk, THREADS, 0, stream>>>(aggb, w1t, b1, dinv, x1b, x1s_bf, N_);

    // ---- conv2: agg(x1s_bf) -> aggb bf16; mm2: relu(@W2+b2) -> hA bf16 [N,128] ----
    k_gather64<false, false, false><<<gblk, THREADS, 0, stream>>>(
        x1s_bf, rowptr, srcs, dinv, nullptr, nullptr, aggb, N_);
    k_mmfa<64, 128, 3><<<mfblk, THREADS, 0, stream>>>(aggb, w2t, b2, nullptr, hA, nullptr, N_);

    // ---- conv3: mm3: t3s_bf = bf16(dinv*(hA @ W3)); gather3: relu(agg+b3)+x1b -> hfb bf16 ----
    k_mmfa<128, 64, 2><<<mfblk, THREADS, 0, stream>>>(hA, w3t, nullptr, dinv, t3s_bf, nullptr, N_);
    k_gather64<true, true, true><<<gblk, THREADS, 0, stream>>>(
        t3s_bf, rowptr, srcs, dinv, b3, x1b, hfb, N_);

    // ---- pool ----
    k_pool<<<nblk, THREADS, 0, stream>>>(hfb, batch, sums, cnts, N_);
    k_div<<<(out_size + THREADS - 1) / THREADS, THREADS, 0, stream>>>(sums, cnts, (float*)d_out, out_size);
}